// Round 11
// baseline (535.805 us; speedup 1.0000x reference)
//
#include <hip/hip_runtime.h>
#include <float.h>
#include <math.h>

// Problem constants: B=32, NF=64, FD=64, ND=256, C=8, K=6, L=2, scale=1/8.

typedef short bf8t __attribute__((ext_vector_type(8)));   // 8 bf16 in 4 VGPRs
typedef float f4t __attribute__((ext_vector_type(4)));

static __device__ __forceinline__ unsigned short f2bf(float x) {
  union { float f; unsigned u; } v; v.f = x;
  unsigned r = (v.u + 0x7FFFu + ((v.u >> 16) & 1u)) >> 16;
  return (unsigned short)r;
}
static __device__ __forceinline__ float bf2f(unsigned short s) {
  union { unsigned u; float f; } v; v.u = ((unsigned)s) << 16; return v.f;
}
static __device__ __forceinline__ float bf2f_lo(unsigned u) {
  union { unsigned u; float f; } v; v.u = u << 16; return v.f;
}
static __device__ __forceinline__ float bf2f_hi(unsigned u) {
  union { unsigned u; float f; } v; v.u = u & 0xFFFF0000u; return v.f;
}
// 2 packed elems of the 3-term split dot: qh*(kh+kl) + ql*kh
static __device__ __forceinline__ float dot3_pair(unsigned uqh, unsigned uql,
                                                  unsigned ukh, unsigned ukl) {
  float s = bf2f_lo(uqh) * (bf2f_lo(ukh) + bf2f_lo(ukl)) + bf2f_lo(uql) * bf2f_lo(ukh);
  s += bf2f_hi(uqh) * (bf2f_hi(ukh) + bf2f_hi(ukl)) + bf2f_hi(uql) * bf2f_hi(ukh);
  return s;
}

// ---------------------------------------------------------------------------
// Cooperative 64x64 row-row matmul (LDS stride 65, 4x4 register tile).
// ---------------------------------------------------------------------------
static __device__ __forceinline__ void mm_rr(
    const float* __restrict__ A, const float* __restrict__ B,
    float* __restrict__ C, int t, float scale, int addI, int transposeStore) {
  int tr = t >> 4, tc = t & 15;
  float acc[4][4];
#pragma unroll
  for (int j = 0; j < 4; j++)
#pragma unroll
    for (int jj = 0; jj < 4; jj++) acc[j][jj] = 0.f;
  const float* Ap = A + (4 * tr) * 65;
  const float* Bp = B + (4 * tc) * 65;
  for (int k = 0; k < 64; k++) {
    float a0 = Ap[k], a1 = Ap[65 + k], a2 = Ap[130 + k], a3 = Ap[195 + k];
    float b0 = Bp[k], b1 = Bp[65 + k], b2 = Bp[130 + k], b3 = Bp[195 + k];
    acc[0][0] += a0 * b0; acc[0][1] += a0 * b1; acc[0][2] += a0 * b2; acc[0][3] += a0 * b3;
    acc[1][0] += a1 * b0; acc[1][1] += a1 * b1; acc[1][2] += a1 * b2; acc[1][3] += a1 * b3;
    acc[2][0] += a2 * b0; acc[2][1] += a2 * b1; acc[2][2] += a2 * b2; acc[2][3] += a2 * b3;
    acc[3][0] += a3 * b0; acc[3][1] += a3 * b1; acc[3][2] += a3 * b2; acc[3][3] += a3 * b3;
  }
#pragma unroll
  for (int j = 0; j < 4; j++)
#pragma unroll
    for (int jj = 0; jj < 4; jj++) {
      int i0 = 4 * tr + j, j0 = 4 * tc + jj;
      float v = acc[j][jj] * scale + ((addI && i0 == j0) ? 1.0f : 0.0f);
      if (transposeStore) C[j0 * 65 + i0] = v; else C[i0 * 65 + j0] = v;
    }
}

// Gram: G = A_glob * A_glob^T (A_glob is 64 x ncols, row-major), staged in S.
static __device__ __forceinline__ void gram(
    const float* __restrict__ Ag, int ncols, float* __restrict__ S,
    float* __restrict__ G, int t) {
  int tr = t >> 4, tc = t & 15;
  float acc[4][4];
#pragma unroll
  for (int j = 0; j < 4; j++)
#pragma unroll
    for (int jj = 0; jj < 4; jj++) acc[j][jj] = 0.f;
  for (int cc = 0; cc < ncols; cc += 64) {
    if (cc) __syncthreads();
    for (int i = t; i < 1024; i += 256) {
      int r = i >> 4, qq = i & 15;
      float4 v = *(const float4*)(Ag + (size_t)r * ncols + cc + 4 * qq);
      float* dst = S + r * 65 + 4 * qq;
      dst[0] = v.x; dst[1] = v.y; dst[2] = v.z; dst[3] = v.w;
    }
    __syncthreads();
    const float* Ap = S + (4 * tr) * 65;
    const float* Bp = S + (4 * tc) * 65;
    for (int k = 0; k < 64; k++) {
      float a0 = Ap[k], a1 = Ap[65 + k], a2 = Ap[130 + k], a3 = Ap[195 + k];
      float b0 = Bp[k], b1 = Bp[65 + k], b2 = Bp[130 + k], b3 = Bp[195 + k];
      acc[0][0] += a0 * b0; acc[0][1] += a0 * b1; acc[0][2] += a0 * b2; acc[0][3] += a0 * b3;
      acc[1][0] += a1 * b0; acc[1][1] += a1 * b1; acc[1][2] += a1 * b2; acc[1][3] += a1 * b3;
      acc[2][0] += a2 * b0; acc[2][1] += a2 * b1; acc[2][2] += a2 * b2; acc[2][3] += a2 * b3;
      acc[3][0] += a3 * b0; acc[3][1] += a3 * b1; acc[3][2] += a3 * b2; acc[3][3] += a3 * b3;
    }
  }
  __syncthreads();
#pragma unroll
  for (int j = 0; j < 4; j++)
#pragma unroll
    for (int jj = 0; jj < 4; jj++) G[(4 * tr + j) * 65 + (4 * tc + jj)] = acc[j][jj];
}

// Single-wave power iteration + Rayleigh on Gm (caller gates t < 64).
static __device__ __forceinline__ float power_rayleigh(
    const float* __restrict__ G4m, const float* __restrict__ Gm, int iters, int i) {
  float row[64];
#pragma unroll
  for (int j = 0; j < 64; j++) row[j] = G4m[i * 65 + j];
  float v = 1.0f + 0.3f * sinf(7.0f * (float)(i + 1));
  for (int it = 0; it < iters; it++) {
    float u = 0.f;
#pragma unroll
    for (int j = 0; j < 64; j++) u += row[j] * __shfl(v, j, 64);
    float ss = u * u;
#pragma unroll
    for (int m = 1; m < 64; m <<= 1) ss += __shfl_xor(ss, m, 64);
    v = u * rsqrtf(fmaxf(ss, 1e-30f));
  }
  float rowg[64];
#pragma unroll
  for (int j = 0; j < 64; j++) rowg[j] = Gm[i * 65 + j];
  float u = 0.f;
#pragma unroll
  for (int j = 0; j < 64; j++) u += rowg[j] * __shfl(v, j, 64);
  float d = v * u;
#pragma unroll
  for (int m = 1; m < 64; m <<= 1) d += __shfl_xor(d, m, 64);
  return d;
}

// ---------------------------------------------------------------------------
// Fused spectral norms + lip: grid 130.
// ---------------------------------------------------------------------------
__global__ __launch_bounds__(256) void speclip_kernel(
    const float* __restrict__ w1, const float* __restrict__ w2,
    const float* __restrict__ gaw, float* __restrict__ invsig1,
    float* __restrict__ invsig2, float* __restrict__ lipv) {
  __shared__ float Sa[64 * 65];
  __shared__ float Sb[64 * 65];
  __shared__ float G[64 * 65];
  int t = threadIdx.x;
  int blk = blockIdx.x;
  if (blk < 128) {
    int n = blk & 63;
    const float* A = (blk < 64) ? (w1 + (size_t)n * 4096) : (w2 + (size_t)n * 16384);
    int ncols = (blk < 64) ? 64 : 256;
    gram(A, ncols, Sa, G, t);
    __syncthreads();
    mm_rr(G, G, Sa, t, 1.f, 0, 0);
    __syncthreads();
    mm_rr(Sa, Sa, Sb, t, 1.f, 0, 0);
    __syncthreads();
    if (t < 64) {
      float d = power_rayleigh(Sb, G, 30, t);
      if (t == 0) {
        float sg = sqrtf(fmaxf(d, 0.f));
        float inv = 1.0f / fmaxf(sg, 1e-6f);
        if (blk < 64) invsig1[n] = inv; else invsig2[n] = inv;
      }
    }
  } else {
    int l = blk - 128;
    const float* Wb = gaw + (size_t)l * 8192;
    for (int i = t; i < 1024; i += 256) {
      int r = i >> 4, qq = i & 15;
      float4 vq = *(const float4*)(Wb + r * 64 + 4 * qq);
      float4 vk = *(const float4*)(Wb + 4096 + r * 64 + 4 * qq);
      float* dq = Sa + r * 65 + 4 * qq;
      dq[0] = vq.x; dq[1] = vq.y; dq[2] = vq.z; dq[3] = vq.w;
      float* dk = Sb + r * 65 + 4 * qq;
      dk[0] = vk.x; dk[1] = vk.y; dk[2] = vk.z; dk[3] = vk.w;
    }
    __syncthreads();
    mm_rr(Sa, Sb, G, t, 0.25f, 1, 1);
    __syncthreads();
    mm_rr(G, G, Sa, t, 1.f, 0, 0);
    __syncthreads();
    mm_rr(Sa, Sa, Sb, t, 1.f, 0, 0);
    __syncthreads();
    mm_rr(Sb, Sb, G, t, 1.f, 0, 0);
    __syncthreads();
    if (t < 64) {
      float d = power_rayleigh(G, Sa, 12, t);
      if (t == 0) lipv[l] = sqrtf(fmaxf(d, 0.f)) + 5.0f;
    }
  }
}

// ---------------------------------------------------------------------------
// h = gelu(fused @ w1n + b1). grid 512 = b*16+ng.
// ---------------------------------------------------------------------------
__global__ __launch_bounds__(256) void h_kernel(
    const float* __restrict__ fused, const float* __restrict__ w1,
    const float* __restrict__ b1, const float* __restrict__ invsig1,
    float* __restrict__ h) {
  __shared__ float fr[256];
  int t = threadIdx.x;
  int blk = blockIdx.x;
  int ng = blk & 15;
  fr[t] = fused[(size_t)blk * 256 + t];
  __syncthreads();
  int nl = t >> 6, j = t & 63;
  int n = ng * 4 + nl;
  float is1 = invsig1[n];
  const float* fp = fr + nl * 64;
  const float* wp = w1 + (size_t)n * 4096 + j;
  float acc = 0.f;
  for (int i = 0; i < 64; i++) acc += fp[i] * wp[i * 64];
  acc = acc * is1 + b1[n * 64 + j];
  float g = 0.5f * acc * (1.0f + erff(acc * 0.70710678118654752440f));
  h[(size_t)blk * 256 + t] = g;
}

// ---------------------------------------------------------------------------
// conv: x[b,d,n0..n0+4) = h @ w2 + b2, float4 store.
// ---------------------------------------------------------------------------
__global__ __launch_bounds__(256) void conv_kernel(
    const float* __restrict__ h, const float* __restrict__ w2,
    const float* __restrict__ b2, const float* __restrict__ invsig2,
    float* __restrict__ x) {
  __shared__ float hr[4][64];
  int t = threadIdx.x;
  int blk = blockIdx.x;
  int b = blk >> 4, ng = blk & 15;
  int n0 = ng * 4;
  {
    int r = t >> 6, i = t & 63;
    hr[r][i] = h[((size_t)b * 64 + n0 + r) * 64 + i];
  }
  __syncthreads();
  const float* w0p = w2 + ((size_t)(n0 + 0) * 64) * 256 + t;
  const float* w1p = w2 + ((size_t)(n0 + 1) * 64) * 256 + t;
  const float* w2p = w2 + ((size_t)(n0 + 2) * 64) * 256 + t;
  const float* w3p = w2 + ((size_t)(n0 + 3) * 64) * 256 + t;
  float a0 = 0.f, a1 = 0.f, a2 = 0.f, a3 = 0.f;
  for (int i = 0; i < 64; i++) {
    a0 += hr[0][i] * w0p[(size_t)i * 256];
    a1 += hr[1][i] * w1p[(size_t)i * 256];
    a2 += hr[2][i] * w2p[(size_t)i * 256];
    a3 += hr[3][i] * w3p[(size_t)i * 256];
  }
  float4 o;
  o.x = a0 * invsig2[n0 + 0] + b2[(n0 + 0) * 256 + t];
  o.y = a1 * invsig2[n0 + 1] + b2[(n0 + 1) * 256 + t];
  o.z = a2 * invsig2[n0 + 2] + b2[(n0 + 2) * 256 + t];
  o.w = a3 * invsig2[n0 + 3] + b2[(n0 + 3) * 256 + t];
  *(float4*)(x + ((size_t)b * 256 + t) * 64 + n0) = o;
}

// ---------------------------------------------------------------------------
// qk v3: grid 1024 = b*32 + c*4 + nq (64-row tile). 3 waves/SIMD resident
// (was 1 -> the whole 57us was unhidden latency). Outputs are the bf16 hi/lo
// split ONLY (fp32 q/k dropped; nr reconstructs from the same split).
// ---------------------------------------------------------------------------
__global__ __launch_bounds__(256, 2) void qk_kernel(
    const float* __restrict__ x, const float* __restrict__ eqk,
    unsigned short* __restrict__ qhi, unsigned short* __restrict__ qlo,
    unsigned short* __restrict__ khi, unsigned short* __restrict__ klo) {
  __shared__ float xL[64 * 64];
  int t = threadIdx.x;
  int blk = blockIdx.x;
  int b = blk >> 5, c = (blk >> 2) & 7, nq = blk & 3;
  int f = t & 63, wv = t >> 6;
  int n0 = nq * 64;
  float wq[64], wk[64];
  const float4* Wq4 = (const float4*)(eqk + ((size_t)(c * 64 + f)) * 64);
  const float4* Wk4 = (const float4*)(eqk + ((size_t)((8 + c) * 64 + f)) * 64);
#pragma unroll
  for (int j = 0; j < 16; j++) {
    float4 aa = Wq4[j];
    wq[4 * j + 0] = aa.x; wq[4 * j + 1] = aa.y; wq[4 * j + 2] = aa.z; wq[4 * j + 3] = aa.w;
    float4 bb = Wk4[j];
    wk[4 * j + 0] = bb.x; wk[4 * j + 1] = bb.y; wk[4 * j + 2] = bb.z; wk[4 * j + 3] = bb.w;
  }
  for (int i = t; i < 1024; i += 256)
    ((float4*)xL)[i] = ((const float4*)(x + ((size_t)b * 256 + n0) * 64))[i];
  __syncthreads();
  for (int i = 0; i < 16; i++) {
    int nl = wv * 16 + i;
    const float4* xr = (const float4*)(xL + nl * 64);
    float aq = 0.f, ak = 0.f;
#pragma unroll
    for (int j = 0; j < 16; j++) {
      float4 v = xr[j];                               // wave-uniform LDS broadcast
      aq += v.x * wq[4 * j] + v.y * wq[4 * j + 1] + v.z * wq[4 * j + 2] + v.w * wq[4 * j + 3];
      ak += v.x * wk[4 * j] + v.y * wk[4 * j + 1] + v.z * wk[4 * j + 2] + v.w * wk[4 * j + 3];
    }
    size_t o = (((size_t)b * 8 + c) * 256 + n0 + nl) * 64 + f;
    unsigned short qh = f2bf(aq);
    qhi[o] = qh;
    qlo[o] = f2bf(aq - bf2f(qh));
    unsigned short kh = f2bf(ak);
    khi[o] = kh;
    klo[o] = f2bf(ak - bf2f(kh));
  }
}

// ---------------------------------------------------------------------------
// Generic slice transpose: in[s][n(256)][f(64)] -> out[s][f(64)][m(256)].
// (loop phase kg only)
// ---------------------------------------------------------------------------
__global__ __launch_bounds__(256, 2) void transpose_kernel(
    const float* __restrict__ in, float* __restrict__ out) {
  __shared__ float T[256 * 65];
  int t = threadIdx.x;
  size_t base = (size_t)blockIdx.x * 16384;
  const float4* in4 = (const float4*)(in + base);
  float4* out4 = (float4*)(out + base);
  for (int i = t; i < 4096; i += 256) {
    int n = i >> 4, fq = i & 15;
    float4 v = in4[i];
    float* dst = T + n * 65 + 4 * fq;
    dst[0] = v.x; dst[1] = v.y; dst[2] = v.z; dst[3] = v.w;
  }
  __syncthreads();
  for (int i = t; i < 4096; i += 256) {
    int f = i >> 6, m4 = i & 63;
    float4 o;
    o.x = T[(4 * m4 + 0) * 65 + f];
    o.y = T[(4 * m4 + 1) * 65 + f];
    o.z = T[(4 * m4 + 2) * 65 + f];
    o.w = T[(4 * m4 + 3) * 65 + f];
    out4[f * 64 + m4] = o;
  }
}

// ---------------------------------------------------------------------------
// Fused attn v6 (R10, proven): MFMA bf16 3-term split.
// ---------------------------------------------------------------------------
__global__ __launch_bounds__(256, 2) void attn_kernel(
    const unsigned short* __restrict__ qhi, const unsigned short* __restrict__ qlo,
    const unsigned short* __restrict__ khi, const unsigned short* __restrict__ klo,
    float* __restrict__ seP, float* __restrict__ mxb, float* __restrict__ rzb) {
  int t = threadIdx.x;
  int blk = blockIdx.x;
  int xcd = blk & 7;
  int b2 = (blk >> 3) & 3;
  int y = blk >> 5;
  int b = xcd * 4 + b2;
  int cg = y >> 2;
  int ng = y & 3;
  int wv = t >> 6, l = t & 63;
  int m16 = l & 15, quad = l >> 4;
  int n0w = ng * 64 + wv * 16;

  f4t sum_acc[16];
#pragma unroll
  for (int mt = 0; mt < 16; mt++) sum_acc[mt] = (f4t){0.f, 0.f, 0.f, 0.f};

  for (int ci = 0; ci < 4; ci++) {
    int c = cg * 4 + ci;
    size_t sl = ((size_t)b * 8 + c) * 16384;
    const bf8t* qh = (const bf8t*)(qhi + sl + (size_t)(n0w + m16) * 64 + quad * 8);
    const bf8t* ql = (const bf8t*)(qlo + sl + (size_t)(n0w + m16) * 64 + quad * 8);
    bf8t ah0 = qh[0], ah1 = qh[4];
    bf8t al0 = ql[0], al1 = ql[4];
    f4t acc[16];
#pragma unroll
    for (int mt = 0; mt < 16; mt++) acc[mt] = (f4t){0.f, 0.f, 0.f, 0.f};
    for (int mt = 0; mt < 16; mt++) {
      const bf8t* kh = (const bf8t*)(khi + sl + (size_t)(mt * 16 + m16) * 64 + quad * 8);
      const bf8t* kl = (const bf8t*)(klo + sl + (size_t)(mt * 16 + m16) * 64 + quad * 8);
      bf8t bh0 = kh[0], bh1 = kh[4];
      bf8t bl0 = kl[0], bl1 = kl[4];
      f4t a = acc[mt];
      a = __builtin_amdgcn_mfma_f32_16x16x32_bf16(al0, bh0, a, 0, 0, 0);
      a = __builtin_amdgcn_mfma_f32_16x16x32_bf16(ah0, bl0, a, 0, 0, 0);
      a = __builtin_amdgcn_mfma_f32_16x16x32_bf16(ah0, bh0, a, 0, 0, 0);
      a = __builtin_amdgcn_mfma_f32_16x16x32_bf16(al1, bh1, a, 0, 0, 0);
      a = __builtin_amdgcn_mfma_f32_16x16x32_bf16(ah1, bl1, a, 0, 0, 0);
      a = __builtin_amdgcn_mfma_f32_16x16x32_bf16(ah1, bh1, a, 0, 0, 0);
      acc[mt] = a;
    }
#pragma unroll
    for (int j = 0; j < 4; j++) {
      float mx = -FLT_MAX;
#pragma unroll
      for (int mt = 0; mt < 16; mt++) mx = fmaxf(mx, acc[mt][j]);
      mx = fmaxf(mx, __shfl_xor(mx, 1, 64));
      mx = fmaxf(mx, __shfl_xor(mx, 2, 64));
      mx = fmaxf(mx, __shfl_xor(mx, 4, 64));
      mx = fmaxf(mx, __shfl_xor(mx, 8, 64));
      float mxl = mx * 0.125f;
      float e[16];
      float z = 0.f;
#pragma unroll
      for (int mt = 0; mt < 16; mt++) {
        e[mt] = expf(acc[mt][j] * 0.125f - mxl);
        z += e[mt];
      }
      z += __shfl_xor(z, 1, 64);
      z += __shfl_xor(z, 2, 64);
      z += __shfl_xor(z, 4, 64);
      z += __shfl_xor(z, 8, 64);
      int n = n0w + quad * 4 + j;
      if (m16 == 0) {
        mxb[((size_t)b * 8 + c) * 256 + n] = mxl;
        rzb[((size_t)b * 8 + c) * 256 + n] = z;
      }
      float zi = 1.0f / z;
#pragma unroll
      for (int mt = 0; mt < 16; mt++) sum_acc[mt][j] += e[mt] * zi;
    }
  }
#pragma unroll
  for (int mt = 0; mt < 16; mt++) {
#pragma unroll
    for (int j = 0; j < 4; j++) {
      int n = n0w + quad * 4 + j;
      seP[((size_t)(cg * 32 + b) * 256 + n) * 256 + mt * 16 + m16] = sum_acc[mt][j];
    }
  }
}

// ---------------------------------------------------------------------------
// Top-6 selection (sums 2 seP partials).
// ---------------------------------------------------------------------------
__global__ __launch_bounds__(256) void topsel_kernel(
    const float* __restrict__ seP, int* __restrict__ idx7) {
  __shared__ float seL[64 * 260];
  __shared__ float cv[64][24];
  __shared__ int cidx[64][24];
  int t = threadIdx.x;
  int b = blockIdx.x >> 2, rg = blockIdx.x & 3;
  int n0 = rg * 64;
  const float* s0 = seP + ((size_t)b * 256 + n0) * 256;
  const float* s1 = seP + ((size_t)(32 + b) * 256 + n0) * 256;
  for (int i = t; i < 4096; i += 256) {
    int m4 = i & 63, r = i >> 6;
    float4 v0 = ((const float4*)(s0 + (size_t)r * 256))[m4];
    float4 v1 = ((const float4*)(s1 + (size_t)r * 256))[m4];
    float4 s;
    s.x = v0.x + v1.x; s.y = v0.y + v1.y; s.z = v0.z + v1.z; s.w = v0.w + v1.w;
    *(float4*)(seL + r * 260 + m4 * 4) = s;
  }
  __syncthreads();
  {
    int r = t >> 2, qtr = t & 3;
    float tv[6]; int ti[6];
#pragma unroll
    for (int s = 0; s < 6; s++) { tv[s] = -FLT_MAX; ti[s] = 1 << 30; }
    for (int i = 0; i < 64; i++) {
      int m = 4 * i + qtr;
      float val = seL[r * 260 + m];
      if (val > tv[5]) {
        tv[5] = val; ti[5] = m;
#pragma unroll
        for (int s = 5; s > 0; s--) {
          if (tv[s] > tv[s - 1]) {
            float tmv = tv[s]; tv[s] = tv[s - 1]; tv[s - 1] = tmv;
            int tmi = ti[s]; ti[s] = ti[s - 1]; ti[s - 1] = tmi;
          }
        }
      }
    }
#pragma unroll
    for (int s = 0; s < 6; s++) { cv[r][qtr * 6 + s] = tv[s]; cidx[r][qtr * 6 + s] = ti[s]; }
  }
  __syncthreads();
  if (t < 64) {
    int r = t, n = n0 + r;
    int sel[7];
    for (int round = 0; round < 6; round++) {
      float best = -FLT_MAX; int bi = 1 << 30, bs = 0;
      for (int j = 0; j < 24; j++) {
        float v = cv[r][j]; int id = cidx[r][j];
        if (v > best || (v == best && id < bi)) { best = v; bi = id; bs = j; }
      }
      sel[round] = bi;
      cv[r][bs] = -FLT_MAX;
    }
    bool dup = false;
#pragma unroll
    for (int j = 0; j < 6; j++) dup = dup || (sel[j] == n);
    sel[6] = dup ? -1 : n;
#pragma unroll
    for (int j = 0; j < 7; j++) idx7[((size_t)b * 256 + n) * 7 + j] = sel[j];
  }
}

// ---------------------------------------------------------------------------
// nr values: recompute <=7 attn entries from the SAME bf16 3-term split used
// by the MFMA attn (consistent with mxb/rzb), row-normalize, atomic colsum.
// ---------------------------------------------------------------------------
__global__ __launch_bounds__(256) void nr_kernel(
    const unsigned short* __restrict__ qhi, const unsigned short* __restrict__ qlo,
    const unsigned short* __restrict__ khi, const unsigned short* __restrict__ klo,
    const float* __restrict__ mxb, const float* __restrict__ rzb,
    const int* __restrict__ idx7, float* __restrict__ nrv,
    float* __restrict__ colsum) {
  __shared__ int idxs[7];
  __shared__ float attL[56];
  int t = threadIdx.x;
  int b = blockIdx.x >> 8, n = blockIdx.x & 255;
  if (t < 7) idxs[t] = idx7[(size_t)blockIdx.x * 7 + t];
  __syncthreads();
  int task = t >> 2, l4 = t & 3;
  if (task < 56) {
    int c = task / 7, j = task - c * 7;
    int d = idxs[j];
    float s = 0.f;
    if (d >= 0) {
      size_t qo = (((size_t)b * 8 + c) * 256 + n) * 64 + l4 * 16;
      size_t ko = (((size_t)b * 8 + c) * 256 + d) * 64 + l4 * 16;
      const uint4* qh4 = (const uint4*)(qhi + qo);
      const uint4* ql4 = (const uint4*)(qlo + qo);
      const uint4* kh4 = (const uint4*)(khi + ko);
      const uint4* kl4 = (const uint4*)(klo + ko);
#pragma unroll
      for (int g = 0; g < 2; g++) {
        uint4 uqh = qh4[g], uql = ql4[g], ukh = kh4[g], ukl = kl4[g];
        s += dot3_pair(uqh.x, uql.x, ukh.x, ukl.x);
        s += dot3_pair(uqh.y, uql.y, ukh.y, ukl.y);
        s += dot3_pair(uqh.z, uql.z, ukh.z, ukl.z);
        s += dot3_pair(uqh.w, uql.w, ukh.w, ukl.w);
      }
    }
    s += __shfl_xor(s, 1, 64);
    s += __shfl_xor(s, 2, 64);
    if (l4 == 0) {
      float att = 0.f;
      if (d >= 0) {
        float logit = s * 0.125f;
        att = expf(logit - mxb[((size_t)b * 8 + c) * 256 + n]) / rzb[((size_t)b * 8 + c) * 256 + n];
      }
      attL[task] = att;
    }
  }
  __syncthreads();
  if (t < 8) {
    float rs = 0.f;
#pragma unroll
    for (int j = 0; j < 7; j++) rs += attL[t * 7 + j];
    float ri = 1.0f / (rs + 1e-6f);
#pragma unroll
    for (int j = 0; j < 7; j++) {
      float nv = attL[t * 7 + j] * ri;
      nrv[(((size_t)b * 8 + t) * 256 + n) * 7 + j] = nv;
      int d = idxs[j];
      if (d >= 0) atomicAdd(&colsum[((size_t)b * 8 + t) * 256 + d], nv);
    }
  }
}

// ---------------------------------------------------------------------------
// edge[b,c,n,m] (bf16): pair-packed LDS, b128 idx/nrv reads.
// ---------------------------------------------------------------------------
__global__ __launch_bounds__(256, 3) void edge_kernel(
    const int* __restrict__ idx7, const float* __restrict__ nrv,
    const float* __restrict__ colsum, unsigned short* __restrict__ edge) {
  __shared__ unsigned short ncT[256 * 64];
  __shared__ short idxL[256 * 8];
  __shared__ float nrvL[256 * 8];
  int t = threadIdx.x;
  int blk = blockIdx.x;
  int b = blk >> 5, c = (blk >> 2) & 7, mq = blk & 3;
  int m0 = mq * 64;
  for (int i = t; i < 8192; i += 256) ((unsigned int*)ncT)[i] = 0u;
  for (int i = t; i < 2048; i += 256) {
    int r = i >> 3, j = i & 7;
    if (j < 7) {
      idxL[i] = (short)idx7[(size_t)b * 1792 + r * 7 + j];
      nrvL[i] = nrv[((size_t)b * 8 + c) * 1792 + r * 7 + j];
    } else {
      idxL[i] = -1;
      nrvL[i] = 0.f;
    }
  }
  __syncthreads();
  for (int i = t; i < 448; i += 256) {
    int mi = i / 7, j = i - mi * 7;
    int m = m0 + mi;
    int d = idxL[m * 8 + j];
    if (d >= 0) {
      float cs = colsum[((size_t)b * 8 + c) * 256 + d];
      ncT[d * 64 + mi] = f2bf(nrvL[m * 8 + j] / (cs + 1e-6f));
    }
  }
  __syncthreads();
  int wv = t >> 6, l = t & 63;
  int half = l >> 5, p = l & 31;
  const unsigned int* ncP = (const unsigned int*)ncT;
  unsigned int* eb = (unsigned int*)(edge + (((size_t)b * 8 + c) * 256) * 256);
  for (int nn = 0; nn < 32; nn++) {
    int n = nn * 8 + wv * 2 + half;
    int4 iv = *(const int4*)(idxL + n * 8);
    float4 w0 = *(const float4*)(nrvL + n * 8);
    float4 w1 = *(const float4*)(nrvL + n * 8 + 4);
    float a0 = 0.f, a1 = 0.f;
    int d;
    unsigned int pr;
    d = (int)(short)(iv.x & 0xFFFF);
    if (d >= 0) { pr = ncP[d * 32 + p]; a0 += w0.x * bf2f_lo(pr); a1 += w0.x * bf2f_hi(pr); }
    d = iv.x >> 16;
    if (d >= 0) { pr = ncP[d * 32 + p]; a0 += w0.y * bf2f_lo(pr); a1 += w0.y * bf2f_hi(pr); }
    d = (int)(short)(iv.y & 0xFFFF);
    if (d >= 0) { pr = ncP[d * 32 + p]; a0 += w0.z * bf2f_lo(pr); a1 += w0.z * bf2f_hi(pr); }
    d = iv.y >> 16;
    if (d >= 0) { pr = ncP[d * 32 + p]; a0 += w0.w * bf2f_lo(pr); a1 += w0.w * bf2f_hi(pr); }
    d = (int)(short)(iv.z & 0xFFFF);
    if (d >= 0) { pr = ncP[d * 32 + p]; a0 += w1.x * bf2f_lo(pr); a1 += w1.x * bf2f_hi(pr); }
    d = iv.z >> 16;
    if (d >= 0) { pr = ncP[d * 32 + p]; a0 += w1.y * bf2f_lo(pr); a1 += w1.y * bf2f_hi(pr); }
    d = (int)(short)(iv.w & 0xFFFF);
    if (d >= 0) { pr = ncP[d * 32 + p]; a0 += w1.z * bf2f_lo(pr); a1 += w1.z * bf2f_hi(pr); }
    unsigned int packo = (unsigned int)f2bf(a0) | ((unsigned int)f2bf(a1) << 16);
    eb[n * 128 + (m0 >> 1) + p] = packo;
  }
}

// ---------------------------------------------------------------------------
// xs = sigmoid(elu(x))
// ---------------------------------------------------------------------------
static __device__ __forceinline__ float selu1(float v) {
  float e = (v > 0.f) ? v : expm1f(v);
  return 1.0f / (1.0f + expf(-e));
}
__global__ __launch_bounds__(256) void xs_kernel(const float* __restrict__ x,
                                                 float* __restrict__ xs) {
  int i = blockIdx.x * 256 + threadIdx.x;
  float4 v = ((const float4*)x)[i];
  float4 o;
  o.x = selu1(v.x); o.y = selu1(v.y); o.z = selu1(v.z); o.w = selu1(v.w);
  ((float4*)xs)[i] = o;
}

// ---------------------------------------------------------------------------
// qg/kg = xs @ W_l^T + b_l  (R7 LDS version, grid 128)
// ---------------------------------------------------------------------------
__global__ __launch_bounds__(256, 1) void qkx_kernel(
    const float* __restrict__ xs, const float* __restrict__ gaw,
    const float* __restrict__ gab, int l, float* __restrict__ qg,
    float* __restrict__ kg) {
  __shared__ float xsL[64 * 64];
  int t = threadIdx.x;
  int b = blockIdx.x >> 2, nt = blockIdx.x & 3;
  int f = t & 63, part = t >> 6;
  float wq[64], wk[64];
  const float4* Wq4 = (const float4*)(gaw + (size_t)l * 8192 + f * 64);
  const float4* Wk4 = (const float4*)(gaw + (size_t)l * 8192 + (64 + f) * 64);
#pragma unroll
  for (int j = 0; j < 16; j++) {
    float4 aa = Wq4[j];
    wq[4 * j + 0] = aa.x; wq[4 * j + 1] = aa.y; wq[4 * j + 2] = aa.z; wq[4 * j + 3] = aa.w;
    float4 bb = Wk4[j];
    wk[4 * j + 0] = bb.x; wk[4 * j + 1] = bb.y; wk[4 * j + 2] = bb.z; wk[4 * j + 3] = bb.w;
  }
  float bq = gab[l * 128 + f], bk = gab[l * 128 + 64 + f];
  for (int i = t; i < 1024; i += 256)
    ((float4*)xsL)[i] = ((const float4*)(xs + ((size_t)b * 256 + nt * 64) * 64))[i];
  __syncthreads();
  for (int i = 0; i < 16; i++) {
    int nl = part * 16 + i;
    const float4* xr = (const float4*)(xsL + nl * 64);
    float aq = 0.f, ak = 0.f;
#pragma unroll
    for (int j = 0; j < 16; j++) {
      float4 v = xr[j];
      aq += v.x * wq[4 * j] + v.y * wq[4 * j + 1] + v.z * wq[4 * j + 2] + v.w * wq[4 * j + 3];
      ak += v.x * wk[4 * j] + v.y * wk[4 * j + 1] + v.z * wk[4 * j + 2] + v.w * wk[4 * j + 3];
    }
    int n = nt * 64 + nl;
    qg[((size_t)b * 256 + n) * 64 + f] = aq + bq;
    kg[((size_t)b * 256 + n) * 64 + f] = ak + bk;
  }
}

// ---------------------------------------------------------------------------
// ga_attn (R7 version): no LDS/barriers; (256,2); grid 256 = b*8+nt.
// ---------------------------------------------------------------------------
__global__ __launch_bounds__(256, 2) void ga_attn_kernel(
    const float* __restrict__ qg, const float* __restrict__ kgT,
    float* __restrict__ a) {
  int t = threadIdx.x;
  int b = blockIdx.x >> 3, nt = blockIdx.x & 7;
  int n0 = nt * 32;
  int wv = t >> 6, l = t & 63;
  const float* kb = kgT + (size_t)b * 16384 + 4 * l;          // [f][m]
  const float* qb = qg + ((size_t)b * 256 + n0 + wv * 8) * 64;
  float acc[8][4];
#pragma unroll
  for (int r = 0; r < 8; r++)
#pragma unroll
    for (int j = 0; j < 4; j++) acc[r][j] = 0.f;
#pragma unroll 4
  for (int kq4 = 0; kq4 < 64; kq4 += 4) {
    float4 kv0 = *(const float4*)(kb + (kq4 + 0) * 256);
    float4 kv1 = *(const float4*)(kb + (kq4 + 1) * 256);
    float4 kv2 = *(const float4*)(kb + (kq4 + 2) * 256);
    float4 kv3 = *(const float4*)(kb + (kq4 + 3) * 256);
#pragma unroll
    for (int r = 0; r < 8; r++) {
      float4 qv = *(const float4*)(qb + r * 64 + kq4);
      acc[r][0] += qv.x * kv0.x + qv.y * kv1.x + qv.z * kv2.x + qv.w * kv3.x;
      acc[r][1] += qv.x * kv0.y + qv.y * kv1.y + qv.z * kv2.y + qv.w * kv3.y;
      acc[r][2] += qv.x * kv0.z + qv.y * kv1.z + qv.z * kv2.z + qv.w * kv3.z;
      acc[r][3] += qv.x * kv0.w + qv.y * kv1.w + qv.z * kv2.w + qv.w * kv3.w;
    }
  }
#pragma unroll
  for (int r = 0; r < 8; r++) {
    float l0 = acc[r][0] * 0.125f, l1 = acc[r][1] * 0.125f;
    float l2 = acc[r][2] * 0.125f, l3 = acc[r][3] * 0.125f;
    float mx = fmaxf(fmaxf(l0, l1), fmaxf(l2, l3));
#pragma unroll
    for (int m = 1; m < 64; m <<= 1) mx = fmaxf(mx, __shfl_xor(mx, m, 64));
    float e0 = expf(l0 - mx), e1 = expf(l1 - mx), e2 = expf(l2 - mx), e3 = expf(l3 - mx);
    float z = e0 + e1 + e2 + e3;
#pragma unroll
    for (int m = 1; m < 64; m <<= 1) z += __shfl_xor(z, m, 64);
    float zi = 1.0f / z;
    int n = n0 + wv * 8 + r;
    float4 o;
    o.x = e0 * zi; o.y = e1 * zi; o.z = e2 * zi; o.w = e3 * zi;
    ((float4*)(a + ((size_t)b * 256 + n) * 256))[l] = o;
  }
}

// ---------------------------------------------------------------------------
// ne normalize + x += (ne3 @ xs)/lip
// ---------------------------------------------------------------------------
__global__ __launch_bounds__(256) void upd_kernel(
    const float* __restrict__ a, const unsigned short* __restrict__ edge,
    const float* __restrict__ xs, const float* __restrict__ gaww,
    const float* __restrict__ lipv, int l, float* __restrict__ x) {
  __shared__ float tt[4][8][256];
  __shared__ float ne3[4][256];
  __shared__ float parts[4][4][64];
  __shared__ float dred[32][8];
  __shared__ float dinv[4][8];
  __shared__ float wcL[8];
  __shared__ float lipi;
  int t = threadIdx.x;
  int b = blockIdx.x >> 6, nq = blockIdx.x & 63;
  int n0 = nq * 4;
  if (t == 0) {
    float s = 0.f;
    float wtmp[8];
    for (int c = 0; c < 8; c++) { wtmp[c] = gaww[l * 8 + c]; s += wtmp[c]; }
    for (int c = 0; c < 8; c++) wcL[c] = wtmp[c] / s;
    lipi = 1.0f / lipv[l];
  }
#pragma unroll
  for (int r = 0; r < 4; r++) {
    float av = a[((size_t)b * 256 + n0 + r) * 256 + t];
#pragma unroll
    for (int c = 0; c < 8; c++)
      tt[r][c][t] = av * bf2f(edge[(((size_t)b * 8 + c) * 256 + n0 + r) * 256 + t]);
  }
  __syncthreads();
  {
    int rc = t >> 3, i = t & 7;
    int r = rc >> 3, c = rc & 7;
    float p = 0.f;
#pragma unroll
    for (int kq = 0; kq < 32; kq++) p += tt[r][c][i + 8 * kq];
    dred[rc][i] = p;
  }
  __syncthreads();
  if (t < 32) {
    float s = 0.f;
#pragma unroll
    for (int i = 0; i < 8; i++) s += dred[t][i];
    dinv[t >> 3][t & 7] = 1.0f / (s + 1e-6f);
  }
  __syncthreads();
#pragma unroll
  for (int r = 0; r < 4; r++) {
    float s = 0.f;
#pragma unroll
    for (int c = 0; c < 8; c++) s += wcL[c] * tt[r][c][t] * dinv[r][c];
    ne3[r][t] = s;
  }
  __syncthreads();
  {
    int f = t & 63, part = t >> 6;
    float a0 = 0.f, a1 = 0.f, a2 = 0.f, a3 = 0.f;
    for (int mm = 0; mm < 64; mm++) {
      int m = part * 64 + mm;
      float xv = xs[((size_t)b * 256 + m) * 64 + f];
      a0 += ne3[0][m] * xv;
      a1 += ne3[1][m] * xv;
      a2 += ne3[2][m] * xv;
      a3 += ne3[3][m] * xv;
    }
    parts[0][part][f] = a0;
    parts[1][part][f] = a1;
    parts[2][part][f] = a2;
    parts[3][part][f] = a3;
  }
  __syncthreads();
  {
    int r = t >> 6, f = t & 63;
    float dx = parts[r][0][f] + parts[r][1][f] + parts[r][2][f] + parts[r][3][f];
    x[((size_t)b * 256 + n0 + r) * 64 + f] += dx * lipi;
  }
}

// ---------------------------------------------------------------------------
extern "C" void kernel_launch(void* const* d_in, const int* in_sizes, int n_in,
                              void* d_out, int out_size, void* d_ws, size_t ws_size,
                              hipStream_t stream) {
  (void)in_sizes; (void)n_in; (void)out_size; (void)ws_size;
  const float* fused = (const float*)d_in[0];
  const float* w1 = (const float*)d_in[1];
  const float* b1 = (const float*)d_in[2];
  const float* w2 = (const float*)d_in[3];
  const float* b2 = (const float*)d_in[4];
  const float* eqk = (const float*)d_in[5];
  const float* gaw = (const float*)d_in[6];
  const float* gab = (const float*)d_in[7];
  const float* gaww = (const float*)d_in[8];
  float* x = (float*)d_out;  // x lives in d_out (B,ND,NF)=(32,256,64); fully overwritten.
  char* ws = (char*)d_ws;
  size_t off = 0;
  auto alloc = [&](size_t bytes) -> char* {
    char* p = ws + off;
    off += (bytes + 1023) & ~(size_t)1023;
    return p;
  };
  float* invsig1 = (float*)alloc(64 * 4);
  float* invsig2 = (float*)alloc(64 * 4);
  float* lipv = (float*)alloc(2 * 4);
  float* h = (float*)alloc((size_t)32 * 64 * 64 * 4);
  unsigned short* qhi = (unsigned short*)alloc((size_t)32 * 8 * 256 * 64 * 2);
  unsigned short* qlo = (unsigned short*)alloc((size_t)32 * 8 * 256 * 64 * 2);
  unsigned short* khi = (unsigned short*)alloc((size_t)32 * 8 * 256 * 64 * 2);
  unsigned short* klo = (unsigned short*)alloc((size_t)32 * 8 * 256 * 64 * 2);
  // seP (2 partials, 16.8 MB) aliases edge (33.6 MB): seP dead after topsel.
  char* sep_edge = alloc((size_t)4 * 32 * 256 * 256 * 4);
  float* seP = (float*)sep_edge;
  unsigned short* edge = (unsigned short*)sep_edge;
  float* mxb = (float*)alloc((size_t)65536 * 4);
  float* rzb = (float*)alloc((size_t)65536 * 4);
  int* idx7 = (int*)alloc((size_t)8192 * 7 * 4);
  float* nrv = (float*)alloc((size_t)65536 * 7 * 4);
  float* colsum = (float*)alloc((size_t)65536 * 4);
  float* xs = (float*)alloc((size_t)524288 * 4);
  float* qg = (float*)alloc((size_t)524288 * 4);
  float* kg = (float*)alloc((size_t)524288 * 4);
  float* a = (float*)alloc((size_t)32 * 256 * 256 * 4);
  float* kgT = (float*)alloc((size_t)524288 * 4);

  speclip_kernel<<<130, 256, 0, stream>>>(w1, w2, gaw, invsig1, invsig2, lipv);
  h_kernel<<<512, 256, 0, stream>>>(fused, w1, b1, invsig1, h);
  conv_kernel<<<512, 256, 0, stream>>>(h, w2, b2, invsig2, x);
  qk_kernel<<<1024, 256, 0, stream>>>(x, eqk, qhi, qlo, khi, klo);
  attn_kernel<<<256, 256, 0, stream>>>(qhi, qlo, khi, klo, seP, mxb, rzb);
  hipMemsetAsync(colsum, 0, (size_t)65536 * 4, stream);
  topsel_kernel<<<128, 256, 0, stream>>>(seP, idx7);
  nr_kernel<<<8192, 256, 0, stream>>>(qhi, qlo, khi, klo, mxb, rzb, idx7, nrv, colsum);
  edge_kernel<<<1024, 256, 0, stream>>>(idx7, nrv, colsum, edge);
  for (int l = 0; l < 2; l++) {
    xs_kernel<<<512, 256, 0, stream>>>(x, xs);
    qkx_kernel<<<128, 256, 0, stream>>>(xs, gaw, gab, l, qg, kg);
    transpose_kernel<<<32, 256, 0, stream>>>(kg, kgT);
    ga_attn_kernel<<<256, 256, 0, stream>>>(qg, kgT, a);
    upd_kernel<<<2048, 256, 0, stream>>>(a, edge, xs, gaww, lipv, l, x);
  }
}

// Round 12
// 454.808 us; speedup vs baseline: 1.1781x; 1.1781x over previous
//
#include <hip/hip_runtime.h>
#include <float.h>
#include <math.h>

// Problem constants: B=32, NF=64, FD=64, ND=256, C=8, K=6, L=2, scale=1/8.

typedef short bf8t __attribute__((ext_vector_type(8)));   // 8 bf16 in 4 VGPRs
typedef float f4t __attribute__((ext_vector_type(4)));

static __device__ __forceinline__ unsigned short f2bf(float x) {
  union { float f; unsigned u; } v; v.f = x;
  unsigned r = (v.u + 0x7FFFu + ((v.u >> 16) & 1u)) >> 16;
  return (unsigned short)r;
}
static __device__ __forceinline__ float bf2f(unsigned short s) {
  union { unsigned u; float f; } v; v.u = ((unsigned)s) << 16; return v.f;
}
static __device__ __forceinline__ float bf2f_lo(unsigned u) {
  union { unsigned u; float f; } v; v.u = u << 16; return v.f;
}
static __device__ __forceinline__ float bf2f_hi(unsigned u) {
  union { unsigned u; float f; } v; v.u = u & 0xFFFF0000u; return v.f;
}
// 2 packed elems of the 3-term split dot: qh*(kh+kl) + ql*kh
static __device__ __forceinline__ float dot3_pair(unsigned uqh, unsigned uql,
                                                  unsigned ukh, unsigned ukl) {
  float s = bf2f_lo(uqh) * (bf2f_lo(ukh) + bf2f_lo(ukl)) + bf2f_lo(uql) * bf2f_lo(ukh);
  s += bf2f_hi(uqh) * (bf2f_hi(ukh) + bf2f_hi(ukl)) + bf2f_hi(uql) * bf2f_hi(ukh);
  return s;
}
// split 8 fp32 into hi/lo bf16 fragments
static __device__ __forceinline__ void split8(const float* __restrict__ p,
                                              bf8t* hi, bf8t* lo) {
  float4 v0 = *(const float4*)(p);
  float4 v1 = *(const float4*)(p + 4);
  float v[8] = {v0.x, v0.y, v0.z, v0.w, v1.x, v1.y, v1.z, v1.w};
#pragma unroll
  for (int j = 0; j < 8; j++) {
    unsigned short h = f2bf(v[j]);
    (*hi)[j] = (short)h;
    (*lo)[j] = (short)f2bf(v[j] - bf2f(h));
  }
}

// ---------------------------------------------------------------------------
// Cooperative 64x64 row-row matmul (LDS stride 65, 4x4 register tile).
// ---------------------------------------------------------------------------
static __device__ __forceinline__ void mm_rr(
    const float* __restrict__ A, const float* __restrict__ B,
    float* __restrict__ C, int t, float scale, int addI, int transposeStore) {
  int tr = t >> 4, tc = t & 15;
  float acc[4][4];
#pragma unroll
  for (int j = 0; j < 4; j++)
#pragma unroll
    for (int jj = 0; jj < 4; jj++) acc[j][jj] = 0.f;
  const float* Ap = A + (4 * tr) * 65;
  const float* Bp = B + (4 * tc) * 65;
  for (int k = 0; k < 64; k++) {
    float a0 = Ap[k], a1 = Ap[65 + k], a2 = Ap[130 + k], a3 = Ap[195 + k];
    float b0 = Bp[k], b1 = Bp[65 + k], b2 = Bp[130 + k], b3 = Bp[195 + k];
    acc[0][0] += a0 * b0; acc[0][1] += a0 * b1; acc[0][2] += a0 * b2; acc[0][3] += a0 * b3;
    acc[1][0] += a1 * b0; acc[1][1] += a1 * b1; acc[1][2] += a1 * b2; acc[1][3] += a1 * b3;
    acc[2][0] += a2 * b0; acc[2][1] += a2 * b1; acc[2][2] += a2 * b2; acc[2][3] += a2 * b3;
    acc[3][0] += a3 * b0; acc[3][1] += a3 * b1; acc[3][2] += a3 * b2; acc[3][3] += a3 * b3;
  }
#pragma unroll
  for (int j = 0; j < 4; j++)
#pragma unroll
    for (int jj = 0; jj < 4; jj++) {
      int i0 = 4 * tr + j, j0 = 4 * tc + jj;
      float v = acc[j][jj] * scale + ((addI && i0 == j0) ? 1.0f : 0.0f);
      if (transposeStore) C[j0 * 65 + i0] = v; else C[i0 * 65 + j0] = v;
    }
}

// Gram: G = A_glob * A_glob^T (A_glob is 64 x ncols, row-major), staged in S.
static __device__ __forceinline__ void gram(
    const float* __restrict__ Ag, int ncols, float* __restrict__ S,
    float* __restrict__ G, int t) {
  int tr = t >> 4, tc = t & 15;
  float acc[4][4];
#pragma unroll
  for (int j = 0; j < 4; j++)
#pragma unroll
    for (int jj = 0; jj < 4; jj++) acc[j][jj] = 0.f;
  for (int cc = 0; cc < ncols; cc += 64) {
    if (cc) __syncthreads();
    for (int i = t; i < 1024; i += 256) {
      int r = i >> 4, qq = i & 15;
      float4 v = *(const float4*)(Ag + (size_t)r * ncols + cc + 4 * qq);
      float* dst = S + r * 65 + 4 * qq;
      dst[0] = v.x; dst[1] = v.y; dst[2] = v.z; dst[3] = v.w;
    }
    __syncthreads();
    const float* Ap = S + (4 * tr) * 65;
    const float* Bp = S + (4 * tc) * 65;
    for (int k = 0; k < 64; k++) {
      float a0 = Ap[k], a1 = Ap[65 + k], a2 = Ap[130 + k], a3 = Ap[195 + k];
      float b0 = Bp[k], b1 = Bp[65 + k], b2 = Bp[130 + k], b3 = Bp[195 + k];
      acc[0][0] += a0 * b0; acc[0][1] += a0 * b1; acc[0][2] += a0 * b2; acc[0][3] += a0 * b3;
      acc[1][0] += a1 * b0; acc[1][1] += a1 * b1; acc[1][2] += a1 * b2; acc[1][3] += a1 * b3;
      acc[2][0] += a2 * b0; acc[2][1] += a2 * b1; acc[2][2] += a2 * b2; acc[2][3] += a2 * b3;
      acc[3][0] += a3 * b0; acc[3][1] += a3 * b1; acc[3][2] += a3 * b2; acc[3][3] += a3 * b3;
    }
  }
  __syncthreads();
#pragma unroll
  for (int j = 0; j < 4; j++)
#pragma unroll
    for (int jj = 0; jj < 4; jj++) G[(4 * tr + j) * 65 + (4 * tc + jj)] = acc[j][jj];
}

// Single-wave power iteration + Rayleigh on Gm (caller gates t < 64).
static __device__ __forceinline__ float power_rayleigh(
    const float* __restrict__ G4m, const float* __restrict__ Gm, int iters, int i) {
  float row[64];
#pragma unroll
  for (int j = 0; j < 64; j++) row[j] = G4m[i * 65 + j];
  float v = 1.0f + 0.3f * sinf(7.0f * (float)(i + 1));
  for (int it = 0; it < iters; it++) {
    float u = 0.f;
#pragma unroll
    for (int j = 0; j < 64; j++) u += row[j] * __shfl(v, j, 64);
    float ss = u * u;
#pragma unroll
    for (int m = 1; m < 64; m <<= 1) ss += __shfl_xor(ss, m, 64);
    v = u * rsqrtf(fmaxf(ss, 1e-30f));
  }
  float rowg[64];
#pragma unroll
  for (int j = 0; j < 64; j++) rowg[j] = Gm[i * 65 + j];
  float u = 0.f;
#pragma unroll
  for (int j = 0; j < 64; j++) u += rowg[j] * __shfl(v, j, 64);
  float d = v * u;
#pragma unroll
  for (int m = 1; m < 64; m <<= 1) d += __shfl_xor(d, m, 64);
  return d;
}

// ---------------------------------------------------------------------------
// Fused spectral norms + lip: grid 130.
// ---------------------------------------------------------------------------
__global__ __launch_bounds__(256) void speclip_kernel(
    const float* __restrict__ w1, const float* __restrict__ w2,
    const float* __restrict__ gaw, float* __restrict__ invsig1,
    float* __restrict__ invsig2, float* __restrict__ lipv) {
  __shared__ float Sa[64 * 65];
  __shared__ float Sb[64 * 65];
  __shared__ float G[64 * 65];
  int t = threadIdx.x;
  int blk = blockIdx.x;
  if (blk < 128) {
    int n = blk & 63;
    const float* A = (blk < 64) ? (w1 + (size_t)n * 4096) : (w2 + (size_t)n * 16384);
    int ncols = (blk < 64) ? 64 : 256;
    gram(A, ncols, Sa, G, t);
    __syncthreads();
    mm_rr(G, G, Sa, t, 1.f, 0, 0);
    __syncthreads();
    mm_rr(Sa, Sa, Sb, t, 1.f, 0, 0);
    __syncthreads();
    if (t < 64) {
      float d = power_rayleigh(Sb, G, 30, t);
      if (t == 0) {
        float sg = sqrtf(fmaxf(d, 0.f));
        float inv = 1.0f / fmaxf(sg, 1e-6f);
        if (blk < 64) invsig1[n] = inv; else invsig2[n] = inv;
      }
    }
  } else {
    int l = blk - 128;
    const float* Wb = gaw + (size_t)l * 8192;
    for (int i = t; i < 1024; i += 256) {
      int r = i >> 4, qq = i & 15;
      float4 vq = *(const float4*)(Wb + r * 64 + 4 * qq);
      float4 vk = *(const float4*)(Wb + 4096 + r * 64 + 4 * qq);
      float* dq = Sa + r * 65 + 4 * qq;
      dq[0] = vq.x; dq[1] = vq.y; dq[2] = vq.z; dq[3] = vq.w;
      float* dk = Sb + r * 65 + 4 * qq;
      dk[0] = vk.x; dk[1] = vk.y; dk[2] = vk.z; dk[3] = vk.w;
    }
    __syncthreads();
    mm_rr(Sa, Sb, G, t, 0.25f, 1, 1);
    __syncthreads();
    mm_rr(G, G, Sa, t, 1.f, 0, 0);
    __syncthreads();
    mm_rr(Sa, Sa, Sb, t, 1.f, 0, 0);
    __syncthreads();
    mm_rr(Sb, Sb, G, t, 1.f, 0, 0);
    __syncthreads();
    if (t < 64) {
      float d = power_rayleigh(G, Sa, 12, t);
      if (t == 0) lipv[l] = sqrtf(fmaxf(d, 0.f)) + 5.0f;
    }
  }
}

// ---------------------------------------------------------------------------
// h = gelu(fused @ w1n + b1). grid 512 = b*16+ng.
// ---------------------------------------------------------------------------
__global__ __launch_bounds__(256) void h_kernel(
    const float* __restrict__ fused, const float* __restrict__ w1,
    const float* __restrict__ b1, const float* __restrict__ invsig1,
    float* __restrict__ h) {
  __shared__ float fr[256];
  int t = threadIdx.x;
  int blk = blockIdx.x;
  int ng = blk & 15;
  fr[t] = fused[(size_t)blk * 256 + t];
  __syncthreads();
  int nl = t >> 6, j = t & 63;
  int n = ng * 4 + nl;
  float is1 = invsig1[n];
  const float* fp = fr + nl * 64;
  const float* wp = w1 + (size_t)n * 4096 + j;
  float acc = 0.f;
  for (int i = 0; i < 64; i++) acc += fp[i] * wp[i * 64];
  acc = acc * is1 + b1[n * 64 + j];
  float g = 0.5f * acc * (1.0f + erff(acc * 0.70710678118654752440f));
  h[(size_t)blk * 256 + t] = g;
}

// ---------------------------------------------------------------------------
// conv: x[b,d,n0..n0+4) = h @ w2 + b2, float4 store.
// ---------------------------------------------------------------------------
__global__ __launch_bounds__(256) void conv_kernel(
    const float* __restrict__ h, const float* __restrict__ w2,
    const float* __restrict__ b2, const float* __restrict__ invsig2,
    float* __restrict__ x) {
  __shared__ float hr[4][64];
  int t = threadIdx.x;
  int blk = blockIdx.x;
  int b = blk >> 4, ng = blk & 15;
  int n0 = ng * 4;
  {
    int r = t >> 6, i = t & 63;
    hr[r][i] = h[((size_t)b * 64 + n0 + r) * 64 + i];
  }
  __syncthreads();
  const float* w0p = w2 + ((size_t)(n0 + 0) * 64) * 256 + t;
  const float* w1p = w2 + ((size_t)(n0 + 1) * 64) * 256 + t;
  const float* w2p = w2 + ((size_t)(n0 + 2) * 64) * 256 + t;
  const float* w3p = w2 + ((size_t)(n0 + 3) * 64) * 256 + t;
  float a0 = 0.f, a1 = 0.f, a2 = 0.f, a3 = 0.f;
  for (int i = 0; i < 64; i++) {
    a0 += hr[0][i] * w0p[(size_t)i * 256];
    a1 += hr[1][i] * w1p[(size_t)i * 256];
    a2 += hr[2][i] * w2p[(size_t)i * 256];
    a3 += hr[3][i] * w3p[(size_t)i * 256];
  }
  float4 o;
  o.x = a0 * invsig2[n0 + 0] + b2[(n0 + 0) * 256 + t];
  o.y = a1 * invsig2[n0 + 1] + b2[(n0 + 1) * 256 + t];
  o.z = a2 * invsig2[n0 + 2] + b2[(n0 + 2) * 256 + t];
  o.w = a3 * invsig2[n0 + 3] + b2[(n0 + 3) * 256 + t];
  *(float4*)(x + ((size_t)b * 256 + t) * 64 + n0) = o;
}

// ---------------------------------------------------------------------------
// qk v4: MFMA bf16 3-term split (same scheme as attn, proven R10).
// grid 512 XCD-swizzled: xcd=blk&7; y=blk>>3; rh=y&1; c=(y>>1)&7; b=(y>>4)*8+xcd.
// Block covers rows rh*128..+128 for one (b,c). Wave: 32 rows (2 row-tiles)
// x 64 f (4 col-tiles) x {q,k}. A = x rows, B = W rows (both k-inner, no
// transpose). Output re-split to bf16 hi/lo (what attn/nr consume).
// ---------------------------------------------------------------------------
__global__ __launch_bounds__(256, 2) void qk_kernel(
    const float* __restrict__ x, const float* __restrict__ eqk,
    unsigned short* __restrict__ qhi, unsigned short* __restrict__ qlo,
    unsigned short* __restrict__ khi, unsigned short* __restrict__ klo) {
  int t = threadIdx.x;
  int blk = blockIdx.x;
  int xcd = blk & 7;
  int y = blk >> 3;
  int rh = y & 1;
  int c = (y >> 1) & 7;
  int b = (y >> 4) * 8 + xcd;
  int wv = t >> 6, l = t & 63;
  int m16 = l & 15, quad = l >> 4;
  int row0 = rh * 128 + wv * 32;

  // A fragments: x rows (fp32 -> hi/lo bf16 in-register)
  bf8t ah[2][2], al[2][2];
#pragma unroll
  for (int rt = 0; rt < 2; rt++) {
    const float* xp = x + ((size_t)b * 256 + row0 + rt * 16 + m16) * 64 + quad * 8;
    split8(xp, &ah[rt][0], &al[rt][0]);
    split8(xp + 32, &ah[rt][1], &al[rt][1]);
  }
#pragma unroll
  for (int mat = 0; mat < 2; mat++) {
    const float* Wbase = eqk + ((size_t)(mat * 8 + c) * 64) * 64;
    unsigned short* ohi = mat ? khi : qhi;
    unsigned short* olo = mat ? klo : qlo;
#pragma unroll
    for (int ct = 0; ct < 4; ct++) {
      bf8t bh[2], bl[2];
      const float* wp = Wbase + (size_t)(ct * 16 + m16) * 64 + quad * 8;
      split8(wp, &bh[0], &bl[0]);
      split8(wp + 32, &bh[1], &bl[1]);
#pragma unroll
      for (int rt = 0; rt < 2; rt++) {
        f4t a = (f4t){0.f, 0.f, 0.f, 0.f};
        a = __builtin_amdgcn_mfma_f32_16x16x32_bf16(al[rt][0], bh[0], a, 0, 0, 0);
        a = __builtin_amdgcn_mfma_f32_16x16x32_bf16(ah[rt][0], bl[0], a, 0, 0, 0);
        a = __builtin_amdgcn_mfma_f32_16x16x32_bf16(ah[rt][0], bh[0], a, 0, 0, 0);
        a = __builtin_amdgcn_mfma_f32_16x16x32_bf16(al[rt][1], bh[1], a, 0, 0, 0);
        a = __builtin_amdgcn_mfma_f32_16x16x32_bf16(ah[rt][1], bl[1], a, 0, 0, 0);
        a = __builtin_amdgcn_mfma_f32_16x16x32_bf16(ah[rt][1], bh[1], a, 0, 0, 0);
#pragma unroll
        for (int j = 0; j < 4; j++) {
          int n = row0 + rt * 16 + quad * 4 + j;
          int f = ct * 16 + m16;
          size_t o = (((size_t)b * 8 + c) * 256 + n) * 64 + f;
          float v = a[j];
          unsigned short h = f2bf(v);
          ohi[o] = h;
          olo[o] = f2bf(v - bf2f(h));
        }
      }
    }
  }
}

// ---------------------------------------------------------------------------
// Generic slice transpose: in[s][n(256)][f(64)] -> out[s][f(64)][m(256)].
// (loop phase kg only)
// ---------------------------------------------------------------------------
__global__ __launch_bounds__(256, 2) void transpose_kernel(
    const float* __restrict__ in, float* __restrict__ out) {
  __shared__ float T[256 * 65];
  int t = threadIdx.x;
  size_t base = (size_t)blockIdx.x * 16384;
  const float4* in4 = (const float4*)(in + base);
  float4* out4 = (float4*)(out + base);
  for (int i = t; i < 4096; i += 256) {
    int n = i >> 4, fq = i & 15;
    float4 v = in4[i];
    float* dst = T + n * 65 + 4 * fq;
    dst[0] = v.x; dst[1] = v.y; dst[2] = v.z; dst[3] = v.w;
  }
  __syncthreads();
  for (int i = t; i < 4096; i += 256) {
    int f = i >> 6, m4 = i & 63;
    float4 o;
    o.x = T[(4 * m4 + 0) * 65 + f];
    o.y = T[(4 * m4 + 1) * 65 + f];
    o.z = T[(4 * m4 + 2) * 65 + f];
    o.w = T[(4 * m4 + 3) * 65 + f];
    out4[f * 64 + m4] = o;
  }
}

// ---------------------------------------------------------------------------
// Fused attn v6 (R10, proven): MFMA bf16 3-term split.
// ---------------------------------------------------------------------------
__global__ __launch_bounds__(256, 2) void attn_kernel(
    const unsigned short* __restrict__ qhi, const unsigned short* __restrict__ qlo,
    const unsigned short* __restrict__ khi, const unsigned short* __restrict__ klo,
    float* __restrict__ seP, float* __restrict__ mxb, float* __restrict__ rzb) {
  int t = threadIdx.x;
  int blk = blockIdx.x;
  int xcd = blk & 7;
  int b2 = (blk >> 3) & 3;
  int y = blk >> 5;
  int b = xcd * 4 + b2;
  int cg = y >> 2;
  int ng = y & 3;
  int wv = t >> 6, l = t & 63;
  int m16 = l & 15, quad = l >> 4;
  int n0w = ng * 64 + wv * 16;

  f4t sum_acc[16];
#pragma unroll
  for (int mt = 0; mt < 16; mt++) sum_acc[mt] = (f4t){0.f, 0.f, 0.f, 0.f};

  for (int ci = 0; ci < 4; ci++) {
    int c = cg * 4 + ci;
    size_t sl = ((size_t)b * 8 + c) * 16384;
    const bf8t* qh = (const bf8t*)(qhi + sl + (size_t)(n0w + m16) * 64 + quad * 8);
    const bf8t* ql = (const bf8t*)(qlo + sl + (size_t)(n0w + m16) * 64 + quad * 8);
    bf8t ah0 = qh[0], ah1 = qh[4];
    bf8t al0 = ql[0], al1 = ql[4];
    f4t acc[16];
#pragma unroll
    for (int mt = 0; mt < 16; mt++) acc[mt] = (f4t){0.f, 0.f, 0.f, 0.f};
    for (int mt = 0; mt < 16; mt++) {
      const bf8t* kh = (const bf8t*)(khi + sl + (size_t)(mt * 16 + m16) * 64 + quad * 8);
      const bf8t* kl = (const bf8t*)(klo + sl + (size_t)(mt * 16 + m16) * 64 + quad * 8);
      bf8t bh0 = kh[0], bh1 = kh[4];
      bf8t bl0 = kl[0], bl1 = kl[4];
      f4t a = acc[mt];
      a = __builtin_amdgcn_mfma_f32_16x16x32_bf16(al0, bh0, a, 0, 0, 0);
      a = __builtin_amdgcn_mfma_f32_16x16x32_bf16(ah0, bl0, a, 0, 0, 0);
      a = __builtin_amdgcn_mfma_f32_16x16x32_bf16(ah0, bh0, a, 0, 0, 0);
      a = __builtin_amdgcn_mfma_f32_16x16x32_bf16(al1, bh1, a, 0, 0, 0);
      a = __builtin_amdgcn_mfma_f32_16x16x32_bf16(ah1, bl1, a, 0, 0, 0);
      a = __builtin_amdgcn_mfma_f32_16x16x32_bf16(ah1, bh1, a, 0, 0, 0);
      acc[mt] = a;
    }
#pragma unroll
    for (int j = 0; j < 4; j++) {
      float mx = -FLT_MAX;
#pragma unroll
      for (int mt = 0; mt < 16; mt++) mx = fmaxf(mx, acc[mt][j]);
      mx = fmaxf(mx, __shfl_xor(mx, 1, 64));
      mx = fmaxf(mx, __shfl_xor(mx, 2, 64));
      mx = fmaxf(mx, __shfl_xor(mx, 4, 64));
      mx = fmaxf(mx, __shfl_xor(mx, 8, 64));
      float mxl = mx * 0.125f;
      float e[16];
      float z = 0.f;
#pragma unroll
      for (int mt = 0; mt < 16; mt++) {
        e[mt] = expf(acc[mt][j] * 0.125f - mxl);
        z += e[mt];
      }
      z += __shfl_xor(z, 1, 64);
      z += __shfl_xor(z, 2, 64);
      z += __shfl_xor(z, 4, 64);
      z += __shfl_xor(z, 8, 64);
      int n = n0w + quad * 4 + j;
      if (m16 == 0) {
        mxb[((size_t)b * 8 + c) * 256 + n] = mxl;
        rzb[((size_t)b * 8 + c) * 256 + n] = z;
      }
      float zi = 1.0f / z;
#pragma unroll
      for (int mt = 0; mt < 16; mt++) sum_acc[mt][j] += e[mt] * zi;
    }
  }
#pragma unroll
  for (int mt = 0; mt < 16; mt++) {
#pragma unroll
    for (int j = 0; j < 4; j++) {
      int n = n0w + quad * 4 + j;
      seP[((size_t)(cg * 32 + b) * 256 + n) * 256 + mt * 16 + m16] = sum_acc[mt][j];
    }
  }
}

// ---------------------------------------------------------------------------
// Top-6 selection (sums 2 seP partials).
// ---------------------------------------------------------------------------
__global__ __launch_bounds__(256) void topsel_kernel(
    const float* __restrict__ seP, int* __restrict__ idx7) {
  __shared__ float seL[64 * 260];
  __shared__ float cv[64][24];
  __shared__ int cidx[64][24];
  int t = threadIdx.x;
  int b = blockIdx.x >> 2, rg = blockIdx.x & 3;
  int n0 = rg * 64;
  const float* s0 = seP + ((size_t)b * 256 + n0) * 256;
  const float* s1 = seP + ((size_t)(32 + b) * 256 + n0) * 256;
  for (int i = t; i < 4096; i += 256) {
    int m4 = i & 63, r = i >> 6;
    float4 v0 = ((const float4*)(s0 + (size_t)r * 256))[m4];
    float4 v1 = ((const float4*)(s1 + (size_t)r * 256))[m4];
    float4 s;
    s.x = v0.x + v1.x; s.y = v0.y + v1.y; s.z = v0.z + v1.z; s.w = v0.w + v1.w;
    *(float4*)(seL + r * 260 + m4 * 4) = s;
  }
  __syncthreads();
  {
    int r = t >> 2, qtr = t & 3;
    float tv[6]; int ti[6];
#pragma unroll
    for (int s = 0; s < 6; s++) { tv[s] = -FLT_MAX; ti[s] = 1 << 30; }
    for (int i = 0; i < 64; i++) {
      int m = 4 * i + qtr;
      float val = seL[r * 260 + m];
      if (val > tv[5]) {
        tv[5] = val; ti[5] = m;
#pragma unroll
        for (int s = 5; s > 0; s--) {
          if (tv[s] > tv[s - 1]) {
            float tmv = tv[s]; tv[s] = tv[s - 1]; tv[s - 1] = tmv;
            int tmi = ti[s]; ti[s] = ti[s - 1]; ti[s - 1] = tmi;
          }
        }
      }
    }
#pragma unroll
    for (int s = 0; s < 6; s++) { cv[r][qtr * 6 + s] = tv[s]; cidx[r][qtr * 6 + s] = ti[s]; }
  }
  __syncthreads();
  if (t < 64) {
    int r = t, n = n0 + r;
    int sel[7];
    for (int round = 0; round < 6; round++) {
      float best = -FLT_MAX; int bi = 1 << 30, bs = 0;
      for (int j = 0; j < 24; j++) {
        float v = cv[r][j]; int id = cidx[r][j];
        if (v > best || (v == best && id < bi)) { best = v; bi = id; bs = j; }
      }
      sel[round] = bi;
      cv[r][bs] = -FLT_MAX;
    }
    bool dup = false;
#pragma unroll
    for (int j = 0; j < 6; j++) dup = dup || (sel[j] == n);
    sel[6] = dup ? -1 : n;
#pragma unroll
    for (int j = 0; j < 7; j++) idx7[((size_t)b * 256 + n) * 7 + j] = sel[j];
  }
}

// ---------------------------------------------------------------------------
// nr values: recompute <=7 attn entries from the stored bf16 3-term split
// (consistent with attn's mxb/rzb), row-normalize, atomic colsum.
// ---------------------------------------------------------------------------
__global__ __launch_bounds__(256) void nr_kernel(
    const unsigned short* __restrict__ qhi, const unsigned short* __restrict__ qlo,
    const unsigned short* __restrict__ khi, const unsigned short* __restrict__ klo,
    const float* __restrict__ mxb, const float* __restrict__ rzb,
    const int* __restrict__ idx7, float* __restrict__ nrv,
    float* __restrict__ colsum) {
  __shared__ int idxs[7];
  __shared__ float attL[56];
  int t = threadIdx.x;
  int b = blockIdx.x >> 8, n = blockIdx.x & 255;
  if (t < 7) idxs[t] = idx7[(size_t)blockIdx.x * 7 + t];
  __syncthreads();
  int task = t >> 2, l4 = t & 3;
  if (task < 56) {
    int c = task / 7, j = task - c * 7;
    int d = idxs[j];
    float s = 0.f;
    if (d >= 0) {
      size_t qo = (((size_t)b * 8 + c) * 256 + n) * 64 + l4 * 16;
      size_t ko = (((size_t)b * 8 + c) * 256 + d) * 64 + l4 * 16;
      const uint4* qh4 = (const uint4*)(qhi + qo);
      const uint4* ql4 = (const uint4*)(qlo + qo);
      const uint4* kh4 = (const uint4*)(khi + ko);
      const uint4* kl4 = (const uint4*)(klo + ko);
#pragma unroll
      for (int g = 0; g < 2; g++) {
        uint4 uqh = qh4[g], uql = ql4[g], ukh = kh4[g], ukl = kl4[g];
        s += dot3_pair(uqh.x, uql.x, ukh.x, ukl.x);
        s += dot3_pair(uqh.y, uql.y, ukh.y, ukl.y);
        s += dot3_pair(uqh.z, uql.z, ukh.z, ukl.z);
        s += dot3_pair(uqh.w, uql.w, ukh.w, ukl.w);
      }
    }
    s += __shfl_xor(s, 1, 64);
    s += __shfl_xor(s, 2, 64);
    if (l4 == 0) {
      float att = 0.f;
      if (d >= 0) {
        float logit = s * 0.125f;
        att = expf(logit - mxb[((size_t)b * 8 + c) * 256 + n]) / rzb[((size_t)b * 8 + c) * 256 + n];
      }
      attL[task] = att;
    }
  }
  __syncthreads();
  if (t < 8) {
    float rs = 0.f;
#pragma unroll
    for (int j = 0; j < 7; j++) rs += attL[t * 7 + j];
    float ri = 1.0f / (rs + 1e-6f);
#pragma unroll
    for (int j = 0; j < 7; j++) {
      float nv = attL[t * 7 + j] * ri;
      nrv[(((size_t)b * 8 + t) * 256 + n) * 7 + j] = nv;
      int d = idxs[j];
      if (d >= 0) atomicAdd(&colsum[((size_t)b * 8 + t) * 256 + d], nv);
    }
  }
}

// ---------------------------------------------------------------------------
// edge[b,c,n,m] (bf16): pair-packed LDS, b128 idx/nrv reads.
// ---------------------------------------------------------------------------
__global__ __launch_bounds__(256, 3) void edge_kernel(
    const int* __restrict__ idx7, const float* __restrict__ nrv,
    const float* __restrict__ colsum, unsigned short* __restrict__ edge) {
  __shared__ unsigned short ncT[256 * 64];
  __shared__ short idxL[256 * 8];
  __shared__ float nrvL[256 * 8];
  int t = threadIdx.x;
  int blk = blockIdx.x;
  int b = blk >> 5, c = (blk >> 2) & 7, mq = blk & 3;
  int m0 = mq * 64;
  for (int i = t; i < 8192; i += 256) ((unsigned int*)ncT)[i] = 0u;
  for (int i = t; i < 2048; i += 256) {
    int r = i >> 3, j = i & 7;
    if (j < 7) {
      idxL[i] = (short)idx7[(size_t)b * 1792 + r * 7 + j];
      nrvL[i] = nrv[((size_t)b * 8 + c) * 1792 + r * 7 + j];
    } else {
      idxL[i] = -1;
      nrvL[i] = 0.f;
    }
  }
  __syncthreads();
  for (int i = t; i < 448; i += 256) {
    int mi = i / 7, j = i - mi * 7;
    int m = m0 + mi;
    int d = idxL[m * 8 + j];
    if (d >= 0) {
      float cs = colsum[((size_t)b * 8 + c) * 256 + d];
      ncT[d * 64 + mi] = f2bf(nrvL[m * 8 + j] / (cs + 1e-6f));
    }
  }
  __syncthreads();
  int wv = t >> 6, l = t & 63;
  int half = l >> 5, p = l & 31;
  const unsigned int* ncP = (const unsigned int*)ncT;
  unsigned int* eb = (unsigned int*)(edge + (((size_t)b * 8 + c) * 256) * 256);
  for (int nn = 0; nn < 32; nn++) {
    int n = nn * 8 + wv * 2 + half;
    int4 iv = *(const int4*)(idxL + n * 8);
    float4 w0 = *(const float4*)(nrvL + n * 8);
    float4 w1 = *(const float4*)(nrvL + n * 8 + 4);
    float a0 = 0.f, a1 = 0.f;
    int d;
    unsigned int pr;
    d = (int)(short)(iv.x & 0xFFFF);
    if (d >= 0) { pr = ncP[d * 32 + p]; a0 += w0.x * bf2f_lo(pr); a1 += w0.x * bf2f_hi(pr); }
    d = iv.x >> 16;
    if (d >= 0) { pr = ncP[d * 32 + p]; a0 += w0.y * bf2f_lo(pr); a1 += w0.y * bf2f_hi(pr); }
    d = (int)(short)(iv.y & 0xFFFF);
    if (d >= 0) { pr = ncP[d * 32 + p]; a0 += w0.z * bf2f_lo(pr); a1 += w0.z * bf2f_hi(pr); }
    d = iv.y >> 16;
    if (d >= 0) { pr = ncP[d * 32 + p]; a0 += w0.w * bf2f_lo(pr); a1 += w0.w * bf2f_hi(pr); }
    d = (int)(short)(iv.z & 0xFFFF);
    if (d >= 0) { pr = ncP[d * 32 + p]; a0 += w1.x * bf2f_lo(pr); a1 += w1.x * bf2f_hi(pr); }
    d = iv.z >> 16;
    if (d >= 0) { pr = ncP[d * 32 + p]; a0 += w1.y * bf2f_lo(pr); a1 += w1.y * bf2f_hi(pr); }
    d = (int)(short)(iv.w & 0xFFFF);
    if (d >= 0) { pr = ncP[d * 32 + p]; a0 += w1.z * bf2f_lo(pr); a1 += w1.z * bf2f_hi(pr); }
    unsigned int packo = (unsigned int)f2bf(a0) | ((unsigned int)f2bf(a1) << 16);
    eb[n * 128 + (m0 >> 1) + p] = packo;
  }
}

// ---------------------------------------------------------------------------
// xs = sigmoid(elu(x))
// ---------------------------------------------------------------------------
static __device__ __forceinline__ float selu1(float v) {
  float e = (v > 0.f) ? v : expm1f(v);
  return 1.0f / (1.0f + expf(-e));
}
__global__ __launch_bounds__(256) void xs_kernel(const float* __restrict__ x,
                                                 float* __restrict__ xs) {
  int i = blockIdx.x * 256 + threadIdx.x;
  float4 v = ((const float4*)x)[i];
  float4 o;
  o.x = selu1(v.x); o.y = selu1(v.y); o.z = selu1(v.z); o.w = selu1(v.w);
  ((float4*)xs)[i] = o;
}

// ---------------------------------------------------------------------------
// qg/kg = xs @ W_l^T + b_l  (R7 LDS version, grid 128)
// ---------------------------------------------------------------------------
__global__ __launch_bounds__(256, 1) void qkx_kernel(
    const float* __restrict__ xs, const float* __restrict__ gaw,
    const float* __restrict__ gab, int l, float* __restrict__ qg,
    float* __restrict__ kg) {
  __shared__ float xsL[64 * 64];
  int t = threadIdx.x;
  int b = blockIdx.x >> 2, nt = blockIdx.x & 3;
  int f = t & 63, part = t >> 6;
  float wq[64], wk[64];
  const float4* Wq4 = (const float4*)(gaw + (size_t)l * 8192 + f * 64);
  const float4* Wk4 = (const float4*)(gaw + (size_t)l * 8192 + (64 + f) * 64);
#pragma unroll
  for (int j = 0; j < 16; j++) {
    float4 aa = Wq4[j];
    wq[4 * j + 0] = aa.x; wq[4 * j + 1] = aa.y; wq[4 * j + 2] = aa.z; wq[4 * j + 3] = aa.w;
    float4 bb = Wk4[j];
    wk[4 * j + 0] = bb.x; wk[4 * j + 1] = bb.y; wk[4 * j + 2] = bb.z; wk[4 * j + 3] = bb.w;
  }
  float bq = gab[l * 128 + f], bk = gab[l * 128 + 64 + f];
  for (int i = t; i < 1024; i += 256)
    ((float4*)xsL)[i] = ((const float4*)(xs + ((size_t)b * 256 + nt * 64) * 64))[i];
  __syncthreads();
  for (int i = 0; i < 16; i++) {
    int nl = part * 16 + i;
    const float4* xr = (const float4*)(xsL + nl * 64);
    float aq = 0.f, ak = 0.f;
#pragma unroll
    for (int j = 0; j < 16; j++) {
      float4 v = xr[j];
      aq += v.x * wq[4 * j] + v.y * wq[4 * j + 1] + v.z * wq[4 * j + 2] + v.w * wq[4 * j + 3];
      ak += v.x * wk[4 * j] + v.y * wk[4 * j + 1] + v.z * wk[4 * j + 2] + v.w * wk[4 * j + 3];
    }
    int n = nt * 64 + nl;
    qg[((size_t)b * 256 + n) * 64 + f] = aq + bq;
    kg[((size_t)b * 256 + n) * 64 + f] = ak + bk;
  }
}

// ---------------------------------------------------------------------------
// ga_attn (R7 version): no LDS/barriers; (256,2); grid 256 = b*8+nt.
// ---------------------------------------------------------------------------
__global__ __launch_bounds__(256, 2) void ga_attn_kernel(
    const float* __restrict__ qg, const float* __restrict__ kgT,
    float* __restrict__ a) {
  int t = threadIdx.x;
  int b = blockIdx.x >> 3, nt = blockIdx.x & 7;
  int n0 = nt * 32;
  int wv = t >> 6, l = t & 63;
  const float* kb = kgT + (size_t)b * 16384 + 4 * l;          // [f][m]
  const float* qb = qg + ((size_t)b * 256 + n0 + wv * 8) * 64;
  float acc[8][4];
#pragma unroll
  for (int r = 0; r < 8; r++)
#pragma unroll
    for (int j = 0; j < 4; j++) acc[r][j] = 0.f;
#pragma unroll 4
  for (int kq4 = 0; kq4 < 64; kq4 += 4) {
    float4 kv0 = *(const float4*)(kb + (kq4 + 0) * 256);
    float4 kv1 = *(const float4*)(kb + (kq4 + 1) * 256);
    float4 kv2 = *(const float4*)(kb + (kq4 + 2) * 256);
    float4 kv3 = *(const float4*)(kb + (kq4 + 3) * 256);
#pragma unroll
    for (int r = 0; r < 8; r++) {
      float4 qv = *(const float4*)(qb + r * 64 + kq4);
      acc[r][0] += qv.x * kv0.x + qv.y * kv1.x + qv.z * kv2.x + qv.w * kv3.x;
      acc[r][1] += qv.x * kv0.y + qv.y * kv1.y + qv.z * kv2.y + qv.w * kv3.y;
      acc[r][2] += qv.x * kv0.z + qv.y * kv1.z + qv.z * kv2.z + qv.w * kv3.z;
      acc[r][3] += qv.x * kv0.w + qv.y * kv1.w + qv.z * kv2.w + qv.w * kv3.w;
    }
  }
#pragma unroll
  for (int r = 0; r < 8; r++) {
    float l0 = acc[r][0] * 0.125f, l1 = acc[r][1] * 0.125f;
    float l2 = acc[r][2] * 0.125f, l3 = acc[r][3] * 0.125f;
    float mx = fmaxf(fmaxf(l0, l1), fmaxf(l2, l3));
#pragma unroll
    for (int m = 1; m < 64; m <<= 1) mx = fmaxf(mx, __shfl_xor(mx, m, 64));
    float e0 = expf(l0 - mx), e1 = expf(l1 - mx), e2 = expf(l2 - mx), e3 = expf(l3 - mx);
    float z = e0 + e1 + e2 + e3;
#pragma unroll
    for (int m = 1; m < 64; m <<= 1) z += __shfl_xor(z, m, 64);
    float zi = 1.0f / z;
    int n = n0 + wv * 8 + r;
    float4 o;
    o.x = e0 * zi; o.y = e1 * zi; o.z = e2 * zi; o.w = e3 * zi;
    ((float4*)(a + ((size_t)b * 256 + n) * 256))[l] = o;
  }
}

// ---------------------------------------------------------------------------
// ne normalize + x += (ne3 @ xs)/lip
// ---------------------------------------------------------------------------
__global__ __launch_bounds__(256) void upd_kernel(
    const float* __restrict__ a, const unsigned short* __restrict__ edge,
    const float* __restrict__ xs, const float* __restrict__ gaww,
    const float* __restrict__ lipv, int l, float* __restrict__ x) {
  __shared__ float tt[4][8][256];
  __shared__ float ne3[4][256];
  __shared__ float parts[4][4][64];
  __shared__ float dred[32][8];
  __shared__ float dinv[4][8];
  __shared__ float wcL[8];
  __shared__ float lipi;
  int t = threadIdx.x;
  int b = blockIdx.x >> 6, nq = blockIdx.x & 63;
  int n0 = nq * 4;
  if (t == 0) {
    float s = 0.f;
    float wtmp[8];
    for (int c = 0; c < 8; c++) { wtmp[c] = gaww[l * 8 + c]; s += wtmp[c]; }
    for (int c = 0; c < 8; c++) wcL[c] = wtmp[c] / s;
    lipi = 1.0f / lipv[l];
  }
#pragma unroll
  for (int r = 0; r < 4; r++) {
    float av = a[((size_t)b * 256 + n0 + r) * 256 + t];
#pragma unroll
    for (int c = 0; c < 8; c++)
      tt[r][c][t] = av * bf2f(edge[(((size_t)b * 8 + c) * 256 + n0 + r) * 256 + t]);
  }
  __syncthreads();
  {
    int rc = t >> 3, i = t & 7;
    int r = rc >> 3, c = rc & 7;
    float p = 0.f;
#pragma unroll
    for (int kq = 0; kq < 32; kq++) p += tt[r][c][i + 8 * kq];
    dred[rc][i] = p;
  }
  __syncthreads();
  if (t < 32) {
    float s = 0.f;
#pragma unroll
    for (int i = 0; i < 8; i++) s += dred[t][i];
    dinv[t >> 3][t & 7] = 1.0f / (s + 1e-6f);
  }
  __syncthreads();
#pragma unroll
  for (int r = 0; r < 4; r++) {
    float s = 0.f;
#pragma unroll
    for (int c = 0; c < 8; c++) s += wcL[c] * tt[r][c][t] * dinv[r][c];
    ne3[r][t] = s;
  }
  __syncthreads();
  {
    int f = t & 63, part = t >> 6;
    float a0 = 0.f, a1 = 0.f, a2 = 0.f, a3 = 0.f;
    for (int mm = 0; mm < 64; mm++) {
      int m = part * 64 + mm;
      float xv = xs[((size_t)b * 256 + m) * 64 + f];
      a0 += ne3[0][m] * xv;
      a1 += ne3[1][m] * xv;
      a2 += ne3[2][m] * xv;
      a3 += ne3[3][m] * xv;
    }
    parts[0][part][f] = a0;
    parts[1][part][f] = a1;
    parts[2][part][f] = a2;
    parts[3][part][f] = a3;
  }
  __syncthreads();
  {
    int r = t >> 6, f = t & 63;
    float dx = parts[r][0][f] + parts[r][1][f] + parts[r][2][f] + parts[r][3][f];
    x[((size_t)b * 256 + n0 + r) * 64 + f] += dx * lipi;
  }
}

// ---------------------------------------------------------------------------
extern "C" void kernel_launch(void* const* d_in, const int* in_sizes, int n_in,
                              void* d_out, int out_size, void* d_ws, size_t ws_size,
                              hipStream_t stream) {
  (void)in_sizes; (void)n_in; (void)out_size; (void)ws_size;
  const float* fused = (const float*)d_in[0];
  const float* w1 = (const float*)d_in[1];
  const float* b1 = (const float*)d_in[2];
  const float* w2 = (const float*)d_in[3];
  const float* b2 = (const float*)d_in[4];
  const float* eqk = (const float*)d_in[5];
  const float* gaw = (const float*)d_in[6];
  const float* gab = (const float*)d_in[7];
  const float* gaww = (const float*)d_in[8];
  float* x = (float*)d_out;  // x lives in d_out (B,ND,NF)=(32,256,64); fully overwritten.
  char* ws = (char*)d_ws;
  size_t off = 0;
  auto alloc = [&](size_t bytes) -> char* {
    char* p = ws + off;
    off += (bytes + 1023) & ~(size_t)1023;
    return p;
  };
  float* invsig1 = (float*)alloc(64 * 4);
  float* invsig2 = (float*)alloc(64 * 4);
  float* lipv = (float*)alloc(2 * 4);
  float* h = (float*)alloc((size_t)32 * 64 * 64 * 4);
  unsigned short* qhi = (unsigned short*)alloc((size_t)32 * 8 * 256 * 64 * 2);
  unsigned short* qlo = (unsigned short*)alloc((size_t)32 * 8 * 256 * 64 * 2);
  unsigned short* khi = (unsigned short*)alloc((size_t)32 * 8 * 256 * 64 * 2);
  unsigned short* klo = (unsigned short*)alloc((size_t)32 * 8 * 256 * 64 * 2);
  // seP (2 partials, 16.8 MB) aliases edge (33.6 MB): seP dead after topsel.
  char* sep_edge = alloc((size_t)4 * 32 * 256 * 256 * 4);
  float* seP = (float*)sep_edge;
  unsigned short* edge = (unsigned short*)sep_edge;
  float* mxb = (float*)alloc((size_t)65536 * 4);
  float* rzb = (float*)alloc((size_t)65536 * 4);
  int* idx7 = (int*)alloc((size_t)8192 * 7 * 4);
  float* nrv = (float*)alloc((size_t)65536 * 7 * 4);
  float* colsum = (float*)alloc((size_t)65536 * 4);
  float* xs = (float*)alloc((size_t)524288 * 4);
  float* qg = (float*)alloc((size_t)524288 * 4);
  float* kg = (float*)alloc((size_t)524288 * 4);
  float* a = (float*)alloc((size_t)32 * 256 * 256 * 4);
  float* kgT = (float*)alloc((size_t)524288 * 4);

  speclip_kernel<<<130, 256, 0, stream>>>(w1, w2, gaw, invsig1, invsig2, lipv);
  h_kernel<<<512, 256, 0, stream>>>(fused, w1, b1, invsig1, h);
  conv_kernel<<<512, 256, 0, stream>>>(h, w2, b2, invsig2, x);
  qk_kernel<<<512, 256, 0, stream>>>(x, eqk, qhi, qlo, khi, klo);
  attn_kernel<<<256, 256, 0, stream>>>(qhi, qlo, khi, klo, seP, mxb, rzb);
  hipMemsetAsync(colsum, 0, (size_t)65536 * 4, stream);
  topsel_kernel<<<128, 256, 0, stream>>>(seP, idx7);
  nr_kernel<<<8192, 256, 0, stream>>>(qhi, qlo, khi, klo, mxb, rzb, idx7, nrv, colsum);
  edge_kernel<<<1024, 256, 0, stream>>>(idx7, nrv, colsum, edge);
  for (int l = 0; l < 2; l++) {
    xs_kernel<<<512, 256, 0, stream>>>(x, xs);
    qkx_kernel<<<128, 256, 0, stream>>>(xs, gaw, gab, l, qg, kg);
    transpose_kernel<<<32, 256, 0, stream>>>(kg, kgT);
    ga_attn_kernel<<<256, 256, 0, stream>>>(qg, kgT, a);
    upd_kernel<<<2048, 256, 0, stream>>>(a, edge, xs, gaww, lipv, l, x);
  }
}

// Round 13
// 421.561 us; speedup vs baseline: 1.2710x; 1.0789x over previous
//
#include <hip/hip_runtime.h>
#include <float.h>
#include <math.h>

// Problem constants: B=32, NF=64, FD=64, ND=256, C=8, K=6, L=2, scale=1/8.

typedef short bf8t __attribute__((ext_vector_type(8)));   // 8 bf16 in 4 VGPRs
typedef float f4t __attribute__((ext_vector_type(4)));

static __device__ __forceinline__ unsigned short f2bf(float x) {
  union { float f; unsigned u; } v; v.f = x;
  unsigned r = (v.u + 0x7FFFu + ((v.u >> 16) & 1u)) >> 16;
  return (unsigned short)r;
}
static __device__ __forceinline__ float bf2f(unsigned short s) {
  union { unsigned u; float f; } v; v.u = ((unsigned)s) << 16; return v.f;
}
static __device__ __forceinline__ float bf2f_lo(unsigned u) {
  union { unsigned u; float f; } v; v.u = u << 16; return v.f;
}
static __device__ __forceinline__ float bf2f_hi(unsigned u) {
  union { unsigned u; float f; } v; v.u = u & 0xFFFF0000u; return v.f;
}
// 2 packed elems of the 3-term split dot: qh*(kh+kl) + ql*kh
static __device__ __forceinline__ float dot3_pair(unsigned uqh, unsigned uql,
                                                  unsigned ukh, unsigned ukl) {
  float s = bf2f_lo(uqh) * (bf2f_lo(ukh) + bf2f_lo(ukl)) + bf2f_lo(uql) * bf2f_lo(ukh);
  s += bf2f_hi(uqh) * (bf2f_hi(ukh) + bf2f_hi(ukl)) + bf2f_hi(uql) * bf2f_hi(ukh);
  return s;
}
// split 8 fp32 into hi/lo bf16 fragments
static __device__ __forceinline__ void split8(const float* __restrict__ p,
                                              bf8t* hi, bf8t* lo) {
  float4 v0 = *(const float4*)(p);
  float4 v1 = *(const float4*)(p + 4);
  float v[8] = {v0.x, v0.y, v0.z, v0.w, v1.x, v1.y, v1.z, v1.w};
#pragma unroll
  for (int j = 0; j < 8; j++) {
    unsigned short h = f2bf(v[j]);
    (*hi)[j] = (short)h;
    (*lo)[j] = (short)f2bf(v[j] - bf2f(h));
  }
}

// ---------------------------------------------------------------------------
// Cooperative 64x64 row-row matmul (LDS stride 65, 4x4 register tile).
// ---------------------------------------------------------------------------
static __device__ __forceinline__ void mm_rr(
    const float* __restrict__ A, const float* __restrict__ B,
    float* __restrict__ C, int t, float scale, int addI, int transposeStore) {
  int tr = t >> 4, tc = t & 15;
  float acc[4][4];
#pragma unroll
  for (int j = 0; j < 4; j++)
#pragma unroll
    for (int jj = 0; jj < 4; jj++) acc[j][jj] = 0.f;
  const float* Ap = A + (4 * tr) * 65;
  const float* Bp = B + (4 * tc) * 65;
  for (int k = 0; k < 64; k++) {
    float a0 = Ap[k], a1 = Ap[65 + k], a2 = Ap[130 + k], a3 = Ap[195 + k];
    float b0 = Bp[k], b1 = Bp[65 + k], b2 = Bp[130 + k], b3 = Bp[195 + k];
    acc[0][0] += a0 * b0; acc[0][1] += a0 * b1; acc[0][2] += a0 * b2; acc[0][3] += a0 * b3;
    acc[1][0] += a1 * b0; acc[1][1] += a1 * b1; acc[1][2] += a1 * b2; acc[1][3] += a1 * b3;
    acc[2][0] += a2 * b0; acc[2][1] += a2 * b1; acc[2][2] += a2 * b2; acc[2][3] += a2 * b3;
    acc[3][0] += a3 * b0; acc[3][1] += a3 * b1; acc[3][2] += a3 * b2; acc[3][3] += a3 * b3;
  }
#pragma unroll
  for (int j = 0; j < 4; j++)
#pragma unroll
    for (int jj = 0; jj < 4; jj++) {
      int i0 = 4 * tr + j, j0 = 4 * tc + jj;
      float v = acc[j][jj] * scale + ((addI && i0 == j0) ? 1.0f : 0.0f);
      if (transposeStore) C[j0 * 65 + i0] = v; else C[i0 * 65 + j0] = v;
    }
}

// Gram: G = A_glob * A_glob^T (A_glob is 64 x ncols, row-major), staged in S.
static __device__ __forceinline__ void gram(
    const float* __restrict__ Ag, int ncols, float* __restrict__ S,
    float* __restrict__ G, int t) {
  int tr = t >> 4, tc = t & 15;
  float acc[4][4];
#pragma unroll
  for (int j = 0; j < 4; j++)
#pragma unroll
    for (int jj = 0; jj < 4; jj++) acc[j][jj] = 0.f;
  for (int cc = 0; cc < ncols; cc += 64) {
    if (cc) __syncthreads();
    for (int i = t; i < 1024; i += 256) {
      int r = i >> 4, qq = i & 15;
      float4 v = *(const float4*)(Ag + (size_t)r * ncols + cc + 4 * qq);
      float* dst = S + r * 65 + 4 * qq;
      dst[0] = v.x; dst[1] = v.y; dst[2] = v.z; dst[3] = v.w;
    }
    __syncthreads();
    const float* Ap = S + (4 * tr) * 65;
    const float* Bp = S + (4 * tc) * 65;
    for (int k = 0; k < 64; k++) {
      float a0 = Ap[k], a1 = Ap[65 + k], a2 = Ap[130 + k], a3 = Ap[195 + k];
      float b0 = Bp[k], b1 = Bp[65 + k], b2 = Bp[130 + k], b3 = Bp[195 + k];
      acc[0][0] += a0 * b0; acc[0][1] += a0 * b1; acc[0][2] += a0 * b2; acc[0][3] += a0 * b3;
      acc[1][0] += a1 * b0; acc[1][1] += a1 * b1; acc[1][2] += a1 * b2; acc[1][3] += a1 * b3;
      acc[2][0] += a2 * b0; acc[2][1] += a2 * b1; acc[2][2] += a2 * b2; acc[2][3] += a2 * b3;
      acc[3][0] += a3 * b0; acc[3][1] += a3 * b1; acc[3][2] += a3 * b2; acc[3][3] += a3 * b3;
    }
  }
  __syncthreads();
#pragma unroll
  for (int j = 0; j < 4; j++)
#pragma unroll
    for (int jj = 0; jj < 4; jj++) G[(4 * tr + j) * 65 + (4 * tc + jj)] = acc[j][jj];
}

// Single-wave power iteration + Rayleigh on Gm (caller gates t < 64).
static __device__ __forceinline__ float power_rayleigh(
    const float* __restrict__ G4m, const float* __restrict__ Gm, int iters, int i) {
  float row[64];
#pragma unroll
  for (int j = 0; j < 64; j++) row[j] = G4m[i * 65 + j];
  float v = 1.0f + 0.3f * sinf(7.0f * (float)(i + 1));
  for (int it = 0; it < iters; it++) {
    float u = 0.f;
#pragma unroll
    for (int j = 0; j < 64; j++) u += row[j] * __shfl(v, j, 64);
    float ss = u * u;
#pragma unroll
    for (int m = 1; m < 64; m <<= 1) ss += __shfl_xor(ss, m, 64);
    v = u * rsqrtf(fmaxf(ss, 1e-30f));
  }
  float rowg[64];
#pragma unroll
  for (int j = 0; j < 64; j++) rowg[j] = Gm[i * 65 + j];
  float u = 0.f;
#pragma unroll
  for (int j = 0; j < 64; j++) u += rowg[j] * __shfl(v, j, 64);
  float d = v * u;
#pragma unroll
  for (int m = 1; m < 64; m <<= 1) d += __shfl_xor(d, m, 64);
  return d;
}

// ---------------------------------------------------------------------------
// Fused spectral norms + lip: grid 130.
// ---------------------------------------------------------------------------
__global__ __launch_bounds__(256) void speclip_kernel(
    const float* __restrict__ w1, const float* __restrict__ w2,
    const float* __restrict__ gaw, float* __restrict__ invsig1,
    float* __restrict__ invsig2, float* __restrict__ lipv) {
  __shared__ float Sa[64 * 65];
  __shared__ float Sb[64 * 65];
  __shared__ float G[64 * 65];
  int t = threadIdx.x;
  int blk = blockIdx.x;
  if (blk < 128) {
    int n = blk & 63;
    const float* A = (blk < 64) ? (w1 + (size_t)n * 4096) : (w2 + (size_t)n * 16384);
    int ncols = (blk < 64) ? 64 : 256;
    gram(A, ncols, Sa, G, t);
    __syncthreads();
    mm_rr(G, G, Sa, t, 1.f, 0, 0);
    __syncthreads();
    mm_rr(Sa, Sa, Sb, t, 1.f, 0, 0);
    __syncthreads();
    if (t < 64) {
      float d = power_rayleigh(Sb, G, 30, t);
      if (t == 0) {
        float sg = sqrtf(fmaxf(d, 0.f));
        float inv = 1.0f / fmaxf(sg, 1e-6f);
        if (blk < 64) invsig1[n] = inv; else invsig2[n] = inv;
      }
    }
  } else {
    int l = blk - 128;
    const float* Wb = gaw + (size_t)l * 8192;
    for (int i = t; i < 1024; i += 256) {
      int r = i >> 4, qq = i & 15;
      float4 vq = *(const float4*)(Wb + r * 64 + 4 * qq);
      float4 vk = *(const float4*)(Wb + 4096 + r * 64 + 4 * qq);
      float* dq = Sa + r * 65 + 4 * qq;
      dq[0] = vq.x; dq[1] = vq.y; dq[2] = vq.z; dq[3] = vq.w;
      float* dk = Sb + r * 65 + 4 * qq;
      dk[0] = vk.x; dk[1] = vk.y; dk[2] = vk.z; dk[3] = vk.w;
    }
    __syncthreads();
    mm_rr(Sa, Sb, G, t, 0.25f, 1, 1);
    __syncthreads();
    mm_rr(G, G, Sa, t, 1.f, 0, 0);
    __syncthreads();
    mm_rr(Sa, Sa, Sb, t, 1.f, 0, 0);
    __syncthreads();
    mm_rr(Sb, Sb, G, t, 1.f, 0, 0);
    __syncthreads();
    if (t < 64) {
      float d = power_rayleigh(G, Sa, 12, t);
      if (t == 0) lipv[l] = sqrtf(fmaxf(d, 0.f)) + 5.0f;
    }
  }
}

// ---------------------------------------------------------------------------
// h = gelu(fused @ w1n + b1). grid 512 = b*16+ng.
// ---------------------------------------------------------------------------
__global__ __launch_bounds__(256) void h_kernel(
    const float* __restrict__ fused, const float* __restrict__ w1,
    const float* __restrict__ b1, const float* __restrict__ invsig1,
    float* __restrict__ h) {
  __shared__ float fr[256];
  int t = threadIdx.x;
  int blk = blockIdx.x;
  int ng = blk & 15;
  fr[t] = fused[(size_t)blk * 256 + t];
  __syncthreads();
  int nl = t >> 6, j = t & 63;
  int n = ng * 4 + nl;
  float is1 = invsig1[n];
  const float* fp = fr + nl * 64;
  const float* wp = w1 + (size_t)n * 4096 + j;
  float acc = 0.f;
  for (int i = 0; i < 64; i++) acc += fp[i] * wp[i * 64];
  acc = acc * is1 + b1[n * 64 + j];
  float g = 0.5f * acc * (1.0f + erff(acc * 0.70710678118654752440f));
  h[(size_t)blk * 256 + t] = g;
}

// ---------------------------------------------------------------------------
// conv: x[b,d,n0..n0+4) = h @ w2 + b2, float4 store.
// ---------------------------------------------------------------------------
__global__ __launch_bounds__(256) void conv_kernel(
    const float* __restrict__ h, const float* __restrict__ w2,
    const float* __restrict__ b2, const float* __restrict__ invsig2,
    float* __restrict__ x) {
  __shared__ float hr[4][64];
  int t = threadIdx.x;
  int blk = blockIdx.x;
  int b = blk >> 4, ng = blk & 15;
  int n0 = ng * 4;
  {
    int r = t >> 6, i = t & 63;
    hr[r][i] = h[((size_t)b * 64 + n0 + r) * 64 + i];
  }
  __syncthreads();
  const float* w0p = w2 + ((size_t)(n0 + 0) * 64) * 256 + t;
  const float* w1p = w2 + ((size_t)(n0 + 1) * 64) * 256 + t;
  const float* w2p = w2 + ((size_t)(n0 + 2) * 64) * 256 + t;
  const float* w3p = w2 + ((size_t)(n0 + 3) * 64) * 256 + t;
  float a0 = 0.f, a1 = 0.f, a2 = 0.f, a3 = 0.f;
  for (int i = 0; i < 64; i++) {
    a0 += hr[0][i] * w0p[(size_t)i * 256];
    a1 += hr[1][i] * w1p[(size_t)i * 256];
    a2 += hr[2][i] * w2p[(size_t)i * 256];
    a3 += hr[3][i] * w3p[(size_t)i * 256];
  }
  float4 o;
  o.x = a0 * invsig2[n0 + 0] + b2[(n0 + 0) * 256 + t];
  o.y = a1 * invsig2[n0 + 1] + b2[(n0 + 1) * 256 + t];
  o.z = a2 * invsig2[n0 + 2] + b2[(n0 + 2) * 256 + t];
  o.w = a3 * invsig2[n0 + 3] + b2[(n0 + 3) * 256 + t];
  *(float4*)(x + ((size_t)b * 256 + t) * 64 + n0) = o;
}

// ---------------------------------------------------------------------------
// qk v4 (R12, proven): MFMA bf16 3-term split, grid 512 XCD-swizzled.
// ---------------------------------------------------------------------------
__global__ __launch_bounds__(256, 2) void qk_kernel(
    const float* __restrict__ x, const float* __restrict__ eqk,
    unsigned short* __restrict__ qhi, unsigned short* __restrict__ qlo,
    unsigned short* __restrict__ khi, unsigned short* __restrict__ klo) {
  int t = threadIdx.x;
  int blk = blockIdx.x;
  int xcd = blk & 7;
  int y = blk >> 3;
  int rh = y & 1;
  int c = (y >> 1) & 7;
  int b = (y >> 4) * 8 + xcd;
  int wv = t >> 6, l = t & 63;
  int m16 = l & 15, quad = l >> 4;
  int row0 = rh * 128 + wv * 32;

  bf8t ah[2][2], al[2][2];
#pragma unroll
  for (int rt = 0; rt < 2; rt++) {
    const float* xp = x + ((size_t)b * 256 + row0 + rt * 16 + m16) * 64 + quad * 8;
    split8(xp, &ah[rt][0], &al[rt][0]);
    split8(xp + 32, &ah[rt][1], &al[rt][1]);
  }
#pragma unroll
  for (int mat = 0; mat < 2; mat++) {
    const float* Wbase = eqk + ((size_t)(mat * 8 + c) * 64) * 64;
    unsigned short* ohi = mat ? khi : qhi;
    unsigned short* olo = mat ? klo : qlo;
#pragma unroll
    for (int ct = 0; ct < 4; ct++) {
      bf8t bh[2], bl[2];
      const float* wp = Wbase + (size_t)(ct * 16 + m16) * 64 + quad * 8;
      split8(wp, &bh[0], &bl[0]);
      split8(wp + 32, &bh[1], &bl[1]);
#pragma unroll
      for (int rt = 0; rt < 2; rt++) {
        f4t a = (f4t){0.f, 0.f, 0.f, 0.f};
        a = __builtin_amdgcn_mfma_f32_16x16x32_bf16(al[rt][0], bh[0], a, 0, 0, 0);
        a = __builtin_amdgcn_mfma_f32_16x16x32_bf16(ah[rt][0], bl[0], a, 0, 0, 0);
        a = __builtin_amdgcn_mfma_f32_16x16x32_bf16(ah[rt][0], bh[0], a, 0, 0, 0);
        a = __builtin_amdgcn_mfma_f32_16x16x32_bf16(al[rt][1], bh[1], a, 0, 0, 0);
        a = __builtin_amdgcn_mfma_f32_16x16x32_bf16(ah[rt][1], bl[1], a, 0, 0, 0);
        a = __builtin_amdgcn_mfma_f32_16x16x32_bf16(ah[rt][1], bh[1], a, 0, 0, 0);
#pragma unroll
        for (int j = 0; j < 4; j++) {
          int n = row0 + rt * 16 + quad * 4 + j;
          int f = ct * 16 + m16;
          size_t o = (((size_t)b * 8 + c) * 256 + n) * 64 + f;
          float v = a[j];
          unsigned short h = f2bf(v);
          ohi[o] = h;
          olo[o] = f2bf(v - bf2f(h));
        }
      }
    }
  }
}

// ---------------------------------------------------------------------------
// Generic slice transpose: in[s][n(256)][f(64)] -> out[s][f(64)][m(256)].
// (loop phase kg only)
// ---------------------------------------------------------------------------
__global__ __launch_bounds__(256, 2) void transpose_kernel(
    const float* __restrict__ in, float* __restrict__ out) {
  __shared__ float T[256 * 65];
  int t = threadIdx.x;
  size_t base = (size_t)blockIdx.x * 16384;
  const float4* in4 = (const float4*)(in + base);
  float4* out4 = (float4*)(out + base);
  for (int i = t; i < 4096; i += 256) {
    int n = i >> 4, fq = i & 15;
    float4 v = in4[i];
    float* dst = T + n * 65 + 4 * fq;
    dst[0] = v.x; dst[1] = v.y; dst[2] = v.z; dst[3] = v.w;
  }
  __syncthreads();
  for (int i = t; i < 4096; i += 256) {
    int f = i >> 6, m4 = i & 63;
    float4 o;
    o.x = T[(4 * m4 + 0) * 65 + f];
    o.y = T[(4 * m4 + 1) * 65 + f];
    o.z = T[(4 * m4 + 2) * 65 + f];
    o.w = T[(4 * m4 + 3) * 65 + f];
    out4[f * 64 + m4] = o;
  }
}

// ---------------------------------------------------------------------------
// Fused attn v7: MFMA bf16 3-term split; 2 c's/block, grid 512 (2 blocks/CU
// vs R12's 1 -- the 65us was undersubscription latency). 4 seP partials.
// ---------------------------------------------------------------------------
__global__ __launch_bounds__(256, 2) void attn_kernel(
    const unsigned short* __restrict__ qhi, const unsigned short* __restrict__ qlo,
    const unsigned short* __restrict__ khi, const unsigned short* __restrict__ klo,
    float* __restrict__ seP, float* __restrict__ mxb, float* __restrict__ rzb) {
  int t = threadIdx.x;
  int blk = blockIdx.x;
  int xcd = blk & 7;
  int y = blk >> 3;
  int b = xcd * 4 + (y & 3);
  int cg = (y >> 2) & 3;
  int ng = y >> 4;
  int wv = t >> 6, l = t & 63;
  int m16 = l & 15, quad = l >> 4;
  int n0w = ng * 64 + wv * 16;

  f4t sum_acc[16];
#pragma unroll
  for (int mt = 0; mt < 16; mt++) sum_acc[mt] = (f4t){0.f, 0.f, 0.f, 0.f};

  for (int ci = 0; ci < 2; ci++) {
    int c = cg * 2 + ci;
    size_t sl = ((size_t)b * 8 + c) * 16384;
    const bf8t* qh = (const bf8t*)(qhi + sl + (size_t)(n0w + m16) * 64 + quad * 8);
    const bf8t* ql = (const bf8t*)(qlo + sl + (size_t)(n0w + m16) * 64 + quad * 8);
    bf8t ah0 = qh[0], ah1 = qh[4];
    bf8t al0 = ql[0], al1 = ql[4];
    f4t acc[16];
#pragma unroll
    for (int mt = 0; mt < 16; mt++) acc[mt] = (f4t){0.f, 0.f, 0.f, 0.f};
    for (int mt = 0; mt < 16; mt++) {
      const bf8t* kh = (const bf8t*)(khi + sl + (size_t)(mt * 16 + m16) * 64 + quad * 8);
      const bf8t* kl = (const bf8t*)(klo + sl + (size_t)(mt * 16 + m16) * 64 + quad * 8);
      bf8t bh0 = kh[0], bh1 = kh[4];
      bf8t bl0 = kl[0], bl1 = kl[4];
      f4t a = acc[mt];
      a = __builtin_amdgcn_mfma_f32_16x16x32_bf16(al0, bh0, a, 0, 0, 0);
      a = __builtin_amdgcn_mfma_f32_16x16x32_bf16(ah0, bl0, a, 0, 0, 0);
      a = __builtin_amdgcn_mfma_f32_16x16x32_bf16(ah0, bh0, a, 0, 0, 0);
      a = __builtin_amdgcn_mfma_f32_16x16x32_bf16(al1, bh1, a, 0, 0, 0);
      a = __builtin_amdgcn_mfma_f32_16x16x32_bf16(ah1, bl1, a, 0, 0, 0);
      a = __builtin_amdgcn_mfma_f32_16x16x32_bf16(ah1, bh1, a, 0, 0, 0);
      acc[mt] = a;
    }
#pragma unroll
    for (int j = 0; j < 4; j++) {
      float mx = -FLT_MAX;
#pragma unroll
      for (int mt = 0; mt < 16; mt++) mx = fmaxf(mx, acc[mt][j]);
      mx = fmaxf(mx, __shfl_xor(mx, 1, 64));
      mx = fmaxf(mx, __shfl_xor(mx, 2, 64));
      mx = fmaxf(mx, __shfl_xor(mx, 4, 64));
      mx = fmaxf(mx, __shfl_xor(mx, 8, 64));
      float mxl = mx * 0.125f;
      float e[16];
      float z = 0.f;
#pragma unroll
      for (int mt = 0; mt < 16; mt++) {
        e[mt] = expf(acc[mt][j] * 0.125f - mxl);
        z += e[mt];
      }
      z += __shfl_xor(z, 1, 64);
      z += __shfl_xor(z, 2, 64);
      z += __shfl_xor(z, 4, 64);
      z += __shfl_xor(z, 8, 64);
      int n = n0w + quad * 4 + j;
      if (m16 == 0) {
        mxb[((size_t)b * 8 + c) * 256 + n] = mxl;
        rzb[((size_t)b * 8 + c) * 256 + n] = z;
      }
      float zi = 1.0f / z;
#pragma unroll
      for (int mt = 0; mt < 16; mt++) sum_acc[mt][j] += e[mt] * zi;
    }
  }
#pragma unroll
  for (int mt = 0; mt < 16; mt++) {
#pragma unroll
    for (int j = 0; j < 4; j++) {
      int n = n0w + quad * 4 + j;
      seP[((size_t)(cg * 32 + b) * 256 + n) * 256 + mt * 16 + m16] = sum_acc[mt][j];
    }
  }
}

// ---------------------------------------------------------------------------
// Top-6 selection (sums 4 seP partials).
// ---------------------------------------------------------------------------
__global__ __launch_bounds__(256) void topsel_kernel(
    const float* __restrict__ seP, int* __restrict__ idx7) {
  __shared__ float seL[64 * 260];
  __shared__ float cv[64][24];
  __shared__ int cidx[64][24];
  int t = threadIdx.x;
  int b = blockIdx.x >> 2, rg = blockIdx.x & 3;
  int n0 = rg * 64;
  const float* s0 = seP + ((size_t)b * 256 + n0) * 256;
  const float* s1 = seP + ((size_t)(32 + b) * 256 + n0) * 256;
  const float* s2 = seP + ((size_t)(64 + b) * 256 + n0) * 256;
  const float* s3 = seP + ((size_t)(96 + b) * 256 + n0) * 256;
  for (int i = t; i < 4096; i += 256) {
    int m4 = i & 63, r = i >> 6;
    float4 v0 = ((const float4*)(s0 + (size_t)r * 256))[m4];
    float4 v1 = ((const float4*)(s1 + (size_t)r * 256))[m4];
    float4 v2 = ((const float4*)(s2 + (size_t)r * 256))[m4];
    float4 v3 = ((const float4*)(s3 + (size_t)r * 256))[m4];
    float4 s;
    s.x = (v0.x + v1.x) + (v2.x + v3.x);
    s.y = (v0.y + v1.y) + (v2.y + v3.y);
    s.z = (v0.z + v1.z) + (v2.z + v3.z);
    s.w = (v0.w + v1.w) + (v2.w + v3.w);
    *(float4*)(seL + r * 260 + m4 * 4) = s;
  }
  __syncthreads();
  {
    int r = t >> 2, qtr = t & 3;
    float tv[6]; int ti[6];
#pragma unroll
    for (int s = 0; s < 6; s++) { tv[s] = -FLT_MAX; ti[s] = 1 << 30; }
    for (int i = 0; i < 64; i++) {
      int m = 4 * i + qtr;
      float val = seL[r * 260 + m];
      if (val > tv[5]) {
        tv[5] = val; ti[5] = m;
#pragma unroll
        for (int s = 5; s > 0; s--) {
          if (tv[s] > tv[s - 1]) {
            float tmv = tv[s]; tv[s] = tv[s - 1]; tv[s - 1] = tmv;
            int tmi = ti[s]; ti[s] = ti[s - 1]; ti[s - 1] = tmi;
          }
        }
      }
    }
#pragma unroll
    for (int s = 0; s < 6; s++) { cv[r][qtr * 6 + s] = tv[s]; cidx[r][qtr * 6 + s] = ti[s]; }
  }
  __syncthreads();
  if (t < 64) {
    int r = t, n = n0 + r;
    int sel[7];
    for (int round = 0; round < 6; round++) {
      float best = -FLT_MAX; int bi = 1 << 30, bs = 0;
      for (int j = 0; j < 24; j++) {
        float v = cv[r][j]; int id = cidx[r][j];
        if (v > best || (v == best && id < bi)) { best = v; bi = id; bs = j; }
      }
      sel[round] = bi;
      cv[r][bs] = -FLT_MAX;
    }
    bool dup = false;
#pragma unroll
    for (int j = 0; j < 6; j++) dup = dup || (sel[j] == n);
    sel[6] = dup ? -1 : n;
#pragma unroll
    for (int j = 0; j < 7; j++) idx7[((size_t)b * 256 + n) * 7 + j] = sel[j];
  }
}

// ---------------------------------------------------------------------------
// nr values: recompute <=7 attn entries from the stored bf16 3-term split
// (consistent with attn's mxb/rzb), row-normalize, atomic colsum.
// ---------------------------------------------------------------------------
__global__ __launch_bounds__(256) void nr_kernel(
    const unsigned short* __restrict__ qhi, const unsigned short* __restrict__ qlo,
    const unsigned short* __restrict__ khi, const unsigned short* __restrict__ klo,
    const float* __restrict__ mxb, const float* __restrict__ rzb,
    const int* __restrict__ idx7, float* __restrict__ nrv,
    float* __restrict__ colsum) {
  __shared__ int idxs[7];
  __shared__ float attL[56];
  int t = threadIdx.x;
  int b = blockIdx.x >> 8, n = blockIdx.x & 255;
  if (t < 7) idxs[t] = idx7[(size_t)blockIdx.x * 7 + t];
  __syncthreads();
  int task = t >> 2, l4 = t & 3;
  if (task < 56) {
    int c = task / 7, j = task - c * 7;
    int d = idxs[j];
    float s = 0.f;
    if (d >= 0) {
      size_t qo = (((size_t)b * 8 + c) * 256 + n) * 64 + l4 * 16;
      size_t ko = (((size_t)b * 8 + c) * 256 + d) * 64 + l4 * 16;
      const uint4* qh4 = (const uint4*)(qhi + qo);
      const uint4* ql4 = (const uint4*)(qlo + qo);
      const uint4* kh4 = (const uint4*)(khi + ko);
      const uint4* kl4 = (const uint4*)(klo + ko);
#pragma unroll
      for (int g = 0; g < 2; g++) {
        uint4 uqh = qh4[g], uql = ql4[g], ukh = kh4[g], ukl = kl4[g];
        s += dot3_pair(uqh.x, uql.x, ukh.x, ukl.x);
        s += dot3_pair(uqh.y, uql.y, ukh.y, ukl.y);
        s += dot3_pair(uqh.z, uql.z, ukh.z, ukl.z);
        s += dot3_pair(uqh.w, uql.w, ukh.w, ukl.w);
      }
    }
    s += __shfl_xor(s, 1, 64);
    s += __shfl_xor(s, 2, 64);
    if (l4 == 0) {
      float att = 0.f;
      if (d >= 0) {
        float logit = s * 0.125f;
        att = expf(logit - mxb[((size_t)b * 8 + c) * 256 + n]) / rzb[((size_t)b * 8 + c) * 256 + n];
      }
      attL[task] = att;
    }
  }
  __syncthreads();
  if (t < 8) {
    float rs = 0.f;
#pragma unroll
    for (int j = 0; j < 7; j++) rs += attL[t * 7 + j];
    float ri = 1.0f / (rs + 1e-6f);
#pragma unroll
    for (int j = 0; j < 7; j++) {
      float nv = attL[t * 7 + j] * ri;
      nrv[(((size_t)b * 8 + t) * 256 + n) * 7 + j] = nv;
      int d = idxs[j];
      if (d >= 0) atomicAdd(&colsum[((size_t)b * 8 + t) * 256 + d], nv);
    }
  }
}

// ---------------------------------------------------------------------------
// edge[b,c,n,m] (bf16): pair-packed LDS, b128 idx/nrv reads.
// ---------------------------------------------------------------------------
__global__ __launch_bounds__(256, 3) void edge_kernel(
    const int* __restrict__ idx7, const float* __restrict__ nrv,
    const float* __restrict__ colsum, unsigned short* __restrict__ edge) {
  __shared__ unsigned short ncT[256 * 64];
  __shared__ short idxL[256 * 8];
  __shared__ float nrvL[256 * 8];
  int t = threadIdx.x;
  int blk = blockIdx.x;
  int b = blk >> 5, c = (blk >> 2) & 7, mq = blk & 3;
  int m0 = mq * 64;
  for (int i = t; i < 8192; i += 256) ((unsigned int*)ncT)[i] = 0u;
  for (int i = t; i < 2048; i += 256) {
    int r = i >> 3, j = i & 7;
    if (j < 7) {
      idxL[i] = (short)idx7[(size_t)b * 1792 + r * 7 + j];
      nrvL[i] = nrv[((size_t)b * 8 + c) * 1792 + r * 7 + j];
    } else {
      idxL[i] = -1;
      nrvL[i] = 0.f;
    }
  }
  __syncthreads();
  for (int i = t; i < 448; i += 256) {
    int mi = i / 7, j = i - mi * 7;
    int m = m0 + mi;
    int d = idxL[m * 8 + j];
    if (d >= 0) {
      float cs = colsum[((size_t)b * 8 + c) * 256 + d];
      ncT[d * 64 + mi] = f2bf(nrvL[m * 8 + j] / (cs + 1e-6f));
    }
  }
  __syncthreads();
  int wv = t >> 6, l = t & 63;
  int half = l >> 5, p = l & 31;
  const unsigned int* ncP = (const unsigned int*)ncT;
  unsigned int* eb = (unsigned int*)(edge + (((size_t)b * 8 + c) * 256) * 256);
  for (int nn = 0; nn < 32; nn++) {
    int n = nn * 8 + wv * 2 + half;
    int4 iv = *(const int4*)(idxL + n * 8);
    float4 w0 = *(const float4*)(nrvL + n * 8);
    float4 w1 = *(const float4*)(nrvL + n * 8 + 4);
    float a0 = 0.f, a1 = 0.f;
    int d;
    unsigned int pr;
    d = (int)(short)(iv.x & 0xFFFF);
    if (d >= 0) { pr = ncP[d * 32 + p]; a0 += w0.x * bf2f_lo(pr); a1 += w0.x * bf2f_hi(pr); }
    d = iv.x >> 16;
    if (d >= 0) { pr = ncP[d * 32 + p]; a0 += w0.y * bf2f_lo(pr); a1 += w0.y * bf2f_hi(pr); }
    d = (int)(short)(iv.y & 0xFFFF);
    if (d >= 0) { pr = ncP[d * 32 + p]; a0 += w0.z * bf2f_lo(pr); a1 += w0.z * bf2f_hi(pr); }
    d = iv.y >> 16;
    if (d >= 0) { pr = ncP[d * 32 + p]; a0 += w0.w * bf2f_lo(pr); a1 += w0.w * bf2f_hi(pr); }
    d = (int)(short)(iv.z & 0xFFFF);
    if (d >= 0) { pr = ncP[d * 32 + p]; a0 += w1.x * bf2f_lo(pr); a1 += w1.x * bf2f_hi(pr); }
    d = iv.z >> 16;
    if (d >= 0) { pr = ncP[d * 32 + p]; a0 += w1.y * bf2f_lo(pr); a1 += w1.y * bf2f_hi(pr); }
    d = (int)(short)(iv.w & 0xFFFF);
    if (d >= 0) { pr = ncP[d * 32 + p]; a0 += w1.z * bf2f_lo(pr); a1 += w1.z * bf2f_hi(pr); }
    unsigned int packo = (unsigned int)f2bf(a0) | ((unsigned int)f2bf(a1) << 16);
    eb[n * 128 + (m0 >> 1) + p] = packo;
  }
}

// ---------------------------------------------------------------------------
// xs = sigmoid(elu(x))
// ---------------------------------------------------------------------------
static __device__ __forceinline__ float selu1(float v) {
  float e = (v > 0.f) ? v : expm1f(v);
  return 1.0f / (1.0f + expf(-e));
}
__global__ __launch_bounds__(256) void xs_kernel(const float* __restrict__ x,
                                                 float* __restrict__ xs) {
  int i = blockIdx.x * 256 + threadIdx.x;
  float4 v = ((const float4*)x)[i];
  float4 o;
  o.x = selu1(v.x); o.y = selu1(v.y); o.z = selu1(v.z); o.w = selu1(v.w);
  ((float4*)xs)[i] = o;
}

// ---------------------------------------------------------------------------
// qg/kg = xs @ W_l^T + b_l  (R7 LDS version, grid 128)
// ---------------------------------------------------------------------------
__global__ __launch_bounds__(256, 1) void qkx_kernel(
    const float* __restrict__ xs, const float* __restrict__ gaw,
    const float* __restrict__ gab, int l, float* __restrict__ qg,
    float* __restrict__ kg) {
  __shared__ float xsL[64 * 64];
  int t = threadIdx.x;
  int b = blockIdx.x >> 2, nt = blockIdx.x & 3;
  int f = t & 63, part = t >> 6;
  float wq[64], wk[64];
  const float4* Wq4 = (const float4*)(gaw + (size_t)l * 8192 + f * 64);
  const float4* Wk4 = (const float4*)(gaw + (size_t)l * 8192 + (64 + f) * 64);
#pragma unroll
  for (int j = 0; j < 16; j++) {
    float4 aa = Wq4[j];
    wq[4 * j + 0] = aa.x; wq[4 * j + 1] = aa.y; wq[4 * j + 2] = aa.z; wq[4 * j + 3] = aa.w;
    float4 bb = Wk4[j];
    wk[4 * j + 0] = bb.x; wk[4 * j + 1] = bb.y; wk[4 * j + 2] = bb.z; wk[4 * j + 3] = bb.w;
  }
  float bq = gab[l * 128 + f], bk = gab[l * 128 + 64 + f];
  for (int i = t; i < 1024; i += 256)
    ((float4*)xsL)[i] = ((const float4*)(xs + ((size_t)b * 256 + nt * 64) * 64))[i];
  __syncthreads();
  for (int i = 0; i < 16; i++) {
    int nl = part * 16 + i;
    const float4* xr = (const float4*)(xsL + nl * 64);
    float aq = 0.f, ak = 0.f;
#pragma unroll
    for (int j = 0; j < 16; j++) {
      float4 v = xr[j];
      aq += v.x * wq[4 * j] + v.y * wq[4 * j + 1] + v.z * wq[4 * j + 2] + v.w * wq[4 * j + 3];
      ak += v.x * wk[4 * j] + v.y * wk[4 * j + 1] + v.z * wk[4 * j + 2] + v.w * wk[4 * j + 3];
    }
    int n = nt * 64 + nl;
    qg[((size_t)b * 256 + n) * 64 + f] = aq + bq;
    kg[((size_t)b * 256 + n) * 64 + f] = ak + bk;
  }
}

// ---------------------------------------------------------------------------
// ga_attn (R7 version): no LDS/barriers; (256,2); grid 256 = b*8+nt.
// ---------------------------------------------------------------------------
__global__ __launch_bounds__(256, 2) void ga_attn_kernel(
    const float* __restrict__ qg, const float* __restrict__ kgT,
    float* __restrict__ a) {
  int t = threadIdx.x;
  int b = blockIdx.x >> 3, nt = blockIdx.x & 7;
  int n0 = nt * 32;
  int wv = t >> 6, l = t & 63;
  const float* kb = kgT + (size_t)b * 16384 + 4 * l;          // [f][m]
  const float* qb = qg + ((size_t)b * 256 + n0 + wv * 8) * 64;
  float acc[8][4];
#pragma unroll
  for (int r = 0; r < 8; r++)
#pragma unroll
    for (int j = 0; j < 4; j++) acc[r][j] = 0.f;
#pragma unroll 4
  for (int kq4 = 0; kq4 < 64; kq4 += 4) {
    float4 kv0 = *(const float4*)(kb + (kq4 + 0) * 256);
    float4 kv1 = *(const float4*)(kb + (kq4 + 1) * 256);
    float4 kv2 = *(const float4*)(kb + (kq4 + 2) * 256);
    float4 kv3 = *(const float4*)(kb + (kq4 + 3) * 256);
#pragma unroll
    for (int r = 0; r < 8; r++) {
      float4 qv = *(const float4*)(qb + r * 64 + kq4);
      acc[r][0] += qv.x * kv0.x + qv.y * kv1.x + qv.z * kv2.x + qv.w * kv3.x;
      acc[r][1] += qv.x * kv0.y + qv.y * kv1.y + qv.z * kv2.y + qv.w * kv3.y;
      acc[r][2] += qv.x * kv0.z + qv.y * kv1.z + qv.z * kv2.z + qv.w * kv3.z;
      acc[r][3] += qv.x * kv0.w + qv.y * kv1.w + qv.z * kv2.w + qv.w * kv3.w;
    }
  }
#pragma unroll
  for (int r = 0; r < 8; r++) {
    float l0 = acc[r][0] * 0.125f, l1 = acc[r][1] * 0.125f;
    float l2 = acc[r][2] * 0.125f, l3 = acc[r][3] * 0.125f;
    float mx = fmaxf(fmaxf(l0, l1), fmaxf(l2, l3));
#pragma unroll
    for (int m = 1; m < 64; m <<= 1) mx = fmaxf(mx, __shfl_xor(mx, m, 64));
    float e0 = expf(l0 - mx), e1 = expf(l1 - mx), e2 = expf(l2 - mx), e3 = expf(l3 - mx);
    float z = e0 + e1 + e2 + e3;
#pragma unroll
    for (int m = 1; m < 64; m <<= 1) z += __shfl_xor(z, m, 64);
    float zi = 1.0f / z;
    int n = n0 + wv * 8 + r;
    float4 o;
    o.x = e0 * zi; o.y = e1 * zi; o.z = e2 * zi; o.w = e3 * zi;
    ((float4*)(a + ((size_t)b * 256 + n) * 256))[l] = o;
  }
}

// ---------------------------------------------------------------------------
// ne normalize + x += (ne3 @ xs)/lip
// ---------------------------------------------------------------------------
__global__ __launch_bounds__(256) void upd_kernel(
    const float* __restrict__ a, const unsigned short* __restrict__ edge,
    const float* __restrict__ xs, const float* __restrict__ gaww,
    const float* __restrict__ lipv, int l, float* __restrict__ x) {
  __shared__ float tt[4][8][256];
  __shared__ float ne3[4][256];
  __shared__ float parts[4][4][64];
  __shared__ float dred[32][8];
  __shared__ float dinv[4][8];
  __shared__ float wcL[8];
  __shared__ float lipi;
  int t = threadIdx.x;
  int b = blockIdx.x >> 6, nq = blockIdx.x & 63;
  int n0 = nq * 4;
  if (t == 0) {
    float s = 0.f;
    float wtmp[8];
    for (int c = 0; c < 8; c++) { wtmp[c] = gaww[l * 8 + c]; s += wtmp[c]; }
    for (int c = 0; c < 8; c++) wcL[c] = wtmp[c] / s;
    lipi = 1.0f / lipv[l];
  }
#pragma unroll
  for (int r = 0; r < 4; r++) {
    float av = a[((size_t)b * 256 + n0 + r) * 256 + t];
#pragma unroll
    for (int c = 0; c < 8; c++)
      tt[r][c][t] = av * bf2f(edge[(((size_t)b * 8 + c) * 256 + n0 + r) * 256 + t]);
  }
  __syncthreads();
  {
    int rc = t >> 3, i = t & 7;
    int r = rc >> 3, c = rc & 7;
    float p = 0.f;
#pragma unroll
    for (int kq = 0; kq < 32; kq++) p += tt[r][c][i + 8 * kq];
    dred[rc][i] = p;
  }
  __syncthreads();
  if (t < 32) {
    float s = 0.f;
#pragma unroll
    for (int i = 0; i < 8; i++) s += dred[t][i];
    dinv[t >> 3][t & 7] = 1.0f / (s + 1e-6f);
  }
  __syncthreads();
#pragma unroll
  for (int r = 0; r < 4; r++) {
    float s = 0.f;
#pragma unroll
    for (int c = 0; c < 8; c++) s += wcL[c] * tt[r][c][t] * dinv[r][c];
    ne3[r][t] = s;
  }
  __syncthreads();
  {
    int f = t & 63, part = t >> 6;
    float a0 = 0.f, a1 = 0.f, a2 = 0.f, a3 = 0.f;
    for (int mm = 0; mm < 64; mm++) {
      int m = part * 64 + mm;
      float xv = xs[((size_t)b * 256 + m) * 64 + f];
      a0 += ne3[0][m] * xv;
      a1 += ne3[1][m] * xv;
      a2 += ne3[2][m] * xv;
      a3 += ne3[3][m] * xv;
    }
    parts[0][part][f] = a0;
    parts[1][part][f] = a1;
    parts[2][part][f] = a2;
    parts[3][part][f] = a3;
  }
  __syncthreads();
  {
    int r = t >> 6, f = t & 63;
    float dx = parts[r][0][f] + parts[r][1][f] + parts[r][2][f] + parts[r][3][f];
    x[((size_t)b * 256 + n0 + r) * 64 + f] += dx * lipi;
  }
}

// ---------------------------------------------------------------------------
extern "C" void kernel_launch(void* const* d_in, const int* in_sizes, int n_in,
                              void* d_out, int out_size, void* d_ws, size_t ws_size,
                              hipStream_t stream) {
  (void)in_sizes; (void)n_in; (void)out_size; (void)ws_size;
  const float* fused = (const float*)d_in[0];
  const float* w1 = (const float*)d_in[1];
  const float* b1 = (const float*)d_in[2];
  const float* w2 = (const float*)d_in[3];
  const float* b2 = (const float*)d_in[4];
  const float* eqk = (const float*)d_in[5];
  const float* gaw = (const float*)d_in[6];
  const float* gab = (const float*)d_in[7];
  const float* gaww = (const float*)d_in[8];
  float* x = (float*)d_out;  // x lives in d_out (B,ND,NF)=(32,256,64); fully overwritten.
  char* ws = (char*)d_ws;
  size_t off = 0;
  auto alloc = [&](size_t bytes) -> char* {
    char* p = ws + off;
    off += (bytes + 1023) & ~(size_t)1023;
    return p;
  };
  float* invsig1 = (float*)alloc(64 * 4);
  float* invsig2 = (float*)alloc(64 * 4);
  float* lipv = (float*)alloc(2 * 4);
  float* h = (float*)alloc((size_t)32 * 64 * 64 * 4);
  unsigned short* qhi = (unsigned short*)alloc((size_t)32 * 8 * 256 * 64 * 2);
  unsigned short* qlo = (unsigned short*)alloc((size_t)32 * 8 * 256 * 64 * 2);
  unsigned short* khi = (unsigned short*)alloc((size_t)32 * 8 * 256 * 64 * 2);
  unsigned short* klo = (unsigned short*)alloc((size_t)32 * 8 * 256 * 64 * 2);
  // seP (4 partials, 33.5 MB) aliases edge (33.5 MB): seP dead after topsel.
  char* sep_edge = alloc((size_t)4 * 32 * 256 * 256 * 4);
  float* seP = (float*)sep_edge;
  unsigned short* edge = (unsigned short*)sep_edge;
  float* mxb = (float*)alloc((size_t)65536 * 4);
  float* rzb = (float*)alloc((size_t)65536 * 4);
  int* idx7 = (int*)alloc((size_t)8192 * 7 * 4);
  float* nrv = (float*)alloc((size_t)65536 * 7 * 4);
  float* colsum = (float*)alloc((size_t)65536 * 4);
  float* xs = (float*)alloc((size_t)524288 * 4);
  float* qg = (float*)alloc((size_t)524288 * 4);
  float* kg = (float*)alloc((size_t)524288 * 4);
  float* a = (float*)alloc((size_t)32 * 256 * 256 * 4);
  float* kgT = (float*)alloc((size_t)524288 * 4);

  speclip_kernel<<<130, 256, 0, stream>>>(w1, w2, gaw, invsig1, invsig2, lipv);
  h_kernel<<<512, 256, 0, stream>>>(fused, w1, b1, invsig1, h);
  conv_kernel<<<512, 256, 0, stream>>>(h, w2, b2, invsig2, x);
  qk_kernel<<<512, 256, 0, stream>>>(x, eqk, qhi, qlo, khi, klo);
  attn_kernel<<<512, 256, 0, stream>>>(qhi, qlo, khi, klo, seP, mxb, rzb);
  hipMemsetAsync(colsum, 0, (size_t)65536 * 4, stream);
  topsel_kernel<<<128, 256, 0, stream>>>(seP, idx7);
  nr_kernel<<<8192, 256, 0, stream>>>(qhi, qlo, khi, klo, mxb, rzb, idx7, nrv, colsum);
  edge_kernel<<<1024, 256, 0, stream>>>(idx7, nrv, colsum, edge);
  for (int l = 0; l < 2; l++) {
    xs_kernel<<<512, 256, 0, stream>>>(x, xs);
    qkx_kernel<<<128, 256, 0, stream>>>(xs, gaw, gab, l, qg, kg);
    transpose_kernel<<<32, 256, 0, stream>>>(kg, kgT);
    ga_attn_kernel<<<256, 256, 0, stream>>>(qg, kgT, a);
    upd_kernel<<<2048, 256, 0, stream>>>(a, edge, xs, gaww, lipv, l, x);
  }
}

// Round 14
// 421.302 us; speedup vs baseline: 1.2718x; 1.0006x over previous
//
#include <hip/hip_runtime.h>
#include <float.h>
#include <math.h>

// Problem constants: B=32, NF=64, FD=64, ND=256, C=8, K=6, L=2, scale=1/8.

typedef short bf8t __attribute__((ext_vector_type(8)));   // 8 bf16 in 4 VGPRs
typedef float f4t __attribute__((ext_vector_type(4)));

static __device__ __forceinline__ unsigned short f2bf(float x) {
  union { float f; unsigned u; } v; v.f = x;
  unsigned r = (v.u + 0x7FFFu + ((v.u >> 16) & 1u)) >> 16;
  return (unsigned short)r;
}
static __device__ __forceinline__ float bf2f(unsigned short s) {
  union { unsigned u; float f; } v; v.u = ((unsigned)s) << 16; return v.f;
}
static __device__ __forceinline__ float bf2f_lo(unsigned u) {
  union { unsigned u; float f; } v; v.u = u << 16; return v.f;
}
static __device__ __forceinline__ float bf2f_hi(unsigned u) {
  union { unsigned u; float f; } v; v.u = u & 0xFFFF0000u; return v.f;
}
// 2 packed elems of the 3-term split dot: qh*(kh+kl) + ql*kh
static __device__ __forceinline__ float dot3_pair(unsigned uqh, unsigned uql,
                                                  unsigned ukh, unsigned ukl) {
  float s = bf2f_lo(uqh) * (bf2f_lo(ukh) + bf2f_lo(ukl)) + bf2f_lo(uql) * bf2f_lo(ukh);
  s += bf2f_hi(uqh) * (bf2f_hi(ukh) + bf2f_hi(ukl)) + bf2f_hi(uql) * bf2f_hi(ukh);
  return s;
}
// split 8 fp32 into hi/lo bf16 fragments
static __device__ __forceinline__ void split8(const float* __restrict__ p,
                                              bf8t* hi, bf8t* lo) {
  float4 v0 = *(const float4*)(p);
  float4 v1 = *(const float4*)(p + 4);
  float v[8] = {v0.x, v0.y, v0.z, v0.w, v1.x, v1.y, v1.z, v1.w};
#pragma unroll
  for (int j = 0; j < 8; j++) {
    unsigned short h = f2bf(v[j]);
    (*hi)[j] = (short)h;
    (*lo)[j] = (short)f2bf(v[j] - bf2f(h));
  }
}

#define SPAD 68   // LDS row stride for speclip (16B-aligned rows)

// ---------------------------------------------------------------------------
// MFMA 64x64 row-row matmul on LDS arrays (stride SPAD), bf16 3-term split.
// C[i][j] = scale * sum_k A[i][k]*B[j][k] (+ addI * I). 4 waves; wave w owns
// rows 16w..16w+15. transposeStore: C[j][i] = v. No internal syncs; caller
// must __syncthreads() between dependent calls (C never aliases A/B here).
// ---------------------------------------------------------------------------
static __device__ __forceinline__ void mm_mfma(
    const float* __restrict__ A, const float* __restrict__ B,
    float* __restrict__ C, int t, float scale, int addI, int transposeStore) {
  int wv = t >> 6, l = t & 63;
  int m16 = l & 15, quad = l >> 4;
  bf8t ah[2], al[2];
  const float* ap = A + (size_t)(16 * wv + m16) * SPAD + quad * 8;
  split8(ap, &ah[0], &al[0]);
  split8(ap + 32, &ah[1], &al[1]);
  f4t acc[4];
#pragma unroll
  for (int ct = 0; ct < 4; ct++) {
    bf8t bh[2], bl[2];
    const float* bp = B + (size_t)(ct * 16 + m16) * SPAD + quad * 8;
    split8(bp, &bh[0], &bl[0]);
    split8(bp + 32, &bh[1], &bl[1]);
    f4t a = (f4t){0.f, 0.f, 0.f, 0.f};
    a = __builtin_amdgcn_mfma_f32_16x16x32_bf16(al[0], bh[0], a, 0, 0, 0);
    a = __builtin_amdgcn_mfma_f32_16x16x32_bf16(ah[0], bl[0], a, 0, 0, 0);
    a = __builtin_amdgcn_mfma_f32_16x16x32_bf16(ah[0], bh[0], a, 0, 0, 0);
    a = __builtin_amdgcn_mfma_f32_16x16x32_bf16(al[1], bh[1], a, 0, 0, 0);
    a = __builtin_amdgcn_mfma_f32_16x16x32_bf16(ah[1], bl[1], a, 0, 0, 0);
    a = __builtin_amdgcn_mfma_f32_16x16x32_bf16(ah[1], bh[1], a, 0, 0, 0);
    acc[ct] = a;
  }
#pragma unroll
  for (int ct = 0; ct < 4; ct++)
#pragma unroll
    for (int j = 0; j < 4; j++) {
      int i0 = 16 * wv + quad * 4 + j;
      int j0 = ct * 16 + m16;
      float v = acc[ct][j] * scale + ((addI && i0 == j0) ? 1.0f : 0.0f);
      if (transposeStore) C[(size_t)j0 * SPAD + i0] = v;
      else C[(size_t)i0 * SPAD + j0] = v;
    }
}

// Gram via MFMA: G = Ag * Ag^T (Ag 64 x ncols row-major global), staged in S.
static __device__ __forceinline__ void gram_mfma(
    const float* __restrict__ Ag, int ncols, float* __restrict__ S,
    float* __restrict__ G, int t) {
  int wv = t >> 6, l = t & 63;
  int m16 = l & 15, quad = l >> 4;
  f4t acc[4];
#pragma unroll
  for (int ct = 0; ct < 4; ct++) acc[ct] = (f4t){0.f, 0.f, 0.f, 0.f};
  for (int cc = 0; cc < ncols; cc += 64) {
    if (cc) __syncthreads();
    for (int i = t; i < 1024; i += 256) {
      int r = i >> 4, qq = i & 15;
      float4 v = *(const float4*)(Ag + (size_t)r * ncols + cc + 4 * qq);
      *(float4*)(S + (size_t)r * SPAD + 4 * qq) = v;
    }
    __syncthreads();
    bf8t ah[2], al[2];
    const float* ap = S + (size_t)(16 * wv + m16) * SPAD + quad * 8;
    split8(ap, &ah[0], &al[0]);
    split8(ap + 32, &ah[1], &al[1]);
#pragma unroll
    for (int ct = 0; ct < 4; ct++) {
      bf8t bh[2], bl[2];
      const float* bp = S + (size_t)(ct * 16 + m16) * SPAD + quad * 8;
      split8(bp, &bh[0], &bl[0]);
      split8(bp + 32, &bh[1], &bl[1]);
      f4t a = acc[ct];
      a = __builtin_amdgcn_mfma_f32_16x16x32_bf16(al[0], bh[0], a, 0, 0, 0);
      a = __builtin_amdgcn_mfma_f32_16x16x32_bf16(ah[0], bl[0], a, 0, 0, 0);
      a = __builtin_amdgcn_mfma_f32_16x16x32_bf16(ah[0], bh[0], a, 0, 0, 0);
      a = __builtin_amdgcn_mfma_f32_16x16x32_bf16(al[1], bh[1], a, 0, 0, 0);
      a = __builtin_amdgcn_mfma_f32_16x16x32_bf16(ah[1], bl[1], a, 0, 0, 0);
      a = __builtin_amdgcn_mfma_f32_16x16x32_bf16(ah[1], bh[1], a, 0, 0, 0);
      acc[ct] = a;
    }
  }
  __syncthreads();
#pragma unroll
  for (int ct = 0; ct < 4; ct++)
#pragma unroll
    for (int j = 0; j < 4; j++)
      G[(size_t)(16 * wv + quad * 4 + j) * SPAD + ct * 16 + m16] = acc[ct][j];
}

// Single-wave power iteration (4-partial ILP chains) + Rayleigh on Gm.
// Caller gates t < 64. Matrices stride SPAD.
static __device__ __forceinline__ float power_rayleigh(
    const float* __restrict__ G4m, const float* __restrict__ Gm, int iters, int i) {
  float row[64];
#pragma unroll
  for (int j = 0; j < 16; j++)
    *(float4*)(row + 4 * j) = *(const float4*)(G4m + (size_t)i * SPAD + 4 * j);
  float v = 1.0f + 0.3f * sinf(7.0f * (float)(i + 1));
  for (int it = 0; it < iters; it++) {
    float u0 = 0.f, u1 = 0.f, u2 = 0.f, u3 = 0.f;
#pragma unroll
    for (int j = 0; j < 16; j++) {
      u0 += row[4 * j + 0] * __shfl(v, 4 * j + 0, 64);
      u1 += row[4 * j + 1] * __shfl(v, 4 * j + 1, 64);
      u2 += row[4 * j + 2] * __shfl(v, 4 * j + 2, 64);
      u3 += row[4 * j + 3] * __shfl(v, 4 * j + 3, 64);
    }
    float u = (u0 + u1) + (u2 + u3);
    float ss = u * u;
#pragma unroll
    for (int m = 1; m < 64; m <<= 1) ss += __shfl_xor(ss, m, 64);
    v = u * rsqrtf(fmaxf(ss, 1e-30f));
  }
  float rowg[64];
#pragma unroll
  for (int j = 0; j < 16; j++)
    *(float4*)(rowg + 4 * j) = *(const float4*)(Gm + (size_t)i * SPAD + 4 * j);
  float u0 = 0.f, u1 = 0.f, u2 = 0.f, u3 = 0.f;
#pragma unroll
  for (int j = 0; j < 16; j++) {
    u0 += rowg[4 * j + 0] * __shfl(v, 4 * j + 0, 64);
    u1 += rowg[4 * j + 1] * __shfl(v, 4 * j + 1, 64);
    u2 += rowg[4 * j + 2] * __shfl(v, 4 * j + 2, 64);
    u3 += rowg[4 * j + 3] * __shfl(v, 4 * j + 3, 64);
  }
  float u = (u0 + u1) + (u2 + u3);
  float d = v * u;
#pragma unroll
  for (int m = 1; m < 64; m <<= 1) d += __shfl_xor(d, m, 64);
  return d;
}

// ---------------------------------------------------------------------------
// Fused spectral norms + lip: grid 130. MFMA 3-term-split matmuls.
// ---------------------------------------------------------------------------
__global__ __launch_bounds__(256) void speclip_kernel(
    const float* __restrict__ w1, const float* __restrict__ w2,
    const float* __restrict__ gaw, float* __restrict__ invsig1,
    float* __restrict__ invsig2, float* __restrict__ lipv) {
  __shared__ float Sa[64 * SPAD];
  __shared__ float Sb[64 * SPAD];
  __shared__ float G[64 * SPAD];
  int t = threadIdx.x;
  int blk = blockIdx.x;
  if (blk < 128) {
    int n = blk & 63;
    const float* A = (blk < 64) ? (w1 + (size_t)n * 4096) : (w2 + (size_t)n * 16384);
    int ncols = (blk < 64) ? 64 : 256;
    gram_mfma(A, ncols, Sa, G, t);        // G = A A^T
    __syncthreads();
    mm_mfma(G, G, Sa, t, 1.f, 0, 0);      // G2 -> Sa (G symmetric)
    __syncthreads();
    mm_mfma(Sa, Sa, Sb, t, 1.f, 0, 0);    // G4 -> Sb
    __syncthreads();
    if (t < 64) {
      float d = power_rayleigh(Sb, G, 30, t);
      if (t == 0) {
        float sg = sqrtf(fmaxf(d, 0.f));
        float inv = 1.0f / fmaxf(sg, 1e-6f);
        if (blk < 64) invsig1[n] = inv; else invsig2[n] = inv;
      }
    }
  } else {
    int l = blk - 128;
    const float* Wb = gaw + (size_t)l * 8192;
    for (int i = t; i < 1024; i += 256) {
      int r = i >> 4, qq = i & 15;
      *(float4*)(Sa + (size_t)r * SPAD + 4 * qq) = *(const float4*)(Wb + r * 64 + 4 * qq);
      *(float4*)(Sb + (size_t)r * SPAD + 4 * qq) = *(const float4*)(Wb + 4096 + r * 64 + 4 * qq);
    }
    __syncthreads();
    mm_mfma(Sa, Sb, G, t, 0.25f, 1, 1);   // Mt -> G (M = 0.25 Wq Wk^T + I, stored transposed)
    __syncthreads();
    mm_mfma(G, G, Sa, t, 1.f, 0, 0);      // Gram(M) = Mt Mt^T -> Sa
    __syncthreads();
    mm_mfma(Sa, Sa, Sb, t, 1.f, 0, 0);    // G2 -> Sb
    __syncthreads();
    mm_mfma(Sb, Sb, G, t, 1.f, 0, 0);     // G4 -> G
    __syncthreads();
    if (t < 64) {
      float d = power_rayleigh(G, Sa, 12, t);
      if (t == 0) lipv[l] = sqrtf(fmaxf(d, 0.f)) + 5.0f;
    }
  }
}

// ---------------------------------------------------------------------------
// h = gelu(fused @ w1n + b1). grid 512 = b*16+ng.
// ---------------------------------------------------------------------------
__global__ __launch_bounds__(256) void h_kernel(
    const float* __restrict__ fused, const float* __restrict__ w1,
    const float* __restrict__ b1, const float* __restrict__ invsig1,
    float* __restrict__ h) {
  __shared__ float fr[256];
  int t = threadIdx.x;
  int blk = blockIdx.x;
  int ng = blk & 15;
  fr[t] = fused[(size_t)blk * 256 + t];
  __syncthreads();
  int nl = t >> 6, j = t & 63;
  int n = ng * 4 + nl;
  float is1 = invsig1[n];
  const float* fp = fr + nl * 64;
  const float* wp = w1 + (size_t)n * 4096 + j;
  float acc = 0.f;
  for (int i = 0; i < 64; i++) acc += fp[i] * wp[i * 64];
  acc = acc * is1 + b1[n * 64 + j];
  float g = 0.5f * acc * (1.0f + erff(acc * 0.70710678118654752440f));
  h[(size_t)blk * 256 + t] = g;
}

// ---------------------------------------------------------------------------
// conv: x[b,d,n0..n0+4) = h @ w2 + b2, float4 store.
// ---------------------------------------------------------------------------
__global__ __launch_bounds__(256) void conv_kernel(
    const float* __restrict__ h, const float* __restrict__ w2,
    const float* __restrict__ b2, const float* __restrict__ invsig2,
    float* __restrict__ x) {
  __shared__ float hr[4][64];
  int t = threadIdx.x;
  int blk = blockIdx.x;
  int b = blk >> 4, ng = blk & 15;
  int n0 = ng * 4;
  {
    int r = t >> 6, i = t & 63;
    hr[r][i] = h[((size_t)b * 64 + n0 + r) * 64 + i];
  }
  __syncthreads();
  const float* w0p = w2 + ((size_t)(n0 + 0) * 64) * 256 + t;
  const float* w1p = w2 + ((size_t)(n0 + 1) * 64) * 256 + t;
  const float* w2p = w2 + ((size_t)(n0 + 2) * 64) * 256 + t;
  const float* w3p = w2 + ((size_t)(n0 + 3) * 64) * 256 + t;
  float a0 = 0.f, a1 = 0.f, a2 = 0.f, a3 = 0.f;
  for (int i = 0; i < 64; i++) {
    a0 += hr[0][i] * w0p[(size_t)i * 256];
    a1 += hr[1][i] * w1p[(size_t)i * 256];
    a2 += hr[2][i] * w2p[(size_t)i * 256];
    a3 += hr[3][i] * w3p[(size_t)i * 256];
  }
  float4 o;
  o.x = a0 * invsig2[n0 + 0] + b2[(n0 + 0) * 256 + t];
  o.y = a1 * invsig2[n0 + 1] + b2[(n0 + 1) * 256 + t];
  o.z = a2 * invsig2[n0 + 2] + b2[(n0 + 2) * 256 + t];
  o.w = a3 * invsig2[n0 + 3] + b2[(n0 + 3) * 256 + t];
  *(float4*)(x + ((size_t)b * 256 + t) * 64 + n0) = o;
}

// ---------------------------------------------------------------------------
// qk v4 (R12, proven): MFMA bf16 3-term split, grid 512 XCD-swizzled.
// ---------------------------------------------------------------------------
__global__ __launch_bounds__(256, 2) void qk_kernel(
    const float* __restrict__ x, const float* __restrict__ eqk,
    unsigned short* __restrict__ qhi, unsigned short* __restrict__ qlo,
    unsigned short* __restrict__ khi, unsigned short* __restrict__ klo) {
  int t = threadIdx.x;
  int blk = blockIdx.x;
  int xcd = blk & 7;
  int y = blk >> 3;
  int rh = y & 1;
  int c = (y >> 1) & 7;
  int b = (y >> 4) * 8 + xcd;
  int wv = t >> 6, l = t & 63;
  int m16 = l & 15, quad = l >> 4;
  int row0 = rh * 128 + wv * 32;

  bf8t ah[2][2], al[2][2];
#pragma unroll
  for (int rt = 0; rt < 2; rt++) {
    const float* xp = x + ((size_t)b * 256 + row0 + rt * 16 + m16) * 64 + quad * 8;
    split8(xp, &ah[rt][0], &al[rt][0]);
    split8(xp + 32, &ah[rt][1], &al[rt][1]);
  }
#pragma unroll
  for (int mat = 0; mat < 2; mat++) {
    const float* Wbase = eqk + ((size_t)(mat * 8 + c) * 64) * 64;
    unsigned short* ohi = mat ? khi : qhi;
    unsigned short* olo = mat ? klo : qlo;
#pragma unroll
    for (int ct = 0; ct < 4; ct++) {
      bf8t bh[2], bl[2];
      const float* wp = Wbase + (size_t)(ct * 16 + m16) * 64 + quad * 8;
      split8(wp, &bh[0], &bl[0]);
      split8(wp + 32, &bh[1], &bl[1]);
#pragma unroll
      for (int rt = 0; rt < 2; rt++) {
        f4t a = (f4t){0.f, 0.f, 0.f, 0.f};
        a = __builtin_amdgcn_mfma_f32_16x16x32_bf16(al[rt][0], bh[0], a, 0, 0, 0);
        a = __builtin_amdgcn_mfma_f32_16x16x32_bf16(ah[rt][0], bl[0], a, 0, 0, 0);
        a = __builtin_amdgcn_mfma_f32_16x16x32_bf16(ah[rt][0], bh[0], a, 0, 0, 0);
        a = __builtin_amdgcn_mfma_f32_16x16x32_bf16(al[rt][1], bh[1], a, 0, 0, 0);
        a = __builtin_amdgcn_mfma_f32_16x16x32_bf16(ah[rt][1], bl[1], a, 0, 0, 0);
        a = __builtin_amdgcn_mfma_f32_16x16x32_bf16(ah[rt][1], bh[1], a, 0, 0, 0);
#pragma unroll
        for (int j = 0; j < 4; j++) {
          int n = row0 + rt * 16 + quad * 4 + j;
          int f = ct * 16 + m16;
          size_t o = (((size_t)b * 8 + c) * 256 + n) * 64 + f;
          float v = a[j];
          unsigned short h = f2bf(v);
          ohi[o] = h;
          olo[o] = f2bf(v - bf2f(h));
        }
      }
    }
  }
}

// ---------------------------------------------------------------------------
// Generic slice transpose: in[s][n(256)][f(64)] -> out[s][f(64)][m(256)].
// (loop phase kg only)
// ---------------------------------------------------------------------------
__global__ __launch_bounds__(256, 2) void transpose_kernel(
    const float* __restrict__ in, float* __restrict__ out) {
  __shared__ float T[256 * 65];
  int t = threadIdx.x;
  size_t base = (size_t)blockIdx.x * 16384;
  const float4* in4 = (const float4*)(in + base);
  float4* out4 = (float4*)(out + base);
  for (int i = t; i < 4096; i += 256) {
    int n = i >> 4, fq = i & 15;
    float4 v = in4[i];
    float* dst = T + n * 65 + 4 * fq;
    dst[0] = v.x; dst[1] = v.y; dst[2] = v.z; dst[3] = v.w;
  }
  __syncthreads();
  for (int i = t; i < 4096; i += 256) {
    int f = i >> 6, m4 = i & 63;
    float4 o;
    o.x = T[(4 * m4 + 0) * 65 + f];
    o.y = T[(4 * m4 + 1) * 65 + f];
    o.z = T[(4 * m4 + 2) * 65 + f];
    o.w = T[(4 * m4 + 3) * 65 + f];
    out4[f * 64 + m4] = o;
  }
}

// ---------------------------------------------------------------------------
// Fused attn v7 (R13, proven): MFMA bf16 3-term split; 2 c's/block, grid 512.
// ---------------------------------------------------------------------------
__global__ __launch_bounds__(256, 2) void attn_kernel(
    const unsigned short* __restrict__ qhi, const unsigned short* __restrict__ qlo,
    const unsigned short* __restrict__ khi, const unsigned short* __restrict__ klo,
    float* __restrict__ seP, float* __restrict__ mxb, float* __restrict__ rzb) {
  int t = threadIdx.x;
  int blk = blockIdx.x;
  int xcd = blk & 7;
  int y = blk >> 3;
  int b = xcd * 4 + (y & 3);
  int cg = (y >> 2) & 3;
  int ng = y >> 4;
  int wv = t >> 6, l = t & 63;
  int m16 = l & 15, quad = l >> 4;
  int n0w = ng * 64 + wv * 16;

  f4t sum_acc[16];
#pragma unroll
  for (int mt = 0; mt < 16; mt++) sum_acc[mt] = (f4t){0.f, 0.f, 0.f, 0.f};

  for (int ci = 0; ci < 2; ci++) {
    int c = cg * 2 + ci;
    size_t sl = ((size_t)b * 8 + c) * 16384;
    const bf8t* qh = (const bf8t*)(qhi + sl + (size_t)(n0w + m16) * 64 + quad * 8);
    const bf8t* ql = (const bf8t*)(qlo + sl + (size_t)(n0w + m16) * 64 + quad * 8);
    bf8t ah0 = qh[0], ah1 = qh[4];
    bf8t al0 = ql[0], al1 = ql[4];
    f4t acc[16];
#pragma unroll
    for (int mt = 0; mt < 16; mt++) acc[mt] = (f4t){0.f, 0.f, 0.f, 0.f};
    for (int mt = 0; mt < 16; mt++) {
      const bf8t* kh = (const bf8t*)(khi + sl + (size_t)(mt * 16 + m16) * 64 + quad * 8);
      const bf8t* kl = (const bf8t*)(klo + sl + (size_t)(mt * 16 + m16) * 64 + quad * 8);
      bf8t bh0 = kh[0], bh1 = kh[4];
      bf8t bl0 = kl[0], bl1 = kl[4];
      f4t a = acc[mt];
      a = __builtin_amdgcn_mfma_f32_16x16x32_bf16(al0, bh0, a, 0, 0, 0);
      a = __builtin_amdgcn_mfma_f32_16x16x32_bf16(ah0, bl0, a, 0, 0, 0);
      a = __builtin_amdgcn_mfma_f32_16x16x32_bf16(ah0, bh0, a, 0, 0, 0);
      a = __builtin_amdgcn_mfma_f32_16x16x32_bf16(al1, bh1, a, 0, 0, 0);
      a = __builtin_amdgcn_mfma_f32_16x16x32_bf16(ah1, bl1, a, 0, 0, 0);
      a = __builtin_amdgcn_mfma_f32_16x16x32_bf16(ah1, bh1, a, 0, 0, 0);
      acc[mt] = a;
    }
#pragma unroll
    for (int j = 0; j < 4; j++) {
      float mx = -FLT_MAX;
#pragma unroll
      for (int mt = 0; mt < 16; mt++) mx = fmaxf(mx, acc[mt][j]);
      mx = fmaxf(mx, __shfl_xor(mx, 1, 64));
      mx = fmaxf(mx, __shfl_xor(mx, 2, 64));
      mx = fmaxf(mx, __shfl_xor(mx, 4, 64));
      mx = fmaxf(mx, __shfl_xor(mx, 8, 64));
      float mxl = mx * 0.125f;
      float e[16];
      float z = 0.f;
#pragma unroll
      for (int mt = 0; mt < 16; mt++) {
        e[mt] = expf(acc[mt][j] * 0.125f - mxl);
        z += e[mt];
      }
      z += __shfl_xor(z, 1, 64);
      z += __shfl_xor(z, 2, 64);
      z += __shfl_xor(z, 4, 64);
      z += __shfl_xor(z, 8, 64);
      int n = n0w + quad * 4 + j;
      if (m16 == 0) {
        mxb[((size_t)b * 8 + c) * 256 + n] = mxl;
        rzb[((size_t)b * 8 + c) * 256 + n] = z;
      }
      float zi = 1.0f / z;
#pragma unroll
      for (int mt = 0; mt < 16; mt++) sum_acc[mt][j] += e[mt] * zi;
    }
  }
#pragma unroll
  for (int mt = 0; mt < 16; mt++) {
#pragma unroll
    for (int j = 0; j < 4; j++) {
      int n = n0w + quad * 4 + j;
      seP[((size_t)(cg * 32 + b) * 256 + n) * 256 + mt * 16 + m16] = sum_acc[mt][j];
    }
  }
}

// ---------------------------------------------------------------------------
// Top-6 selection (sums 4 seP partials).
// ---------------------------------------------------------------------------
__global__ __launch_bounds__(256) void topsel_kernel(
    const float* __restrict__ seP, int* __restrict__ idx7) {
  __shared__ float seL[64 * 260];
  __shared__ float cv[64][24];
  __shared__ int cidx[64][24];
  int t = threadIdx.x;
  int b = blockIdx.x >> 2, rg = blockIdx.x & 3;
  int n0 = rg * 64;
  const float* s0 = seP + ((size_t)b * 256 + n0) * 256;
  const float* s1 = seP + ((size_t)(32 + b) * 256 + n0) * 256;
  const float* s2 = seP + ((size_t)(64 + b) * 256 + n0) * 256;
  const float* s3 = seP + ((size_t)(96 + b) * 256 + n0) * 256;
  for (int i = t; i < 4096; i += 256) {
    int m4 = i & 63, r = i >> 6;
    float4 v0 = ((const float4*)(s0 + (size_t)r * 256))[m4];
    float4 v1 = ((const float4*)(s1 + (size_t)r * 256))[m4];
    float4 v2 = ((const float4*)(s2 + (size_t)r * 256))[m4];
    float4 v3 = ((const float4*)(s3 + (size_t)r * 256))[m4];
    float4 s;
    s.x = (v0.x + v1.x) + (v2.x + v3.x);
    s.y = (v0.y + v1.y) + (v2.y + v3.y);
    s.z = (v0.z + v1.z) + (v2.z + v3.z);
    s.w = (v0.w + v1.w) + (v2.w + v3.w);
    *(float4*)(seL + r * 260 + m4 * 4) = s;
  }
  __syncthreads();
  {
    int r = t >> 2, qtr = t & 3;
    float tv[6]; int ti[6];
#pragma unroll
    for (int s = 0; s < 6; s++) { tv[s] = -FLT_MAX; ti[s] = 1 << 30; }
    for (int i = 0; i < 64; i++) {
      int m = 4 * i + qtr;
      float val = seL[r * 260 + m];
      if (val > tv[5]) {
        tv[5] = val; ti[5] = m;
#pragma unroll
        for (int s = 5; s > 0; s--) {
          if (tv[s] > tv[s - 1]) {
            float tmv = tv[s]; tv[s] = tv[s - 1]; tv[s - 1] = tmv;
            int tmi = ti[s]; ti[s] = ti[s - 1]; ti[s - 1] = tmi;
          }
        }
      }
    }
#pragma unroll
    for (int s = 0; s < 6; s++) { cv[r][qtr * 6 + s] = tv[s]; cidx[r][qtr * 6 + s] = ti[s]; }
  }
  __syncthreads();
  if (t < 64) {
    int r = t, n = n0 + r;
    int sel[7];
    for (int round = 0; round < 6; round++) {
      float best = -FLT_MAX; int bi = 1 << 30, bs = 0;
      for (int j = 0; j < 24; j++) {
        float v = cv[r][j]; int id = cidx[r][j];
        if (v > best || (v == best && id < bi)) { best = v; bi = id; bs = j; }
      }
      sel[round] = bi;
      cv[r][bs] = -FLT_MAX;
    }
    bool dup = false;
#pragma unroll
    for (int j = 0; j < 6; j++) dup = dup || (sel[j] == n);
    sel[6] = dup ? -1 : n;
#pragma unroll
    for (int j = 0; j < 7; j++) idx7[((size_t)b * 256 + n) * 7 + j] = sel[j];
  }
}

// ---------------------------------------------------------------------------
// nr values: recompute <=7 attn entries from the stored bf16 3-term split
// (consistent with attn's mxb/rzb), row-normalize, atomic colsum.
// ---------------------------------------------------------------------------
__global__ __launch_bounds__(256) void nr_kernel(
    const unsigned short* __restrict__ qhi, const unsigned short* __restrict__ qlo,
    const unsigned short* __restrict__ khi, const unsigned short* __restrict__ klo,
    const float* __restrict__ mxb, const float* __restrict__ rzb,
    const int* __restrict__ idx7, float* __restrict__ nrv,
    float* __restrict__ colsum) {
  __shared__ int idxs[7];
  __shared__ float attL[56];
  int t = threadIdx.x;
  int b = blockIdx.x >> 8, n = blockIdx.x & 255;
  if (t < 7) idxs[t] = idx7[(size_t)blockIdx.x * 7 + t];
  __syncthreads();
  int task = t >> 2, l4 = t & 3;
  if (task < 56) {
    int c = task / 7, j = task - c * 7;
    int d = idxs[j];
    float s = 0.f;
    if (d >= 0) {
      size_t qo = (((size_t)b * 8 + c) * 256 + n) * 64 + l4 * 16;
      size_t ko = (((size_t)b * 8 + c) * 256 + d) * 64 + l4 * 16;
      const uint4* qh4 = (const uint4*)(qhi + qo);
      const uint4* ql4 = (const uint4*)(qlo + qo);
      const uint4* kh4 = (const uint4*)(khi + ko);
      const uint4* kl4 = (const uint4*)(klo + ko);
#pragma unroll
      for (int g = 0; g < 2; g++) {
        uint4 uqh = qh4[g], uql = ql4[g], ukh = kh4[g], ukl = kl4[g];
        s += dot3_pair(uqh.x, uql.x, ukh.x, ukl.x);
        s += dot3_pair(uqh.y, uql.y, ukh.y, ukl.y);
        s += dot3_pair(uqh.z, uql.z, ukh.z, ukl.z);
        s += dot3_pair(uqh.w, uql.w, ukh.w, ukl.w);
      }
    }
    s += __shfl_xor(s, 1, 64);
    s += __shfl_xor(s, 2, 64);
    if (l4 == 0) {
      float att = 0.f;
      if (d >= 0) {
        float logit = s * 0.125f;
        att = expf(logit - mxb[((size_t)b * 8 + c) * 256 + n]) / rzb[((size_t)b * 8 + c) * 256 + n];
      }
      attL[task] = att;
    }
  }
  __syncthreads();
  if (t < 8) {
    float rs = 0.f;
#pragma unroll
    for (int j = 0; j < 7; j++) rs += attL[t * 7 + j];
    float ri = 1.0f / (rs + 1e-6f);
#pragma unroll
    for (int j = 0; j < 7; j++) {
      float nv = attL[t * 7 + j] * ri;
      nrv[(((size_t)b * 8 + t) * 256 + n) * 7 + j] = nv;
      int d = idxs[j];
      if (d >= 0) atomicAdd(&colsum[((size_t)b * 8 + t) * 256 + d], nv);
    }
  }
}

// ---------------------------------------------------------------------------
// edge[b,c,n,m] (bf16): pair-packed LDS, b128 idx/nrv reads.
// ---------------------------------------------------------------------------
__global__ __launch_bounds__(256, 3) void edge_kernel(
    const int* __restrict__ idx7, const float* __restrict__ nrv,
    const float* __restrict__ colsum, unsigned short* __restrict__ edge) {
  __shared__ unsigned short ncT[256 * 64];
  __shared__ short idxL[256 * 8];
  __shared__ float nrvL[256 * 8];
  int t = threadIdx.x;
  int blk = blockIdx.x;
  int b = blk >> 5, c = (blk >> 2) & 7, mq = blk & 3;
  int m0 = mq * 64;
  for (int i = t; i < 8192; i += 256) ((unsigned int*)ncT)[i] = 0u;
  for (int i = t; i < 2048; i += 256) {
    int r = i >> 3, j = i & 7;
    if (j < 7) {
      idxL[i] = (short)idx7[(size_t)b * 1792 + r * 7 + j];
      nrvL[i] = nrv[((size_t)b * 8 + c) * 1792 + r * 7 + j];
    } else {
      idxL[i] = -1;
      nrvL[i] = 0.f;
    }
  }
  __syncthreads();
  for (int i = t; i < 448; i += 256) {
    int mi = i / 7, j = i - mi * 7;
    int m = m0 + mi;
    int d = idxL[m * 8 + j];
    if (d >= 0) {
      float cs = colsum[((size_t)b * 8 + c) * 256 + d];
      ncT[d * 64 + mi] = f2bf(nrvL[m * 8 + j] / (cs + 1e-6f));
    }
  }
  __syncthreads();
  int wv = t >> 6, l = t & 63;
  int half = l >> 5, p = l & 31;
  const unsigned int* ncP = (const unsigned int*)ncT;
  unsigned int* eb = (unsigned int*)(edge + (((size_t)b * 8 + c) * 256) * 256);
  for (int nn = 0; nn < 32; nn++) {
    int n = nn * 8 + wv * 2 + half;
    int4 iv = *(const int4*)(idxL + n * 8);
    float4 w0 = *(const float4*)(nrvL + n * 8);
    float4 w1 = *(const float4*)(nrvL + n * 8 + 4);
    float a0 = 0.f, a1 = 0.f;
    int d;
    unsigned int pr;
    d = (int)(short)(iv.x & 0xFFFF);
    if (d >= 0) { pr = ncP[d * 32 + p]; a0 += w0.x * bf2f_lo(pr); a1 += w0.x * bf2f_hi(pr); }
    d = iv.x >> 16;
    if (d >= 0) { pr = ncP[d * 32 + p]; a0 += w0.y * bf2f_lo(pr); a1 += w0.y * bf2f_hi(pr); }
    d = (int)(short)(iv.y & 0xFFFF);
    if (d >= 0) { pr = ncP[d * 32 + p]; a0 += w0.z * bf2f_lo(pr); a1 += w0.z * bf2f_hi(pr); }
    d = iv.y >> 16;
    if (d >= 0) { pr = ncP[d * 32 + p]; a0 += w0.w * bf2f_lo(pr); a1 += w0.w * bf2f_hi(pr); }
    d = (int)(short)(iv.z & 0xFFFF);
    if (d >= 0) { pr = ncP[d * 32 + p]; a0 += w1.x * bf2f_lo(pr); a1 += w1.x * bf2f_hi(pr); }
    d = iv.z >> 16;
    if (d >= 0) { pr = ncP[d * 32 + p]; a0 += w1.y * bf2f_lo(pr); a1 += w1.y * bf2f_hi(pr); }
    d = (int)(short)(iv.w & 0xFFFF);
    if (d >= 0) { pr = ncP[d * 32 + p]; a0 += w1.z * bf2f_lo(pr); a1 += w1.z * bf2f_hi(pr); }
    unsigned int packo = (unsigned int)f2bf(a0) | ((unsigned int)f2bf(a1) << 16);
    eb[n * 128 + (m0 >> 1) + p] = packo;
  }
}

// ---------------------------------------------------------------------------
// xs = sigmoid(elu(x))
// ---------------------------------------------------------------------------
static __device__ __forceinline__ float selu1(float v) {
  float e = (v > 0.f) ? v : expm1f(v);
  return 1.0f / (1.0f + expf(-e));
}
__global__ __launch_bounds__(256) void xs_kernel(const float* __restrict__ x,
                                                 float* __restrict__ xs) {
  int i = blockIdx.x * 256 + threadIdx.x;
  float4 v = ((const float4*)x)[i];
  float4 o;
  o.x = selu1(v.x); o.y = selu1(v.y); o.z = selu1(v.z); o.w = selu1(v.w);
  ((float4*)xs)[i] = o;
}

// ---------------------------------------------------------------------------
// qg/kg = xs @ W_l^T + b_l  (R7 LDS version, grid 128)
// ---------------------------------------------------------------------------
__global__ __launch_bounds__(256, 1) void qkx_kernel(
    const float* __restrict__ xs, const float* __restrict__ gaw,
    const float* __restrict__ gab, int l, float* __restrict__ qg,
    float* __restrict__ kg) {
  __shared__ float xsL[64 * 64];
  int t = threadIdx.x;
  int b = blockIdx.x >> 2, nt = blockIdx.x & 3;
  int f = t & 63, part = t >> 6;
  float wq[64], wk[64];
  const float4* Wq4 = (const float4*)(gaw + (size_t)l * 8192 + f * 64);
  const float4* Wk4 = (const float4*)(gaw + (size_t)l * 8192 + (64 + f) * 64);
#pragma unroll
  for (int j = 0; j < 16; j++) {
    float4 aa = Wq4[j];
    wq[4 * j + 0] = aa.x; wq[4 * j + 1] = aa.y; wq[4 * j + 2] = aa.z; wq[4 * j + 3] = aa.w;
    float4 bb = Wk4[j];
    wk[4 * j + 0] = bb.x; wk[4 * j + 1] = bb.y; wk[4 * j + 2] = bb.z; wk[4 * j + 3] = bb.w;
  }
  float bq = gab[l * 128 + f], bk = gab[l * 128 + 64 + f];
  for (int i = t; i < 1024; i += 256)
    ((float4*)xsL)[i] = ((const float4*)(xs + ((size_t)b * 256 + nt * 64) * 64))[i];
  __syncthreads();
  for (int i = 0; i < 16; i++) {
    int nl = part * 16 + i;
    const float4* xr = (const float4*)(xsL + nl * 64);
    float aq = 0.f, ak = 0.f;
#pragma unroll
    for (int j = 0; j < 16; j++) {
      float4 v = xr[j];
      aq += v.x * wq[4 * j] + v.y * wq[4 * j + 1] + v.z * wq[4 * j + 2] + v.w * wq[4 * j + 3];
      ak += v.x * wk[4 * j] + v.y * wk[4 * j + 1] + v.z * wk[4 * j + 2] + v.w * wk[4 * j + 3];
    }
    int n = nt * 64 + nl;
    qg[((size_t)b * 256 + n) * 64 + f] = aq + bq;
    kg[((size_t)b * 256 + n) * 64 + f] = ak + bk;
  }
}

// ---------------------------------------------------------------------------
// ga_attn (R7 version): no LDS/barriers; (256,2); grid 256 = b*8+nt.
// ---------------------------------------------------------------------------
__global__ __launch_bounds__(256, 2) void ga_attn_kernel(
    const float* __restrict__ qg, const float* __restrict__ kgT,
    float* __restrict__ a) {
  int t = threadIdx.x;
  int b = blockIdx.x >> 3, nt = blockIdx.x & 7;
  int n0 = nt * 32;
  int wv = t >> 6, l = t & 63;
  const float* kb = kgT + (size_t)b * 16384 + 4 * l;          // [f][m]
  const float* qb = qg + ((size_t)b * 256 + n0 + wv * 8) * 64;
  float acc[8][4];
#pragma unroll
  for (int r = 0; r < 8; r++)
#pragma unroll
    for (int j = 0; j < 4; j++) acc[r][j] = 0.f;
#pragma unroll 4
  for (int kq4 = 0; kq4 < 64; kq4 += 4) {
    float4 kv0 = *(const float4*)(kb + (kq4 + 0) * 256);
    float4 kv1 = *(const float4*)(kb + (kq4 + 1) * 256);
    float4 kv2 = *(const float4*)(kb + (kq4 + 2) * 256);
    float4 kv3 = *(const float4*)(kb + (kq4 + 3) * 256);
#pragma unroll
    for (int r = 0; r < 8; r++) {
      float4 qv = *(const float4*)(qb + r * 64 + kq4);
      acc[r][0] += qv.x * kv0.x + qv.y * kv1.x + qv.z * kv2.x + qv.w * kv3.x;
      acc[r][1] += qv.x * kv0.y + qv.y * kv1.y + qv.z * kv2.y + qv.w * kv3.y;
      acc[r][2] += qv.x * kv0.z + qv.y * kv1.z + qv.z * kv2.z + qv.w * kv3.z;
      acc[r][3] += qv.x * kv0.w + qv.y * kv1.w + qv.z * kv2.w + qv.w * kv3.w;
    }
  }
#pragma unroll
  for (int r = 0; r < 8; r++) {
    float l0 = acc[r][0] * 0.125f, l1 = acc[r][1] * 0.125f;
    float l2 = acc[r][2] * 0.125f, l3 = acc[r][3] * 0.125f;
    float mx = fmaxf(fmaxf(l0, l1), fmaxf(l2, l3));
#pragma unroll
    for (int m = 1; m < 64; m <<= 1) mx = fmaxf(mx, __shfl_xor(mx, m, 64));
    float e0 = expf(l0 - mx), e1 = expf(l1 - mx), e2 = expf(l2 - mx), e3 = expf(l3 - mx);
    float z = e0 + e1 + e2 + e3;
#pragma unroll
    for (int m = 1; m < 64; m <<= 1) z += __shfl_xor(z, m, 64);
    float zi = 1.0f / z;
    int n = n0 + wv * 8 + r;
    float4 o;
    o.x = e0 * zi; o.y = e1 * zi; o.z = e2 * zi; o.w = e3 * zi;
    ((float4*)(a + ((size_t)b * 256 + n) * 256))[l] = o;
  }
}

// ---------------------------------------------------------------------------
// ne normalize + x += (ne3 @ xs)/lip
// ---------------------------------------------------------------------------
__global__ __launch_bounds__(256) void upd_kernel(
    const float* __restrict__ a, const unsigned short* __restrict__ edge,
    const float* __restrict__ xs, const float* __restrict__ gaww,
    const float* __restrict__ lipv, int l, float* __restrict__ x) {
  __shared__ float tt[4][8][256];
  __shared__ float ne3[4][256];
  __shared__ float parts[4][4][64];
  __shared__ float dred[32][8];
  __shared__ float dinv[4][8];
  __shared__ float wcL[8];
  __shared__ float lipi;
  int t = threadIdx.x;
  int b = blockIdx.x >> 6, nq = blockIdx.x & 63;
  int n0 = nq * 4;
  if (t == 0) {
    float s = 0.f;
    float wtmp[8];
    for (int c = 0; c < 8; c++) { wtmp[c] = gaww[l * 8 + c]; s += wtmp[c]; }
    for (int c = 0; c < 8; c++) wcL[c] = wtmp[c] / s;
    lipi = 1.0f / lipv[l];
  }
#pragma unroll
  for (int r = 0; r < 4; r++) {
    float av = a[((size_t)b * 256 + n0 + r) * 256 + t];
#pragma unroll
    for (int c = 0; c < 8; c++)
      tt[r][c][t] = av * bf2f(edge[(((size_t)b * 8 + c) * 256 + n0 + r) * 256 + t]);
  }
  __syncthreads();
  {
    int rc = t >> 3, i = t & 7;
    int r = rc >> 3, c = rc & 7;
    float p = 0.f;
#pragma unroll
    for (int kq = 0; kq < 32; kq++) p += tt[r][c][i + 8 * kq];
    dred[rc][i] = p;
  }
  __syncthreads();
  if (t < 32) {
    float s = 0.f;
#pragma unroll
    for (int i = 0; i < 8; i++) s += dred[t][i];
    dinv[t >> 3][t & 7] = 1.0f / (s + 1e-6f);
  }
  __syncthreads();
#pragma unroll
  for (int r = 0; r < 4; r++) {
    float s = 0.f;
#pragma unroll
    for (int c = 0; c < 8; c++) s += wcL[c] * tt[r][c][t] * dinv[r][c];
    ne3[r][t] = s;
  }
  __syncthreads();
  {
    int f = t & 63, part = t >> 6;
    float a0 = 0.f, a1 = 0.f, a2 = 0.f, a3 = 0.f;
    for (int mm = 0; mm < 64; mm++) {
      int m = part * 64 + mm;
      float xv = xs[((size_t)b * 256 + m) * 64 + f];
      a0 += ne3[0][m] * xv;
      a1 += ne3[1][m] * xv;
      a2 += ne3[2][m] * xv;
      a3 += ne3[3][m] * xv;
    }
    parts[0][part][f] = a0;
    parts[1][part][f] = a1;
    parts[2][part][f] = a2;
    parts[3][part][f] = a3;
  }
  __syncthreads();
  {
    int r = t >> 6, f = t & 63;
    float dx = parts[r][0][f] + parts[r][1][f] + parts[r][2][f] + parts[r][3][f];
    x[((size_t)b * 256 + n0 + r) * 64 + f] += dx * lipi;
  }
}

// ---------------------------------------------------------------------------
extern "C" void kernel_launch(void* const* d_in, const int* in_sizes, int n_in,
                              void* d_out, int out_size, void* d_ws, size_t ws_size,
                              hipStream_t stream) {
  (void)in_sizes; (void)n_in; (void)out_size; (void)ws_size;
  const float* fused = (const float*)d_in[0];
  const float* w1 = (const float*)d_in[1];
  const float* b1 = (const float*)d_in[2];
  const float* w2 = (const float*)d_in[3];
  const float* b2 = (const float*)d_in[4];
  const float* eqk = (const float*)d_in[5];
  const float* gaw = (const float*)d_in[6];
  const float* gab = (const float*)d_in[7];
  const float* gaww = (const float*)d_in[8];
  float* x = (float*)d_out;  // x lives in d_out (B,ND,NF)=(32,256,64); fully overwritten.
  char* ws = (char*)d_ws;
  size_t off = 0;
  auto alloc = [&](size_t bytes) -> char* {
    char* p = ws + off;
    off += (bytes + 1023) & ~(size_t)1023;
    return p;
  };
  float* invsig1 = (float*)alloc(64 * 4);
  float* invsig2 = (float*)alloc(64 * 4);
  float* lipv = (float*)alloc(2 * 4);
  float* h = (float*)alloc((size_t)32 * 64 * 64 * 4);
  unsigned short* qhi = (unsigned short*)alloc((size_t)32 * 8 * 256 * 64 * 2);
  unsigned short* qlo = (unsigned short*)alloc((size_t)32 * 8 * 256 * 64 * 2);
  unsigned short* khi = (unsigned short*)alloc((size_t)32 * 8 * 256 * 64 * 2);
  unsigned short* klo = (unsigned short*)alloc((size_t)32 * 8 * 256 * 64 * 2);
  // seP (4 partials, 33.5 MB) aliases edge (33.5 MB): seP dead after topsel.
  char* sep_edge = alloc((size_t)4 * 32 * 256 * 256 * 4);
  float* seP = (float*)sep_edge;
  unsigned short* edge = (unsigned short*)sep_edge;
  float* mxb = (float*)alloc((size_t)65536 * 4);
  float* rzb = (float*)alloc((size_t)65536 * 4);
  int* idx7 = (int*)alloc((size_t)8192 * 7 * 4);
  float* nrv = (float*)alloc((size_t)65536 * 7 * 4);
  float* colsum = (float*)alloc((size_t)65536 * 4);
  float* xs = (float*)alloc((size_t)524288 * 4);
  float* qg = (float*)alloc((size_t)524288 * 4);
  float* kg = (float*)alloc((size_t)524288 * 4);
  float* a = (float*)alloc((size_t)32 * 256 * 256 * 4);
  float* kgT = (float*)alloc((size_t)524288 * 4);

  speclip_kernel<<<130, 256, 0, stream>>>(w1, w2, gaw, invsig1, invsig2, lipv);
  h_kernel<<<512, 256, 0, stream>>>(fused, w1, b1, invsig1, h);
  conv_kernel<<<512, 256, 0, stream>>>(h, w2, b2, invsig2, x);
  qk_kernel<<<512, 256, 0, stream>>>(x, eqk, qhi, qlo, khi, klo);
  attn_kernel<<<512, 256, 0, stream>>>(qhi, qlo, khi, klo, seP, mxb, rzb);
  hipMemsetAsync(colsum, 0, (size_t)65536 * 4, stream);
  topsel_kernel<<<128, 256, 0, stream>>>(seP, idx7);
  nr_kernel<<<8192, 256, 0, stream>>>(qhi, qlo, khi, klo, mxb, rzb, idx7, nrv, colsum);
  edge_kernel<<<1024, 256, 0, stream>>>(idx7, nrv, colsum, edge);
  for (int l = 0; l < 2; l++) {
    xs_kernel<<<512, 256, 0, stream>>>(x, xs);
    qkx_kernel<<<128, 256, 0, stream>>>(xs, gaw, gab, l, qg, kg);
    transpose_kernel<<<32, 256, 0, stream>>>(kg, kgT);
    ga_attn_kernel<<<256, 256, 0, stream>>>(qg, kgT, a);
    upd_kernel<<<2048, 256, 0, stream>>>(a, edge, xs, gaww, lipv, l, x);
  }
}

// Round 15
// 393.222 us; speedup vs baseline: 1.3626x; 1.0714x over previous
//
#include <hip/hip_runtime.h>
#include <float.h>
#include <math.h>

// Problem constants: B=32, NF=64, FD=64, ND=256, C=8, K=6, L=2, scale=1/8.

typedef short bf8t __attribute__((ext_vector_type(8)));   // 8 bf16 in 4 VGPRs
typedef float f4t __attribute__((ext_vector_type(4)));

static __device__ __forceinline__ unsigned short f2bf(float x) {
  union { float f; unsigned u; } v; v.f = x;
  unsigned r = (v.u + 0x7FFFu + ((v.u >> 16) & 1u)) >> 16;
  return (unsigned short)r;
}
static __device__ __forceinline__ float bf2f(unsigned short s) {
  union { unsigned u; float f; } v; v.u = ((unsigned)s) << 16; return v.f;
}
static __device__ __forceinline__ float bf2f_lo(unsigned u) {
  union { unsigned u; float f; } v; v.u = u << 16; return v.f;
}
static __device__ __forceinline__ float bf2f_hi(unsigned u) {
  union { unsigned u; float f; } v; v.u = u & 0xFFFF0000u; return v.f;
}
// 2 packed elems of the 3-term split dot: qh*(kh+kl) + ql*kh
static __device__ __forceinline__ float dot3_pair(unsigned uqh, unsigned uql,
                                                  unsigned ukh, unsigned ukl) {
  float s = bf2f_lo(uqh) * (bf2f_lo(ukh) + bf2f_lo(ukl)) + bf2f_lo(uql) * bf2f_lo(ukh);
  s += bf2f_hi(uqh) * (bf2f_hi(ukh) + bf2f_hi(ukl)) + bf2f_hi(uql) * bf2f_hi(ukh);
  return s;
}
// split 8 fp32 into hi/lo bf16 fragments
static __device__ __forceinline__ void split8(const float* __restrict__ p,
                                              bf8t* hi, bf8t* lo) {
  float4 v0 = *(const float4*)(p);
  float4 v1 = *(const float4*)(p + 4);
  float v[8] = {v0.x, v0.y, v0.z, v0.w, v1.x, v1.y, v1.z, v1.w};
#pragma unroll
  for (int j = 0; j < 8; j++) {
    unsigned short h = f2bf(v[j]);
    (*hi)[j] = (short)h;
    (*lo)[j] = (short)f2bf(v[j] - bf2f(h));
  }
}

#define SPAD 68   // LDS row stride for speclip (16B-aligned rows)

// ---------------------------------------------------------------------------
// MFMA 64x64 row-row matmul on LDS (stride SPAD), bf16 3-term split.
// C[i][j] = scale*sum_k A[i][k]*B[j][k] (+addI*I). transposeStore: C[j][i].
// Caller barriers between dependent calls; C never aliases A/B.
// ---------------------------------------------------------------------------
static __device__ __forceinline__ void mm_mfma(
    const float* __restrict__ A, const float* __restrict__ B,
    float* __restrict__ C, int t, float scale, int addI, int transposeStore) {
  int wv = t >> 6, l = t & 63;
  int m16 = l & 15, quad = l >> 4;
  bf8t ah[2], al[2];
  const float* ap = A + (size_t)(16 * wv + m16) * SPAD + quad * 8;
  split8(ap, &ah[0], &al[0]);
  split8(ap + 32, &ah[1], &al[1]);
  f4t acc[4];
#pragma unroll
  for (int ct = 0; ct < 4; ct++) {
    bf8t bh[2], bl[2];
    const float* bp = B + (size_t)(ct * 16 + m16) * SPAD + quad * 8;
    split8(bp, &bh[0], &bl[0]);
    split8(bp + 32, &bh[1], &bl[1]);
    f4t a = (f4t){0.f, 0.f, 0.f, 0.f};
    a = __builtin_amdgcn_mfma_f32_16x16x32_bf16(al[0], bh[0], a, 0, 0, 0);
    a = __builtin_amdgcn_mfma_f32_16x16x32_bf16(ah[0], bl[0], a, 0, 0, 0);
    a = __builtin_amdgcn_mfma_f32_16x16x32_bf16(ah[0], bh[0], a, 0, 0, 0);
    a = __builtin_amdgcn_mfma_f32_16x16x32_bf16(al[1], bh[1], a, 0, 0, 0);
    a = __builtin_amdgcn_mfma_f32_16x16x32_bf16(ah[1], bl[1], a, 0, 0, 0);
    a = __builtin_amdgcn_mfma_f32_16x16x32_bf16(ah[1], bh[1], a, 0, 0, 0);
    acc[ct] = a;
  }
#pragma unroll
  for (int ct = 0; ct < 4; ct++)
#pragma unroll
    for (int j = 0; j < 4; j++) {
      int i0 = 16 * wv + quad * 4 + j;
      int j0 = ct * 16 + m16;
      float v = acc[ct][j] * scale + ((addI && i0 == j0) ? 1.0f : 0.0f);
      if (transposeStore) C[(size_t)j0 * SPAD + i0] = v;
      else C[(size_t)i0 * SPAD + j0] = v;
    }
}

// Squaring with max-normalization: C = (A A^T) / maxabs (A symmetric -> A^2).
// redm = LDS float[4] scratch. Internal barrier; caller barriers after.
static __device__ __forceinline__ void mm_sq_norm(
    const float* __restrict__ A, float* __restrict__ C, int t,
    float* __restrict__ redm) {
  int wv = t >> 6, l = t & 63;
  int m16 = l & 15, quad = l >> 4;
  bf8t ah[2], al[2];
  const float* ap = A + (size_t)(16 * wv + m16) * SPAD + quad * 8;
  split8(ap, &ah[0], &al[0]);
  split8(ap + 32, &ah[1], &al[1]);
  f4t acc[4];
#pragma unroll
  for (int ct = 0; ct < 4; ct++) {
    bf8t bh[2], bl[2];
    const float* bp = A + (size_t)(ct * 16 + m16) * SPAD + quad * 8;
    split8(bp, &bh[0], &bl[0]);
    split8(bp + 32, &bh[1], &bl[1]);
    f4t a = (f4t){0.f, 0.f, 0.f, 0.f};
    a = __builtin_amdgcn_mfma_f32_16x16x32_bf16(al[0], bh[0], a, 0, 0, 0);
    a = __builtin_amdgcn_mfma_f32_16x16x32_bf16(ah[0], bl[0], a, 0, 0, 0);
    a = __builtin_amdgcn_mfma_f32_16x16x32_bf16(ah[0], bh[0], a, 0, 0, 0);
    a = __builtin_amdgcn_mfma_f32_16x16x32_bf16(al[1], bh[1], a, 0, 0, 0);
    a = __builtin_amdgcn_mfma_f32_16x16x32_bf16(ah[1], bl[1], a, 0, 0, 0);
    a = __builtin_amdgcn_mfma_f32_16x16x32_bf16(ah[1], bh[1], a, 0, 0, 0);
    acc[ct] = a;
  }
  float mx = 0.f;
#pragma unroll
  for (int ct = 0; ct < 4; ct++)
#pragma unroll
    for (int j = 0; j < 4; j++) mx = fmaxf(mx, fabsf(acc[ct][j]));
#pragma unroll
  for (int m = 1; m < 64; m <<= 1) mx = fmaxf(mx, __shfl_xor(mx, m, 64));
  if (l == 0) redm[wv] = mx;
  __syncthreads();
  float gmx = fmaxf(fmaxf(redm[0], redm[1]), fmaxf(redm[2], redm[3]));
  float sc = 1.0f / fmaxf(gmx, 1e-30f);
#pragma unroll
  for (int ct = 0; ct < 4; ct++)
#pragma unroll
    for (int j = 0; j < 4; j++)
      C[(size_t)(16 * wv + quad * 4 + j) * SPAD + ct * 16 + m16] = acc[ct][j] * sc;
}

// Gram via MFMA: G = Ag * Ag^T (Ag 64 x ncols row-major global), staged in S.
static __device__ __forceinline__ void gram_mfma(
    const float* __restrict__ Ag, int ncols, float* __restrict__ S,
    float* __restrict__ G, int t) {
  int wv = t >> 6, l = t & 63;
  int m16 = l & 15, quad = l >> 4;
  f4t acc[4];
#pragma unroll
  for (int ct = 0; ct < 4; ct++) acc[ct] = (f4t){0.f, 0.f, 0.f, 0.f};
  for (int cc = 0; cc < ncols; cc += 64) {
    if (cc) __syncthreads();
    for (int i = t; i < 1024; i += 256) {
      int r = i >> 4, qq = i & 15;
      float4 v = *(const float4*)(Ag + (size_t)r * ncols + cc + 4 * qq);
      *(float4*)(S + (size_t)r * SPAD + 4 * qq) = v;
    }
    __syncthreads();
    bf8t ah[2], al[2];
    const float* ap = S + (size_t)(16 * wv + m16) * SPAD + quad * 8;
    split8(ap, &ah[0], &al[0]);
    split8(ap + 32, &ah[1], &al[1]);
#pragma unroll
    for (int ct = 0; ct < 4; ct++) {
      bf8t bh[2], bl[2];
      const float* bp = S + (size_t)(ct * 16 + m16) * SPAD + quad * 8;
      split8(bp, &bh[0], &bl[0]);
      split8(bp + 32, &bh[1], &bl[1]);
      f4t a = acc[ct];
      a = __builtin_amdgcn_mfma_f32_16x16x32_bf16(al[0], bh[0], a, 0, 0, 0);
      a = __builtin_amdgcn_mfma_f32_16x16x32_bf16(ah[0], bl[0], a, 0, 0, 0);
      a = __builtin_amdgcn_mfma_f32_16x16x32_bf16(ah[0], bh[0], a, 0, 0, 0);
      a = __builtin_amdgcn_mfma_f32_16x16x32_bf16(al[1], bh[1], a, 0, 0, 0);
      a = __builtin_amdgcn_mfma_f32_16x16x32_bf16(ah[1], bl[1], a, 0, 0, 0);
      a = __builtin_amdgcn_mfma_f32_16x16x32_bf16(ah[1], bh[1], a, 0, 0, 0);
      acc[ct] = a;
    }
  }
  __syncthreads();
#pragma unroll
  for (int ct = 0; ct < 4; ct++)
#pragma unroll
    for (int j = 0; j < 4; j++)
      G[(size_t)(16 * wv + quad * 4 + j) * SPAD + ct * 16 + m16] = acc[ct][j];
}

// Single-wave power iteration (4-partial ILP) + Rayleigh on Gm (t < 64).
static __device__ __forceinline__ float power_rayleigh(
    const float* __restrict__ G4m, const float* __restrict__ Gm, int iters, int i) {
  float row[64];
#pragma unroll
  for (int j = 0; j < 16; j++)
    *(float4*)(row + 4 * j) = *(const float4*)(G4m + (size_t)i * SPAD + 4 * j);
  float v = 1.0f + 0.3f * sinf(7.0f * (float)(i + 1));
  for (int it = 0; it < iters; it++) {
    float u0 = 0.f, u1 = 0.f, u2 = 0.f, u3 = 0.f;
#pragma unroll
    for (int j = 0; j < 16; j++) {
      u0 += row[4 * j + 0] * __shfl(v, 4 * j + 0, 64);
      u1 += row[4 * j + 1] * __shfl(v, 4 * j + 1, 64);
      u2 += row[4 * j + 2] * __shfl(v, 4 * j + 2, 64);
      u3 += row[4 * j + 3] * __shfl(v, 4 * j + 3, 64);
    }
    float u = (u0 + u1) + (u2 + u3);
    float ss = u * u;
#pragma unroll
    for (int m = 1; m < 64; m <<= 1) ss += __shfl_xor(ss, m, 64);
    v = u * rsqrtf(fmaxf(ss, 1e-30f));
  }
  float rowg[64];
#pragma unroll
  for (int j = 0; j < 16; j++)
    *(float4*)(rowg + 4 * j) = *(const float4*)(Gm + (size_t)i * SPAD + 4 * j);
  float u0 = 0.f, u1 = 0.f, u2 = 0.f, u3 = 0.f;
#pragma unroll
  for (int j = 0; j < 16; j++) {
    u0 += rowg[4 * j + 0] * __shfl(v, 4 * j + 0, 64);
    u1 += rowg[4 * j + 1] * __shfl(v, 4 * j + 1, 64);
    u2 += rowg[4 * j + 2] * __shfl(v, 4 * j + 2, 64);
    u3 += rowg[4 * j + 3] * __shfl(v, 4 * j + 3, 64);
  }
  float u = (u0 + u1) + (u2 + u3);
  float d = v * u;
#pragma unroll
  for (int m = 1; m < 64; m <<= 1) d += __shfl_xor(d, m, 64);
  return d;
}

// ---------------------------------------------------------------------------
// Fused spectral norms + lip: grid 130. Repeated squaring (log-depth) replaces
// the 30-iter latency-bound power loop: S = G^128 via 6 normalized squarings,
// then 2 power iters on S (effective power 256 > previous 120).
// ---------------------------------------------------------------------------
__global__ __launch_bounds__(256) void speclip_kernel(
    const float* __restrict__ w1, const float* __restrict__ w2,
    const float* __restrict__ gaw, float* __restrict__ invsig1,
    float* __restrict__ invsig2, float* __restrict__ lipv) {
  __shared__ float Sa[64 * SPAD];
  __shared__ float Sb[64 * SPAD];
  __shared__ float G[64 * SPAD];
  __shared__ float redm[4];
  int t = threadIdx.x;
  int blk = blockIdx.x;
  if (blk < 128) {
    int n = blk & 63;
    const float* A = (blk < 64) ? (w1 + (size_t)n * 4096) : (w2 + (size_t)n * 16384);
    int ncols = (blk < 64) ? 64 : 256;
    gram_mfma(A, ncols, Sa, G, t);        // G = A A^T (kept for Rayleigh)
    __syncthreads();
    mm_mfma(G, G, Sa, t, 1.f, 0, 0);      // G^2 -> Sa
    __syncthreads();
    mm_sq_norm(Sa, Sb, t, redm);  __syncthreads();  // G^4   -> Sb
    mm_sq_norm(Sb, Sa, t, redm);  __syncthreads();  // G^8   -> Sa
    mm_sq_norm(Sa, Sb, t, redm);  __syncthreads();  // G^16  -> Sb
    mm_sq_norm(Sb, Sa, t, redm);  __syncthreads();  // G^32  -> Sa
    mm_sq_norm(Sa, Sb, t, redm);  __syncthreads();  // G^64  -> Sb
    mm_sq_norm(Sb, Sa, t, redm);  __syncthreads();  // G^128 -> Sa
    if (t < 64) {
      float d = power_rayleigh(Sa, G, 2, t);
      if (t == 0) {
        float sg = sqrtf(fmaxf(d, 0.f));
        float inv = 1.0f / fmaxf(sg, 1e-6f);
        if (blk < 64) invsig1[n] = inv; else invsig2[n] = inv;
      }
    }
  } else {
    int l = blk - 128;
    const float* Wb = gaw + (size_t)l * 8192;
    for (int i = t; i < 1024; i += 256) {
      int r = i >> 4, qq = i & 15;
      *(float4*)(Sa + (size_t)r * SPAD + 4 * qq) = *(const float4*)(Wb + r * 64 + 4 * qq);
      *(float4*)(Sb + (size_t)r * SPAD + 4 * qq) = *(const float4*)(Wb + 4096 + r * 64 + 4 * qq);
    }
    __syncthreads();
    mm_mfma(Sa, Sb, G, t, 0.25f, 1, 1);   // Mt -> G (M = 0.25 Wq Wk^T + I, transposed)
    __syncthreads();
    mm_mfma(G, G, Sa, t, 1.f, 0, 0);      // M^T M -> Sa (kept for Rayleigh)
    __syncthreads();
    mm_sq_norm(Sa, Sb, t, redm);  __syncthreads();  // ^2  -> Sb
    mm_sq_norm(Sb, G, t, redm);   __syncthreads();  // ^4  -> G (Mt dead)
    mm_sq_norm(G, Sb, t, redm);   __syncthreads();  // ^8  -> Sb
    mm_sq_norm(Sb, G, t, redm);   __syncthreads();  // ^16 -> G
    mm_sq_norm(G, Sb, t, redm);   __syncthreads();  // ^32 -> Sb
    mm_sq_norm(Sb, G, t, redm);   __syncthreads();  // ^64 -> G
    if (t < 64) {
      float d = power_rayleigh(G, Sa, 2, t);
      if (t == 0) lipv[l] = sqrtf(fmaxf(d, 0.f)) + 5.0f;
    }
  }
}

// ---------------------------------------------------------------------------
// h = gelu(fused @ w1n + b1). grid 512 = b*16+ng.
// ---------------------------------------------------------------------------
__global__ __launch_bounds__(256) void h_kernel(
    const float* __restrict__ fused, const float* __restrict__ w1,
    const float* __restrict__ b1, const float* __restrict__ invsig1,
    float* __restrict__ h) {
  __shared__ float fr[256];
  int t = threadIdx.x;
  int blk = blockIdx.x;
  int ng = blk & 15;
  fr[t] = fused[(size_t)blk * 256 + t];
  __syncthreads();
  int nl = t >> 6, j = t & 63;
  int n = ng * 4 + nl;
  float is1 = invsig1[n];
  const float* fp = fr + nl * 64;
  const float* wp = w1 + (size_t)n * 4096 + j;
  float acc = 0.f;
  for (int i = 0; i < 64; i++) acc += fp[i] * wp[i * 64];
  acc = acc * is1 + b1[n * 64 + j];
  float g = 0.5f * acc * (1.0f + erff(acc * 0.70710678118654752440f));
  h[(size_t)blk * 256 + t] = g;
}

// ---------------------------------------------------------------------------
// conv: x[b,d,n0..n0+4) = h @ w2 + b2, float4 store.
// ---------------------------------------------------------------------------
__global__ __launch_bounds__(256) void conv_kernel(
    const float* __restrict__ h, const float* __restrict__ w2,
    const float* __restrict__ b2, const float* __restrict__ invsig2,
    float* __restrict__ x) {
  __shared__ float hr[4][64];
  int t = threadIdx.x;
  int blk = blockIdx.x;
  int b = blk >> 4, ng = blk & 15;
  int n0 = ng * 4;
  {
    int r = t >> 6, i = t & 63;
    hr[r][i] = h[((size_t)b * 64 + n0 + r) * 64 + i];
  }
  __syncthreads();
  const float* w0p = w2 + ((size_t)(n0 + 0) * 64) * 256 + t;
  const float* w1p = w2 + ((size_t)(n0 + 1) * 64) * 256 + t;
  const float* w2p = w2 + ((size_t)(n0 + 2) * 64) * 256 + t;
  const float* w3p = w2 + ((size_t)(n0 + 3) * 64) * 256 + t;
  float a0 = 0.f, a1 = 0.f, a2 = 0.f, a3 = 0.f;
  for (int i = 0; i < 64; i++) {
    a0 += hr[0][i] * w0p[(size_t)i * 256];
    a1 += hr[1][i] * w1p[(size_t)i * 256];
    a2 += hr[2][i] * w2p[(size_t)i * 256];
    a3 += hr[3][i] * w3p[(size_t)i * 256];
  }
  float4 o;
  o.x = a0 * invsig2[n0 + 0] + b2[(n0 + 0) * 256 + t];
  o.y = a1 * invsig2[n0 + 1] + b2[(n0 + 1) * 256 + t];
  o.z = a2 * invsig2[n0 + 2] + b2[(n0 + 2) * 256 + t];
  o.w = a3 * invsig2[n0 + 3] + b2[(n0 + 3) * 256 + t];
  *(float4*)(x + ((size_t)b * 256 + t) * 64 + n0) = o;
}

// ---------------------------------------------------------------------------
// qk v4 (R12, proven): MFMA bf16 3-term split, grid 512 XCD-swizzled.
// ---------------------------------------------------------------------------
__global__ __launch_bounds__(256, 2) void qk_kernel(
    const float* __restrict__ x, const float* __restrict__ eqk,
    unsigned short* __restrict__ qhi, unsigned short* __restrict__ qlo,
    unsigned short* __restrict__ khi, unsigned short* __restrict__ klo) {
  int t = threadIdx.x;
  int blk = blockIdx.x;
  int xcd = blk & 7;
  int y = blk >> 3;
  int rh = y & 1;
  int c = (y >> 1) & 7;
  int b = (y >> 4) * 8 + xcd;
  int wv = t >> 6, l = t & 63;
  int m16 = l & 15, quad = l >> 4;
  int row0 = rh * 128 + wv * 32;

  bf8t ah[2][2], al[2][2];
#pragma unroll
  for (int rt = 0; rt < 2; rt++) {
    const float* xp = x + ((size_t)b * 256 + row0 + rt * 16 + m16) * 64 + quad * 8;
    split8(xp, &ah[rt][0], &al[rt][0]);
    split8(xp + 32, &ah[rt][1], &al[rt][1]);
  }
#pragma unroll
  for (int mat = 0; mat < 2; mat++) {
    const float* Wbase = eqk + ((size_t)(mat * 8 + c) * 64) * 64;
    unsigned short* ohi = mat ? khi : qhi;
    unsigned short* olo = mat ? klo : qlo;
#pragma unroll
    for (int ct = 0; ct < 4; ct++) {
      bf8t bh[2], bl[2];
      const float* wp = Wbase + (size_t)(ct * 16 + m16) * 64 + quad * 8;
      split8(wp, &bh[0], &bl[0]);
      split8(wp + 32, &bh[1], &bl[1]);
#pragma unroll
      for (int rt = 0; rt < 2; rt++) {
        f4t a = (f4t){0.f, 0.f, 0.f, 0.f};
        a = __builtin_amdgcn_mfma_f32_16x16x32_bf16(al[rt][0], bh[0], a, 0, 0, 0);
        a = __builtin_amdgcn_mfma_f32_16x16x32_bf16(ah[rt][0], bl[0], a, 0, 0, 0);
        a = __builtin_amdgcn_mfma_f32_16x16x32_bf16(ah[rt][0], bh[0], a, 0, 0, 0);
        a = __builtin_amdgcn_mfma_f32_16x16x32_bf16(al[rt][1], bh[1], a, 0, 0, 0);
        a = __builtin_amdgcn_mfma_f32_16x16x32_bf16(ah[rt][1], bl[1], a, 0, 0, 0);
        a = __builtin_amdgcn_mfma_f32_16x16x32_bf16(ah[rt][1], bh[1], a, 0, 0, 0);
#pragma unroll
        for (int j = 0; j < 4; j++) {
          int n = row0 + rt * 16 + quad * 4 + j;
          int f = ct * 16 + m16;
          size_t o = (((size_t)b * 8 + c) * 256 + n) * 64 + f;
          float v = a[j];
          unsigned short hh = f2bf(v);
          ohi[o] = hh;
          olo[o] = f2bf(v - bf2f(hh));
        }
      }
    }
  }
}

// ---------------------------------------------------------------------------
// Generic slice transpose: in[s][n(256)][f(64)] -> out[s][f(64)][m(256)].
// (loop phase kg only)
// ---------------------------------------------------------------------------
__global__ __launch_bounds__(256, 2) void transpose_kernel(
    const float* __restrict__ in, float* __restrict__ out) {
  __shared__ float T[256 * 65];
  int t = threadIdx.x;
  size_t base = (size_t)blockIdx.x * 16384;
  const float4* in4 = (const float4*)(in + base);
  float4* out4 = (float4*)(out + base);
  for (int i = t; i < 4096; i += 256) {
    int n = i >> 4, fq = i & 15;
    float4 v = in4[i];
    float* dst = T + n * 65 + 4 * fq;
    dst[0] = v.x; dst[1] = v.y; dst[2] = v.z; dst[3] = v.w;
  }
  __syncthreads();
  for (int i = t; i < 4096; i += 256) {
    int f = i >> 6, m4 = i & 63;
    float4 o;
    o.x = T[(4 * m4 + 0) * 65 + f];
    o.y = T[(4 * m4 + 1) * 65 + f];
    o.z = T[(4 * m4 + 2) * 65 + f];
    o.w = T[(4 * m4 + 3) * 65 + f];
    out4[f * 64 + m4] = o;
  }
}

// ---------------------------------------------------------------------------
// Fused attn v7 (R13, proven): MFMA bf16 3-term split; 2 c's/block, grid 512.
// ---------------------------------------------------------------------------
__global__ __launch_bounds__(256, 2) void attn_kernel(
    const unsigned short* __restrict__ qhi, const unsigned short* __restrict__ qlo,
    const unsigned short* __restrict__ khi, const unsigned short* __restrict__ klo,
    float* __restrict__ seP, float* __restrict__ mxb, float* __restrict__ rzb) {
  int t = threadIdx.x;
  int blk = blockIdx.x;
  int xcd = blk & 7;
  int y = blk >> 3;
  int b = xcd * 4 + (y & 3);
  int cg = (y >> 2) & 3;
  int ng = y >> 4;
  int wv = t >> 6, l = t & 63;
  int m16 = l & 15, quad = l >> 4;
  int n0w = ng * 64 + wv * 16;

  f4t sum_acc[16];
#pragma unroll
  for (int mt = 0; mt < 16; mt++) sum_acc[mt] = (f4t){0.f, 0.f, 0.f, 0.f};

  for (int ci = 0; ci < 2; ci++) {
    int c = cg * 2 + ci;
    size_t sl = ((size_t)b * 8 + c) * 16384;
    const bf8t* qh = (const bf8t*)(qhi + sl + (size_t)(n0w + m16) * 64 + quad * 8);
    const bf8t* ql = (const bf8t*)(qlo + sl + (size_t)(n0w + m16) * 64 + quad * 8);
    bf8t ah0 = qh[0], ah1 = qh[4];
    bf8t al0 = ql[0], al1 = ql[4];
    f4t acc[16];
#pragma unroll
    for (int mt = 0; mt < 16; mt++) acc[mt] = (f4t){0.f, 0.f, 0.f, 0.f};
    for (int mt = 0; mt < 16; mt++) {
      const bf8t* kh = (const bf8t*)(khi + sl + (size_t)(mt * 16 + m16) * 64 + quad * 8);
      const bf8t* kl = (const bf8t*)(klo + sl + (size_t)(mt * 16 + m16) * 64 + quad * 8);
      bf8t bh0 = kh[0], bh1 = kh[4];
      bf8t bl0 = kl[0], bl1 = kl[4];
      f4t a = acc[mt];
      a = __builtin_amdgcn_mfma_f32_16x16x32_bf16(al0, bh0, a, 0, 0, 0);
      a = __builtin_amdgcn_mfma_f32_16x16x32_bf16(ah0, bl0, a, 0, 0, 0);
      a = __builtin_amdgcn_mfma_f32_16x16x32_bf16(ah0, bh0, a, 0, 0, 0);
      a = __builtin_amdgcn_mfma_f32_16x16x32_bf16(al1, bh1, a, 0, 0, 0);
      a = __builtin_amdgcn_mfma_f32_16x16x32_bf16(ah1, bl1, a, 0, 0, 0);
      a = __builtin_amdgcn_mfma_f32_16x16x32_bf16(ah1, bh1, a, 0, 0, 0);
      acc[mt] = a;
    }
#pragma unroll
    for (int j = 0; j < 4; j++) {
      float mx = -FLT_MAX;
#pragma unroll
      for (int mt = 0; mt < 16; mt++) mx = fmaxf(mx, acc[mt][j]);
      mx = fmaxf(mx, __shfl_xor(mx, 1, 64));
      mx = fmaxf(mx, __shfl_xor(mx, 2, 64));
      mx = fmaxf(mx, __shfl_xor(mx, 4, 64));
      mx = fmaxf(mx, __shfl_xor(mx, 8, 64));
      float mxl = mx * 0.125f;
      float e[16];
      float z = 0.f;
#pragma unroll
      for (int mt = 0; mt < 16; mt++) {
        e[mt] = expf(acc[mt][j] * 0.125f - mxl);
        z += e[mt];
      }
      z += __shfl_xor(z, 1, 64);
      z += __shfl_xor(z, 2, 64);
      z += __shfl_xor(z, 4, 64);
      z += __shfl_xor(z, 8, 64);
      int n = n0w + quad * 4 + j;
      if (m16 == 0) {
        mxb[((size_t)b * 8 + c) * 256 + n] = mxl;
        rzb[((size_t)b * 8 + c) * 256 + n] = z;
      }
      float zi = 1.0f / z;
#pragma unroll
      for (int mt = 0; mt < 16; mt++) sum_acc[mt][j] += e[mt] * zi;
    }
  }
#pragma unroll
  for (int mt = 0; mt < 16; mt++) {
#pragma unroll
    for (int j = 0; j < 4; j++) {
      int n = n0w + quad * 4 + j;
      seP[((size_t)(cg * 32 + b) * 256 + n) * 256 + mt * 16 + m16] = sum_acc[mt][j];
    }
  }
}

// ---------------------------------------------------------------------------
// Top-6 selection (sums 4 seP partials).
// ---------------------------------------------------------------------------
__global__ __launch_bounds__(256) void topsel_kernel(
    const float* __restrict__ seP, int* __restrict__ idx7) {
  __shared__ float seL[64 * 260];
  __shared__ float cv[64][24];
  __shared__ int cidx[64][24];
  int t = threadIdx.x;
  int b = blockIdx.x >> 2, rg = blockIdx.x & 3;
  int n0 = rg * 64;
  const float* s0 = seP + ((size_t)b * 256 + n0) * 256;
  const float* s1 = seP + ((size_t)(32 + b) * 256 + n0) * 256;
  const float* s2 = seP + ((size_t)(64 + b) * 256 + n0) * 256;
  const float* s3 = seP + ((size_t)(96 + b) * 256 + n0) * 256;
  for (int i = t; i < 4096; i += 256) {
    int m4 = i & 63, r = i >> 6;
    float4 v0 = ((const float4*)(s0 + (size_t)r * 256))[m4];
    float4 v1 = ((const float4*)(s1 + (size_t)r * 256))[m4];
    float4 v2 = ((const float4*)(s2 + (size_t)r * 256))[m4];
    float4 v3 = ((const float4*)(s3 + (size_t)r * 256))[m4];
    float4 s;
    s.x = (v0.x + v1.x) + (v2.x + v3.x);
    s.y = (v0.y + v1.y) + (v2.y + v3.y);
    s.z = (v0.z + v1.z) + (v2.z + v3.z);
    s.w = (v0.w + v1.w) + (v2.w + v3.w);
    *(float4*)(seL + r * 260 + m4 * 4) = s;
  }
  __syncthreads();
  {
    int r = t >> 2, qtr = t & 3;
    float tv[6]; int ti[6];
#pragma unroll
    for (int s = 0; s < 6; s++) { tv[s] = -FLT_MAX; ti[s] = 1 << 30; }
    for (int i = 0; i < 64; i++) {
      int m = 4 * i + qtr;
      float val = seL[r * 260 + m];
      if (val > tv[5]) {
        tv[5] = val; ti[5] = m;
#pragma unroll
        for (int s = 5; s > 0; s--) {
          if (tv[s] > tv[s - 1]) {
            float tmv = tv[s]; tv[s] = tv[s - 1]; tv[s - 1] = tmv;
            int tmi = ti[s]; ti[s] = ti[s - 1]; ti[s - 1] = tmi;
          }
        }
      }
    }
#pragma unroll
    for (int s = 0; s < 6; s++) { cv[r][qtr * 6 + s] = tv[s]; cidx[r][qtr * 6 + s] = ti[s]; }
  }
  __syncthreads();
  if (t < 64) {
    int r = t, n = n0 + r;
    int sel[7];
    for (int round = 0; round < 6; round++) {
      float best = -FLT_MAX; int bi = 1 << 30, bs = 0;
      for (int j = 0; j < 24; j++) {
        float v = cv[r][j]; int id = cidx[r][j];
        if (v > best || (v == best && id < bi)) { best = v; bi = id; bs = j; }
      }
      sel[round] = bi;
      cv[r][bs] = -FLT_MAX;
    }
    bool dup = false;
#pragma unroll
    for (int j = 0; j < 6; j++) dup = dup || (sel[j] == n);
    sel[6] = dup ? -1 : n;
#pragma unroll
    for (int j = 0; j < 7; j++) idx7[((size_t)b * 256 + n) * 7 + j] = sel[j];
  }
}

// ---------------------------------------------------------------------------
// nr values: recompute <=7 attn entries from the stored bf16 3-term split
// (consistent with attn's mxb/rzb), row-normalize, atomic colsum.
// ---------------------------------------------------------------------------
__global__ __launch_bounds__(256) void nr_kernel(
    const unsigned short* __restrict__ qhi, const unsigned short* __restrict__ qlo,
    const unsigned short* __restrict__ khi, const unsigned short* __restrict__ klo,
    const float* __restrict__ mxb, const float* __restrict__ rzb,
    const int* __restrict__ idx7, float* __restrict__ nrv,
    float* __restrict__ colsum) {
  __shared__ int idxs[7];
  __shared__ float attL[56];
  int t = threadIdx.x;
  int b = blockIdx.x >> 8, n = blockIdx.x & 255;
  if (t < 7) idxs[t] = idx7[(size_t)blockIdx.x * 7 + t];
  __syncthreads();
  int task = t >> 2, l4 = t & 3;
  if (task < 56) {
    int c = task / 7, j = task - c * 7;
    int d = idxs[j];
    float s = 0.f;
    if (d >= 0) {
      size_t qo = (((size_t)b * 8 + c) * 256 + n) * 64 + l4 * 16;
      size_t ko = (((size_t)b * 8 + c) * 256 + d) * 64 + l4 * 16;
      const uint4* qh4 = (const uint4*)(qhi + qo);
      const uint4* ql4 = (const uint4*)(qlo + qo);
      const uint4* kh4 = (const uint4*)(khi + ko);
      const uint4* kl4 = (const uint4*)(klo + ko);
#pragma unroll
      for (int g = 0; g < 2; g++) {
        uint4 uqh = qh4[g], uql = ql4[g], ukh = kh4[g], ukl = kl4[g];
        s += dot3_pair(uqh.x, uql.x, ukh.x, ukl.x);
        s += dot3_pair(uqh.y, uql.y, ukh.y, ukl.y);
        s += dot3_pair(uqh.z, uql.z, ukh.z, ukl.z);
        s += dot3_pair(uqh.w, uql.w, ukh.w, ukl.w);
      }
    }
    s += __shfl_xor(s, 1, 64);
    s += __shfl_xor(s, 2, 64);
    if (l4 == 0) {
      float att = 0.f;
      if (d >= 0) {
        float logit = s * 0.125f;
        att = expf(logit - mxb[((size_t)b * 8 + c) * 256 + n]) / rzb[((size_t)b * 8 + c) * 256 + n];
      }
      attL[task] = att;
    }
  }
  __syncthreads();
  if (t < 8) {
    float rs = 0.f;
#pragma unroll
    for (int j = 0; j < 7; j++) rs += attL[t * 7 + j];
    float ri = 1.0f / (rs + 1e-6f);
#pragma unroll
    for (int j = 0; j < 7; j++) {
      float nv = attL[t * 7 + j] * ri;
      nrv[(((size_t)b * 8 + t) * 256 + n) * 7 + j] = nv;
      int d = idxs[j];
      if (d >= 0) atomicAdd(&colsum[((size_t)b * 8 + t) * 256 + d], nv);
    }
  }
}

// ---------------------------------------------------------------------------
// edge[b,c,n,m] (bf16): pair-packed LDS, b128 idx/nrv reads.
// ---------------------------------------------------------------------------
__global__ __launch_bounds__(256, 3) void edge_kernel(
    const int* __restrict__ idx7, const float* __restrict__ nrv,
    const float* __restrict__ colsum, unsigned short* __restrict__ edge) {
  __shared__ unsigned short ncT[256 * 64];
  __shared__ short idxL[256 * 8];
  __shared__ float nrvL[256 * 8];
  int t = threadIdx.x;
  int blk = blockIdx.x;
  int b = blk >> 5, c = (blk >> 2) & 7, mq = blk & 3;
  int m0 = mq * 64;
  for (int i = t; i < 8192; i += 256) ((unsigned int*)ncT)[i] = 0u;
  for (int i = t; i < 2048; i += 256) {
    int r = i >> 3, j = i & 7;
    if (j < 7) {
      idxL[i] = (short)idx7[(size_t)b * 1792 + r * 7 + j];
      nrvL[i] = nrv[((size_t)b * 8 + c) * 1792 + r * 7 + j];
    } else {
      idxL[i] = -1;
      nrvL[i] = 0.f;
    }
  }
  __syncthreads();
  for (int i = t; i < 448; i += 256) {
    int mi = i / 7, j = i - mi * 7;
    int m = m0 + mi;
    int d = idxL[m * 8 + j];
    if (d >= 0) {
      float cs = colsum[((size_t)b * 8 + c) * 256 + d];
      ncT[d * 64 + mi] = f2bf(nrvL[m * 8 + j] / (cs + 1e-6f));
    }
  }
  __syncthreads();
  int wv = t >> 6, l = t & 63;
  int half = l >> 5, p = l & 31;
  const unsigned int* ncP = (const unsigned int*)ncT;
  unsigned int* eb = (unsigned int*)(edge + (((size_t)b * 8 + c) * 256) * 256);
  for (int nn = 0; nn < 32; nn++) {
    int n = nn * 8 + wv * 2 + half;
    int4 iv = *(const int4*)(idxL + n * 8);
    float4 w0 = *(const float4*)(nrvL + n * 8);
    float4 w1 = *(const float4*)(nrvL + n * 8 + 4);
    float a0 = 0.f, a1 = 0.f;
    int d;
    unsigned int pr;
    d = (int)(short)(iv.x & 0xFFFF);
    if (d >= 0) { pr = ncP[d * 32 + p]; a0 += w0.x * bf2f_lo(pr); a1 += w0.x * bf2f_hi(pr); }
    d = iv.x >> 16;
    if (d >= 0) { pr = ncP[d * 32 + p]; a0 += w0.y * bf2f_lo(pr); a1 += w0.y * bf2f_hi(pr); }
    d = (int)(short)(iv.y & 0xFFFF);
    if (d >= 0) { pr = ncP[d * 32 + p]; a0 += w0.z * bf2f_lo(pr); a1 += w0.z * bf2f_hi(pr); }
    d = iv.y >> 16;
    if (d >= 0) { pr = ncP[d * 32 + p]; a0 += w0.w * bf2f_lo(pr); a1 += w0.w * bf2f_hi(pr); }
    d = (int)(short)(iv.z & 0xFFFF);
    if (d >= 0) { pr = ncP[d * 32 + p]; a0 += w1.x * bf2f_lo(pr); a1 += w1.x * bf2f_hi(pr); }
    d = iv.z >> 16;
    if (d >= 0) { pr = ncP[d * 32 + p]; a0 += w1.y * bf2f_lo(pr); a1 += w1.y * bf2f_hi(pr); }
    d = (int)(short)(iv.w & 0xFFFF);
    if (d >= 0) { pr = ncP[d * 32 + p]; a0 += w1.z * bf2f_lo(pr); a1 += w1.z * bf2f_hi(pr); }
    unsigned int packo = (unsigned int)f2bf(a0) | ((unsigned int)f2bf(a1) << 16);
    eb[n * 128 + (m0 >> 1) + p] = packo;
  }
}

// ---------------------------------------------------------------------------
// qkx (fused with xs): stages x-tile, applies sigmoid(elu(.)) writing xs to
// LDS and global (for upd), then qg/kg = xs @ W_l^T + b_l. grid 128.
// ---------------------------------------------------------------------------
static __device__ __forceinline__ float selu1(float v) {
  float e = (v > 0.f) ? v : expm1f(v);
  return 1.0f / (1.0f + expf(-e));
}
__global__ __launch_bounds__(256, 1) void qkx_kernel(
    const float* __restrict__ x, const float* __restrict__ gaw,
    const float* __restrict__ gab, int l, float* __restrict__ xs,
    float* __restrict__ qg, float* __restrict__ kg) {
  __shared__ float xsL[64 * 64];
  int t = threadIdx.x;
  int b = blockIdx.x >> 2, nt = blockIdx.x & 3;
  int f = t & 63, part = t >> 6;
  float wq[64], wk[64];
  const float4* Wq4 = (const float4*)(gaw + (size_t)l * 8192 + f * 64);
  const float4* Wk4 = (const float4*)(gaw + (size_t)l * 8192 + (64 + f) * 64);
#pragma unroll
  for (int j = 0; j < 16; j++) {
    float4 aa = Wq4[j];
    wq[4 * j + 0] = aa.x; wq[4 * j + 1] = aa.y; wq[4 * j + 2] = aa.z; wq[4 * j + 3] = aa.w;
    float4 bb = Wk4[j];
    wk[4 * j + 0] = bb.x; wk[4 * j + 1] = bb.y; wk[4 * j + 2] = bb.z; wk[4 * j + 3] = bb.w;
  }
  float bq = gab[l * 128 + f], bk = gab[l * 128 + 64 + f];
  for (int i = t; i < 1024; i += 256) {
    float4 v = ((const float4*)(x + ((size_t)b * 256 + nt * 64) * 64))[i];
    float4 o;
    o.x = selu1(v.x); o.y = selu1(v.y); o.z = selu1(v.z); o.w = selu1(v.w);
    ((float4*)xsL)[i] = o;
    ((float4*)(xs + ((size_t)b * 256 + nt * 64) * 64))[i] = o;
  }
  __syncthreads();
  for (int i = 0; i < 16; i++) {
    int nl = part * 16 + i;
    const float4* xr = (const float4*)(xsL + nl * 64);
    float aq = 0.f, ak = 0.f;
#pragma unroll
    for (int j = 0; j < 16; j++) {
      float4 v = xr[j];
      aq += v.x * wq[4 * j] + v.y * wq[4 * j + 1] + v.z * wq[4 * j + 2] + v.w * wq[4 * j + 3];
      ak += v.x * wk[4 * j] + v.y * wk[4 * j + 1] + v.z * wk[4 * j + 2] + v.w * wk[4 * j + 3];
    }
    int n = nt * 64 + nl;
    qg[((size_t)b * 256 + n) * 64 + f] = aq + bq;
    kg[((size_t)b * 256 + n) * 64 + f] = ak + bk;
  }
}

// ---------------------------------------------------------------------------
// ga_attn (R7 version): no LDS/barriers; (256,2); grid 256 = b*8+nt.
// ---------------------------------------------------------------------------
__global__ __launch_bounds__(256, 2) void ga_attn_kernel(
    const float* __restrict__ qg, const float* __restrict__ kgT,
    float* __restrict__ a) {
  int t = threadIdx.x;
  int b = blockIdx.x >> 3, nt = blockIdx.x & 7;
  int n0 = nt * 32;
  int wv = t >> 6, l = t & 63;
  const float* kb = kgT + (size_t)b * 16384 + 4 * l;          // [f][m]
  const float* qb = qg + ((size_t)b * 256 + n0 + wv * 8) * 64;
  float acc[8][4];
#pragma unroll
  for (int r = 0; r < 8; r++)
#pragma unroll
    for (int j = 0; j < 4; j++) acc[r][j] = 0.f;
#pragma unroll 4
  for (int kq4 = 0; kq4 < 64; kq4 += 4) {
    float4 kv0 = *(const float4*)(kb + (kq4 + 0) * 256);
    float4 kv1 = *(const float4*)(kb + (kq4 + 1) * 256);
    float4 kv2 = *(const float4*)(kb + (kq4 + 2) * 256);
    float4 kv3 = *(const float4*)(kb + (kq4 + 3) * 256);
#pragma unroll
    for (int r = 0; r < 8; r++) {
      float4 qv = *(const float4*)(qb + r * 64 + kq4);
      acc[r][0] += qv.x * kv0.x + qv.y * kv1.x + qv.z * kv2.x + qv.w * kv3.x;
      acc[r][1] += qv.x * kv0.y + qv.y * kv1.y + qv.z * kv2.y + qv.w * kv3.y;
      acc[r][2] += qv.x * kv0.z + qv.y * kv1.z + qv.z * kv2.z + qv.w * kv3.z;
      acc[r][3] += qv.x * kv0.w + qv.y * kv1.w + qv.z * kv2.w + qv.w * kv3.w;
    }
  }
#pragma unroll
  for (int r = 0; r < 8; r++) {
    float l0 = acc[r][0] * 0.125f, l1 = acc[r][1] * 0.125f;
    float l2 = acc[r][2] * 0.125f, l3 = acc[r][3] * 0.125f;
    float mx = fmaxf(fmaxf(l0, l1), fmaxf(l2, l3));
#pragma unroll
    for (int m = 1; m < 64; m <<= 1) mx = fmaxf(mx, __shfl_xor(mx, m, 64));
    float e0 = expf(l0 - mx), e1 = expf(l1 - mx), e2 = expf(l2 - mx), e3 = expf(l3 - mx);
    float z = e0 + e1 + e2 + e3;
#pragma unroll
    for (int m = 1; m < 64; m <<= 1) z += __shfl_xor(z, m, 64);
    float zi = 1.0f / z;
    int n = n0 + wv * 8 + r;
    float4 o;
    o.x = e0 * zi; o.y = e1 * zi; o.z = e2 * zi; o.w = e3 * zi;
    ((float4*)(a + ((size_t)b * 256 + n) * 256))[l] = o;
  }
}

// ---------------------------------------------------------------------------
// ne normalize + x += (ne3 @ xs)/lip. tt stride 260 (was 256: 8-way LDS bank
// conflicts in the dred stage; 260 -> (4rc+i)%32 ~ conflict-free).
// ---------------------------------------------------------------------------
__global__ __launch_bounds__(256) void upd_kernel(
    const float* __restrict__ a, const unsigned short* __restrict__ edge,
    const float* __restrict__ xs, const float* __restrict__ gaww,
    const float* __restrict__ lipv, int l, float* __restrict__ x) {
  __shared__ float tt[4][8][260];
  __shared__ float ne3[4][256];
  __shared__ float parts[4][4][64];
  __shared__ float dred[32][8];
  __shared__ float dinv[4][8];
  __shared__ float wcL[8];
  __shared__ float lipi;
  int t = threadIdx.x;
  int b = blockIdx.x >> 6, nq = blockIdx.x & 63;
  int n0 = nq * 4;
  if (t == 0) {
    float s = 0.f;
    float wtmp[8];
    for (int c = 0; c < 8; c++) { wtmp[c] = gaww[l * 8 + c]; s += wtmp[c]; }
    for (int c = 0; c < 8; c++) wcL[c] = wtmp[c] / s;
    lipi = 1.0f / lipv[l];
  }
#pragma unroll
  for (int r = 0; r < 4; r++) {
    float av = a[((size_t)b * 256 + n0 + r) * 256 + t];
#pragma unroll
    for (int c = 0; c < 8; c++)
      tt[r][c][t] = av * bf2f(edge[(((size_t)b * 8 + c) * 256 + n0 + r) * 256 + t]);
  }
  __syncthreads();
  {
    int rc = t >> 3, i = t & 7;
    int r = rc >> 3, c = rc & 7;
    float p = 0.f;
#pragma unroll
    for (int kq = 0; kq < 32; kq++) p += tt[r][c][i + 8 * kq];
    dred[rc][i] = p;
  }
  __syncthreads();
  if (t < 32) {
    float s = 0.f;
#pragma unroll
    for (int i = 0; i < 8; i++) s += dred[t][i];
    dinv[t >> 3][t & 7] = 1.0f / (s + 1e-6f);
  }
  __syncthreads();
#pragma unroll
  for (int r = 0; r < 4; r++) {
    float s = 0.f;
#pragma unroll
    for (int c = 0; c < 8; c++) s += wcL[c] * tt[r][c][t] * dinv[r][c];
    ne3[r][t] = s;
  }
  __syncthreads();
  {
    int f = t & 63, part = t >> 6;
    float a0 = 0.f, a1 = 0.f, a2 = 0.f, a3 = 0.f;
    for (int mm = 0; mm < 64; mm++) {
      int m = part * 64 + mm;
      float xv = xs[((size_t)b * 256 + m) * 64 + f];
      a0 += ne3[0][m] * xv;
      a1 += ne3[1][m] * xv;
      a2 += ne3[2][m] * xv;
      a3 += ne3[3][m] * xv;
    }
    parts[0][part][f] = a0;
    parts[1][part][f] = a1;
    parts[2][part][f] = a2;
    parts[3][part][f] = a3;
  }
  __syncthreads();
  {
    int r = t >> 6, f = t & 63;
    float dx = parts[r][0][f] + parts[r][1][f] + parts[r][2][f] + parts[r][3][f];
    x[((size_t)b * 256 + n0 + r) * 64 + f] += dx * lipi;
  }
}

// ---------------------------------------------------------------------------
extern "C" void kernel_launch(void* const* d_in, const int* in_sizes, int n_in,
                              void* d_out, int out_size, void* d_ws, size_t ws_size,
                              hipStream_t stream) {
  (void)in_sizes; (void)n_in; (void)out_size; (void)ws_size;
  const float* fused = (const float*)d_in[0];
  const float* w1 = (const float*)d_in[1];
  const float* b1 = (const float*)d_in[2];
  const float* w2 = (const float*)d_in[3];
  const float* b2 = (const float*)d_in[4];
  const float* eqk = (const float*)d_in[5];
  const float* gaw = (const float*)d_in[6];
  const float* gab = (const float*)d_in[7];
  const float* gaww = (const float*)d_in[8];
  float* x = (float*)d_out;  // x lives in d_out (B,ND,NF)=(32,256,64); fully overwritten.
  char* ws = (char*)d_ws;
  size_t off = 0;
  auto alloc = [&](size_t bytes) -> char* {
    char* p = ws + off;
    off += (bytes + 1023) & ~(size_t)1023;
    return p;
  };
  float* invsig1 = (float*)alloc(64 * 4);
  float* invsig2 = (float*)alloc(64 * 4);
  float* lipv = (float*)alloc(2 * 4);
  float* h = (float*)alloc((size_t)32 * 64 * 64 * 4);
  unsigned short* qhi = (unsigned short*)alloc((size_t)32 * 8 * 256 * 64 * 2);
  unsigned short* qlo = (unsigned short*)alloc((size_t)32 * 8 * 256 * 64 * 2);
  unsigned short* khi = (unsigned short*)alloc((size_t)32 * 8 * 256 * 64 * 2);
  unsigned short* klo = (unsigned short*)alloc((size_t)32 * 8 * 256 * 64 * 2);
  // seP (4 partials, 33.5 MB) aliases edge (33.5 MB): seP dead after topsel.
  char* sep_edge = alloc((size_t)4 * 32 * 256 * 256 * 4);
  float* seP = (float*)sep_edge;
  unsigned short* edge = (unsigned short*)sep_edge;
  float* mxb = (float*)alloc((size_t)65536 * 4);
  float* rzb = (float*)alloc((size_t)65536 * 4);
  int* idx7 = (int*)alloc((size_t)8192 * 7 * 4);
  float* nrv = (float*)alloc((size_t)65536 * 7 * 4);
  float* colsum = (float*)alloc((size_t)65536 * 4);
  float* xs = (float*)alloc((size_t)524288 * 4);
  float* qg = (float*)alloc((size_t)524288 * 4);
  float* kg = (float*)alloc((size_t)524288 * 4);
  float* a = (float*)alloc((size_t)32 * 256 * 256 * 4);
  float* kgT = (float*)alloc((size_t)524288 * 4);

  speclip_kernel<<<130, 256, 0, stream>>>(w1, w2, gaw, invsig1, invsig2, lipv);
  h_kernel<<<512, 256, 0, stream>>>(fused, w1, b1, invsig1, h);
  conv_kernel<<<512, 256, 0, stream>>>(h, w2, b2, invsig2, x);
  qk_kernel<<<512, 256, 0, stream>>>(x, eqk, qhi, qlo, khi, klo);
  attn_kernel<<<512, 256, 0, stream>>>(qhi, qlo, khi, klo, seP, mxb, rzb);
  hipMemsetAsync(colsum, 0, (size_t)65536 * 4, stream);
  topsel_kernel<<<128, 256, 0, stream>>>(seP, idx7);
  nr_kernel<<<8192, 256, 0, stream>>>(qhi, qlo, khi, klo, mxb, rzb, idx7, nrv, colsum);
  edge_kernel<<<1024, 256, 0, stream>>>(idx7, nrv, colsum, edge);
  for (int l = 0; l < 2; l++) {
    qkx_kernel<<<128, 256, 0, stream>>>(x, gaw, gab, l, xs, qg, kg);
    transpose_kernel<<<32, 256, 0, stream>>>(kg, kgT);
    ga_attn_kernel<<<256, 256, 0, stream>>>(qg, kgT, a);
    upd_kernel<<<2048, 256, 0, stream>>>(a, edge, xs, gaww, lipv, l, x);
  }
}